// Round 3
// baseline (550.621 us; speedup 1.0000x reference)
//
#include <hip/hip_runtime.h>
#include <math.h>

#define B_ 32
#define T_ 2048
#define C_ 96
#define L_ 256
#define BLANK 95
#define NEG2 -1.0e30f

typedef const __attribute__((address_space(1))) void* gptr_t;
typedef __attribute__((address_space(3))) void* lptr_t;

// Hardware exp2/log2 (v_exp_f32 / v_log_f32 are base-2 on CDNA).
__device__ __forceinline__ float ex2(float x) {
#if __has_builtin(__builtin_amdgcn_exp2f)
  return __builtin_amdgcn_exp2f(x);
#else
  float r; asm("v_exp_f32 %0, %1" : "=v"(r) : "v"(x)); return r;
#endif
}
__device__ __forceinline__ float lg2(float x) {
#if __has_builtin(__builtin_amdgcn_logf)
  return __builtin_amdgcn_logf(x);
#else
  float r; asm("v_log_f32 %0, %1" : "=v"(r) : "v"(x)); return r;
#endif
}

// ---------------- Kernel 1: log2(softmax + eps) ----------------
__global__ __launch_bounds__(256) void softmax_k(const float* __restrict__ x,
                                                 float* __restrict__ p) {
  int tid = threadIdx.x;
  size_t r = (size_t)blockIdx.x * 8 + (tid >> 5);  // 8 rows per 256-thr block
  int l = tid & 31;
  const float* xr = x + r * C_;
  float x0 = xr[l], x1 = xr[l + 32], x2 = xr[l + 64];
  float m = fmaxf(fmaxf(x0, x1), x2);
#pragma unroll
  for (int off = 16; off >= 1; off >>= 1) m = fmaxf(m, __shfl_xor(m, off));
  float e0 = __expf(x0 - m), e1 = __expf(x1 - m), e2 = __expf(x2 - m);
  float z = e0 + e1 + e2;
#pragma unroll
  for (int off = 16; off >= 1; off >>= 1) z += __shfl_xor(z, off);
  float rz = 1.0f / z;
  float* pr = p + r * C_;
  pr[l]      = lg2(fmaf(e0, rz, 1e-7f));
  pr[l + 32] = lg2(fmaf(e1, rz, 1e-7f));
  pr[l + 64] = lg2(fmaf(e2, rz, 1e-7f));
}

// logaddexp2, 2-term and 3-term (args may be ~ -1e30 stand-ins for -inf)
__device__ __forceinline__ float le2(float x, float y) {
  float m = fmaxf(x, y);
  float d = fminf(x, y) - m;              // <= 0
  return m + lg2(1.0f + ex2(d));
}
__device__ __forceinline__ float le3(float x, float y, float z) {
  float m = fmaxf(fmaxf(x, y), z);
  float md = __builtin_amdgcn_fmed3f(x, y, z);
  float mn = fminf(fminf(x, y), z);
  return m + lg2(1.0f + ex2(md - m) + ex2(mn - m));
}

// ---------------- Kernel 2: CTC alpha DP in log2 domain ----------------
// One wave per batch. States s = lane*8 + j (j=0..7) + tail s=512 on lane 63.
// Even j == blank state (2-term recurrence), odd j == label state (3-term).
__global__ __launch_bounds__(64) void ctc_dp(const float* __restrict__ probs,
                                             const int* __restrict__ labels,
                                             const int* __restrict__ widths,
                                             const int* __restrict__ lengths,
                                             float* __restrict__ out) {
  __shared__ float sbuf[2 * 6144];  // 2 x (64 rows x 96 classes) = 48 KiB
  const int b = blockIdx.x;
  const int lane = threadIdx.x;
  const int Tb = widths[b] >> 3;   // widths / WIDTH_DOWN(8); in [1536,2048]
  const int s_end = 2 * lengths[b];
  const int* lab = labels + b * L_;

  int ext[9];
  float madd[8];
#pragma unroll
  for (int j = 0; j < 8; ++j) {
    int s = lane * 8 + j;
    if (s & 1) {
      int li = (s - 1) >> 1;
      ext[j] = lab[li];
      madd[j] = (li >= 1 && lab[li] == lab[li - 1]) ? NEG2 : 0.f;
    } else {
      ext[j] = BLANK;
      madd[j] = 0.f;
    }
  }
  ext[8] = BLANK;  // tail state s=512 (blank), meaningful on lane 63 only

  const float* gp = probs + (size_t)b * (T_ * C_);

  // Drain label/width loads so vmcnt counts only staging loads below.
  asm volatile("s_waitcnt vmcnt(0)" ::: "memory");

  // Stage chunk 0 (64 rows = 24 KiB) into buffer 0.
#pragma unroll
  for (int i = 0; i < 24; ++i)
    __builtin_amdgcn_global_load_lds((gptr_t)(gp + i * 256 + lane * 4),
                                     (lptr_t)(sbuf + i * 256), 16, 0, 0);

  float a0 = NEG2, a1 = NEG2, a2 = NEG2, a3 = NEG2;
  float a4 = NEG2, a5 = NEG2, a6 = NEG2, a7 = NEG2, at = NEG2;

  const int NC = (Tb + 63) >> 6;

  for (int tc = 0; tc < NC; ++tc) {
    const float* cb = sbuf + (tc & 1) * 6144;
    if (tc + 1 < NC) {
      float* nb = sbuf + ((tc + 1) & 1) * 6144;
      const float* gsrc = gp + (tc + 1) * 6144;
#pragma unroll
      for (int i = 0; i < 24; ++i)
        __builtin_amdgcn_global_load_lds((gptr_t)(gsrc + i * 256 + lane * 4),
                                         (lptr_t)(nb + i * 256), 16, 0, 0);
      asm volatile("s_waitcnt vmcnt(24)" ::: "memory");  // chunk tc complete
    } else {
      asm volatile("s_waitcnt vmcnt(0)" ::: "memory");
    }

    const int tbase = tc << 6;
    if (tc == 0 && lane == 0) {  // alpha0
      a0 = cb[BLANK];
      a1 = cb[ext[1]];
    }
    const int tstart = (tc == 0) ? 1 : tbase;
    const int tend = (Tb < tbase + 64) ? Tb : (tbase + 64);

    float pc[9];
    {
      const float* r0 = cb + (tstart - tbase) * C_;
#pragma unroll
      for (int j = 0; j < 9; ++j) pc[j] = r0[ext[j]];
    }

    for (int tt = tstart; tt < tend; ++tt) {
      const bool hv = (tt + 1 < tend);
      const float* r2 = cb + (hv ? (tt + 1 - tbase) : 0) * C_;
      float pn[9];
#pragma unroll
      for (int j = 0; j < 9; ++j) pn[j] = r2[ext[j]];

      float b1 = __shfl_up(a7, 1);  // prev lane's last state (s-1 for j=0)
      if (lane == 0) b1 = NEG2;

      // Descending update: each line reads only not-yet-updated (old) values.
      at = le2(at, a7) + pc[8];                  // s=512 (blank, lane 63)
      a7 = le3(a7, a6, a5 + madd[7]) + pc[7];
      a6 = le2(a6, a5) + pc[6];
      a5 = le3(a5, a4, a3 + madd[5]) + pc[5];
      a4 = le2(a4, a3) + pc[4];
      a3 = le3(a3, a2, a1 + madd[3]) + pc[3];
      a2 = le2(a2, a1) + pc[2];
      a1 = le3(a1, a0, b1 + madd[1]) + pc[1];
      a0 = le2(a0, b1) + pc[0];

#pragma unroll
      for (int j = 0; j < 9; ++j) pc[j] = pn[j];
    }
  }

  // loss = -ln2 * logaddexp2(alpha[s_end], alpha[s_end-1])
  const int j1 = (s_end - 1) & 7, l1 = (s_end - 1) >> 3;  // s_end-1 <= 511
  float v1 = a0;
  v1 = (j1 == 1) ? a1 : v1; v1 = (j1 == 2) ? a2 : v1;
  v1 = (j1 == 3) ? a3 : v1; v1 = (j1 == 4) ? a4 : v1;
  v1 = (j1 == 5) ? a5 : v1; v1 = (j1 == 6) ? a6 : v1;
  v1 = (j1 == 7) ? a7 : v1;
  const float aend1 = __shfl(v1, l1);

  const int j0 = s_end & 7;
  const int l0 = (s_end >> 3) > 63 ? 63 : (s_end >> 3);
  float v0 = a0;
  v0 = (j0 == 1) ? a1 : v0; v0 = (j0 == 2) ? a2 : v0;
  v0 = (j0 == 3) ? a3 : v0; v0 = (j0 == 4) ? a4 : v0;
  v0 = (j0 == 5) ? a5 : v0; v0 = (j0 == 6) ? a6 : v0;
  v0 = (j0 == 7) ? a7 : v0;
  const float ge = __shfl(v0, l0);
  const float gt = __shfl(at, 63);
  const float aend = (s_end == 512) ? gt : ge;

  if (lane == 0)
    out[b] = -0.6931471805599453f * le2(aend, aend1);
}

extern "C" void kernel_launch(void* const* d_in, const int* in_sizes, int n_in,
                              void* d_out, int out_size, void* d_ws, size_t ws_size,
                              hipStream_t stream) {
  const int* labels = (const int*)d_in[0];
  const float* logits = (const float*)d_in[1];
  const int* widths = (const int*)d_in[2];
  const int* lengths = (const int*)d_in[3];
  float* out = (float*)d_out;
  float* probs = (float*)d_ws;  // B*T*C fp32 = 25.2 MB scratch

  softmax_k<<<(B_ * T_) / 8, 256, 0, stream>>>(logits, probs);
  ctc_dp<<<B_, 64, 0, stream>>>(probs, labels, widths, lengths, out);
}

// Round 4
// 443.126 us; speedup vs baseline: 1.2426x; 1.2426x over previous
//
#include <hip/hip_runtime.h>
#include <math.h>

#define B_ 32
#define T_ 2048
#define C_ 96
#define L_ 256
#define BLANK 95

typedef const __attribute__((address_space(1))) void* gptr_t;
typedef __attribute__((address_space(3))) void* lptr_t;

// Hardware exp2/log2 (epilogue only).
__device__ __forceinline__ float ex2(float x) {
  float r; asm("v_exp_f32 %0, %1" : "=v"(r) : "v"(x)); return r;
}
__device__ __forceinline__ float lg2(float x) {
  float r; asm("v_log_f32 %0, %1" : "=v"(r) : "v"(x)); return r;
}
__device__ __forceinline__ float le2l(float x, float y) {  // logaddexp2
  float m = fmaxf(x, y);
  float d = fminf(x, y) - m;
  return m + lg2(1.0f + ex2(d));
}

// ---------------- Kernel 1: linear p = softmax + eps ----------------
__global__ __launch_bounds__(256) void softmax_k(const float* __restrict__ x,
                                                 float* __restrict__ p) {
  int tid = threadIdx.x;
  size_t r = (size_t)blockIdx.x * 8 + (tid >> 5);
  int l = tid & 31;
  const float* xr = x + r * C_;
  float x0 = xr[l], x1 = xr[l + 32], x2 = xr[l + 64];
  float m = fmaxf(fmaxf(x0, x1), x2);
#pragma unroll
  for (int off = 16; off >= 1; off >>= 1) m = fmaxf(m, __shfl_xor(m, off));
  float e0 = __expf(x0 - m), e1 = __expf(x1 - m), e2 = __expf(x2 - m);
  float z = e0 + e1 + e2;
#pragma unroll
  for (int off = 16; off >= 1; off >>= 1) z += __shfl_xor(z, off);
  float rz = 1.0f / z;
  float* pr = p + r * C_;
  pr[l]      = fmaf(e0, rz, 1e-7f);
  pr[l + 32] = fmaf(e1, rz, 1e-7f);
  pr[l + 64] = fmaf(e2, rz, 1e-7f);
}

// ---------------- Kernel 2: CTC alpha DP, linear w/ per-lane 2^F frames ----
// One wave per batch. Lane owns states s = 8*lane .. 8*lane+7 (+ tail s=512
// on lane 63). Invariant: true_alpha[s] = a[j] * 2^F(lane).
__global__ __launch_bounds__(64) void ctc_dp(const float* __restrict__ probs,
                                             const int* __restrict__ labels,
                                             const int* __restrict__ widths,
                                             const int* __restrict__ lengths,
                                             float* __restrict__ out) {
  __shared__ float sbuf[2 * 6144];  // 2 x (64 rows x 96 classes) = 48 KiB
  const int b = blockIdx.x;
  const int lane = threadIdx.x;
  const int Tb = widths[b] >> 3;   // in [1536, 2048]
  const int s_end = 2 * lengths[b];
  const int* lab = labels + b * L_;

  // 4 labels per lane (states 8l+1,8l+3,8l+5,8l+7 -> labels 4l..4l+3).
  const int4 lb = *reinterpret_cast<const int4*>(lab + 4 * lane);
  const int e1 = lb.x, e3 = lb.y, e5 = lb.z, e7 = lb.w;
  const int pw = __shfl_up(lb.w, 1);  // lab[4l-1]
  const float m1 = (lane > 0 && e1 != pw) ? 1.f : 0.f;
  const float m3 = (e3 != e1) ? 1.f : 0.f;
  const float m5 = (e5 != e3) ? 1.f : 0.f;
  const float m7 = (e7 != e5) ? 1.f : 0.f;

  const float* gp = probs + (size_t)b * (T_ * C_);
  asm volatile("s_waitcnt vmcnt(0)" ::: "memory");

#pragma unroll
  for (int i = 0; i < 24; ++i)
    __builtin_amdgcn_global_load_lds((gptr_t)(gp + i * 256 + lane * 4),
                                     (lptr_t)(sbuf + i * 256), 16, 0, 0);

  float a0 = 0.f, a1 = 0.f, a2 = 0.f, a3 = 0.f;
  float a4 = 0.f, a5 = 0.f, a6 = 0.f, a7 = 0.f, at = 0.f;
  int F = 0;
  bool dead = true;
  float b1_raw = 0.f;  // prev lane's a7 (pre-rescale), frame Fp_s
  int Fp_s = 0;

  const int NC = (Tb + 63) >> 6;

  for (int tc = 0; tc < NC; ++tc) {
    const float* cb = sbuf + (tc & 1) * 6144;
    if (tc + 1 < NC) {
      float* nb = sbuf + ((tc + 1) & 1) * 6144;
      const float* gsrc = gp + (tc + 1) * 6144;
#pragma unroll
      for (int i = 0; i < 24; ++i)
        __builtin_amdgcn_global_load_lds((gptr_t)(gsrc + i * 256 + lane * 4),
                                         (lptr_t)(nb + i * 256), 16, 0, 0);
      asm volatile("s_waitcnt vmcnt(24)" ::: "memory");
    } else {
      asm volatile("s_waitcnt vmcnt(0)" ::: "memory");
    }

    const int tbase = tc << 6;
    if (tc == 0 && lane == 0) {  // alpha0 (t=0): a0=p(blank), a1=p(lab0)
      a0 = cb[BLANK];
      a1 = cb[e1];
    }
    const int tstart = (tc == 0) ? 1 : tbase;
    const int tend = (Tb < tbase + 64) ? Tb : (tbase + 64);

    // Gathers for row tstart.
    const float* r0 = cb + (tstart - tbase) * C_;
    float pb = r0[BLANK], p1 = r0[e1], p3 = r0[e3], p5 = r0[e5], p7 = r0[e7];

    for (int tt = tstart; tt < tend; ++tt) {
      // Prefetch next row's 5 gathers.
      const bool hv = (tt + 1 < tend);
      const float* rn = cb + (hv ? (tt + 1 - tbase) : 0) * C_;
      float qb = rn[BLANK], q1 = rn[e1], q3 = rn[e3], q5 = rn[e5], q7 = rn[e7];

      // Frame reconciliation for incoming boundary value.
      int di = Fp_s - F;
      const bool adopt = (b1_raw > 0.f) && (di > 60 || dead);
      if (__any(adopt)) {
        if (adopt) {  // lossless reframe (tiny values underflow -> flushed)
          a0 = ldexpf(a0, -di); a1 = ldexpf(a1, -di); a2 = ldexpf(a2, -di);
          a3 = ldexpf(a3, -di); a4 = ldexpf(a4, -di); a5 = ldexpf(a5, -di);
          a6 = ldexpf(a6, -di); a7 = ldexpf(a7, -di); at = ldexpf(at, -di);
          F = Fp_s;
          di = 0;
        }
      }
      const float b1a = ldexpf(b1_raw, di);

      // Send my start-of-step frame (post-adopt) for next step's recv.
      int Fp_next = __shfl_up(F, 1);

      // Updates (descending; all read pre-step values).
      float na7 = fmaf(m7, a5, a7 + a6) * p7;
      float b1n = __shfl_up(na7, 1);  // issued early -> latency hidden
      at = (at + a7) * pb;
      a6 = (a6 + a5) * pb;
      a5 = fmaf(m5, a3, a5 + a4) * p5;
      a4 = (a4 + a3) * pb;
      a3 = fmaf(m3, a1, a3 + a2) * p3;
      a2 = (a2 + a1) * pb;
      a1 = fmaf(m1, b1a, a1 + a0) * p1;
      a0 = (a0 + b1a) * pb;
      a7 = na7;

      // Rescale (pin lane max) every 2nd step.
      if (tt & 1) {
        float m8 = fmaxf(fmaxf(fmaxf(a0, a1), fmaxf(a2, a3)),
                         fmaxf(fmaxf(a4, a5), fmaxf(fmaxf(a6, a7), at)));
        const int e = (int)((__float_as_uint(m8) >> 23) & 0xFF) - 126;
        dead = (m8 == 0.f);
        const float scl = __uint_as_float((unsigned)(127 - e) << 23);  // 2^-e
        a0 *= scl; a1 *= scl; a2 *= scl; a3 *= scl; a4 *= scl;
        a5 *= scl; a6 *= scl; a7 *= scl; at *= scl;
        F += e;
      }

      if (lane == 0) b1n = 0.f;
      b1_raw = b1n;
      Fp_s = Fp_next;
      pb = qb; p1 = q1; p3 = q3; p5 = q5; p7 = q7;
    }
  }

  // loss = -ln2 * logaddexp2(log2 alpha[s_end], log2 alpha[s_end-1])
  // Per-lane: pick own a[j], convert to log2 + F, then shfl.
  const int sm1 = s_end - 1;               // in [127, 511]
  const int j1 = sm1 & 7, l1 = sm1 >> 3;
  const int j0 = s_end & 7;
  const int l0 = (s_end >> 3) > 63 ? 63 : (s_end >> 3);

  float v1 = a0;
  v1 = (j1 == 1) ? a1 : v1; v1 = (j1 == 2) ? a2 : v1;
  v1 = (j1 == 3) ? a3 : v1; v1 = (j1 == 4) ? a4 : v1;
  v1 = (j1 == 5) ? a5 : v1; v1 = (j1 == 6) ? a6 : v1;
  v1 = (j1 == 7) ? a7 : v1;
  float v0 = a0;
  v0 = (j0 == 1) ? a1 : v0; v0 = (j0 == 2) ? a2 : v0;
  v0 = (j0 == 3) ? a3 : v0; v0 = (j0 == 4) ? a4 : v0;
  v0 = (j0 == 5) ? a5 : v0; v0 = (j0 == 6) ? a6 : v0;
  v0 = (j0 == 7) ? a7 : v0;

  const float Ff = (float)F;
  const float lv1 = (v1 > 0.f) ? (lg2(v1) + Ff) : -1.0e30f;
  const float lv0 = (v0 > 0.f) ? (lg2(v0) + Ff) : -1.0e30f;
  const float lvt = (at > 0.f) ? (lg2(at) + Ff) : -1.0e30f;

  const float ge1 = __shfl(lv1, l1);
  const float ge0 = __shfl(lv0, l0);
  const float gt = __shfl(lvt, 63);
  const float aend = (s_end == 512) ? gt : ge0;

  if (lane == 0)
    out[b] = -0.6931471805599453f * le2l(aend, ge1);
}

extern "C" void kernel_launch(void* const* d_in, const int* in_sizes, int n_in,
                              void* d_out, int out_size, void* d_ws, size_t ws_size,
                              hipStream_t stream) {
  const int* labels = (const int*)d_in[0];
  const float* logits = (const float*)d_in[1];
  const int* widths = (const int*)d_in[2];
  const int* lengths = (const int*)d_in[3];
  float* out = (float*)d_out;
  float* probs = (float*)d_ws;  // B*T*C fp32 = 25.2 MB scratch

  softmax_k<<<(B_ * T_) / 8, 256, 0, stream>>>(logits, probs);
  ctc_dp<<<B_, 64, 0, stream>>>(probs, labels, widths, lengths, out);
}

// Round 7
// 420.930 us; speedup vs baseline: 1.3081x; 1.0527x over previous
//
#include <hip/hip_runtime.h>
#include <math.h>

#define B_ 32
#define T_ 2048
#define C_ 96
#define L_ 256
#define BLANK 95
#define CH 30  // DP time-steps per staged chunk

typedef const __attribute__((address_space(1))) void* gptr_t;
typedef __attribute__((address_space(3))) void* lptr_t;

__device__ __forceinline__ float ex2(float x) {
  float r; asm("v_exp_f32 %0, %1" : "=v"(r) : "v"(x)); return r;
}
__device__ __forceinline__ float lg2(float x) {
  float r; asm("v_log_f32 %0, %1" : "=v"(r) : "v"(x)); return r;
}
__device__ __forceinline__ float le2l(float x, float y) {  // logaddexp2
  float m = fmaxf(x, y);
  float d = fminf(x, y) - m;
  return m + lg2(1.0f + ex2(d));
}
__device__ __forceinline__ unsigned short f2bf(float f) {  // RNE f32->bf16
  unsigned u = __float_as_uint(f);
  return (unsigned short)((u + 0x7FFFu + ((u >> 16) & 1u)) >> 16);
}
__device__ __forceinline__ float bfu(unsigned short u) {
  return __uint_as_float((unsigned)u << 16);
}

// ---- Kernel 1: fused softmax + per-lane label-prob gather/pack ----
__global__ __launch_bounds__(64) void gather_pack(const float* __restrict__ logits,
                                                  const int* __restrict__ labels,
                                                  float* __restrict__ blanks,
                                                  ushort4* __restrict__ packed) {
  const int tid = threadIdx.x;
  const int bt = blockIdx.x;  // b*T + t
  const int b = bt >> 11;
  const float* xr = logits + (size_t)bt * C_;
  float xa = xr[tid];
  float xb = (tid < 32) ? xr[64 + tid] : -1.0e30f;
  float m = fmaxf(xa, xb);
#pragma unroll
  for (int off = 32; off >= 1; off >>= 1) m = fmaxf(m, __shfl_xor(m, off));
  float ea = __expf(xa - m);
  float eb = (tid < 32) ? __expf(xb - m) : 0.f;
  float z = ea + eb;
#pragma unroll
  for (int off = 32; off >= 1; off >>= 1) z += __shfl_xor(z, off);
  float rz = 1.0f / z;
  __shared__ float sp[C_];
  sp[tid] = fmaf(ea, rz, 1e-7f);
  if (tid < 32) sp[64 + tid] = fmaf(eb, rz, 1e-7f);
  __syncthreads();
  const int4 lb = *reinterpret_cast<const int4*>(labels + (b << 8) + 4 * tid);
  ushort4 o;
  o.x = f2bf(sp[lb.x]); o.y = f2bf(sp[lb.y]);
  o.z = f2bf(sp[lb.z]); o.w = f2bf(sp[lb.w]);
  packed[(size_t)bt * 64 + tid] = o;
  if (tid == 0) blanks[bt] = sp[BLANK];
}

// ---- Kernel 2: CTC alpha DP, linear domain w/ per-lane 2^F frames ----
// One wave per batch; lane owns states 8l..8l+7 (+ s=512 tail on lane 63).
// true_alpha = a * 2^F.  IMMEDIATE pinning: measure entry-max exponent and
// fold 2^-e into this step's P-values (no lag -> single-step transients).
// Boundary value sent as exact mantissa (<2) + frame: no transient cascade.
// Bound: entry<=2^101, b1a<=2^41, scl<=2^60  =>  all values < 2^102. Finite.
#define STEP(NX4PTR, NXBPTR) do {                                            \
    const ushort4 qu = *(NX4PTR);                                            \
    const float qb = *(NXBPTR);                                              \
    float m8 = fmaxf(fmaxf(fmaxf(a0, a1), fmaxf(a2, a3)),                    \
                     fmaxf(fmaxf(a4, a5), fmaxf(fmaxf(a6, a7), at)));        \
    const unsigned ebyte = (__float_as_uint(m8) >> 23) & 255u;               \
    int e_cur = (ebyte == 0u) ? 0 : ((int)ebyte - 126);                      \
    e_cur = (e_cur < -60) ? -60 : ((e_cur > 126) ? 126 : e_cur);             \
    const bool dead_now = (m8 == 0.f);                                       \
    int di = Fp_s - F;                                                       \
    const bool adopt = (b1_raw > 0.f) && (di > 40 || dead_now);              \
    if (__any(adopt)) { if (adopt) {                                         \
      a0 = ldexpf(a0, -di); a1 = ldexpf(a1, -di); a2 = ldexpf(a2, -di);      \
      a3 = ldexpf(a3, -di); a4 = ldexpf(a4, -di); a5 = ldexpf(a5, -di);      \
      a6 = ldexpf(a6, -di); a7 = ldexpf(a7, -di); at = ldexpf(at, -di);      \
      F = Fp_s; di = 0; e_cur = 0; } }                                       \
    const float b1a = ldexpf(b1_raw, di);                                    \
    F += e_cur;                                                              \
    const float scl = __uint_as_float((unsigned)(127 - e_cur) << 23);        \
    const float P1 = p1 * scl, P3 = p3 * scl, P5 = p5 * scl;                 \
    const float P7 = p7 * scl, PB = pb * scl;                                \
    const float na7 = fmaf(m7, a5, a7 + a6) * P7;                            \
    const int en = (int)((__float_as_uint(na7) >> 23) & 255u) - 126;         \
    const float mant = ldexpf(na7, -en);  /* exact: na7 == mant*2^en */      \
    const int Fs = F + en;                                                   \
    float b1n = __shfl_up(mant, 1);                                          \
    int Fp_n = __shfl_up(Fs, 1);                                             \
    at = (at + a7) * PB;                                                     \
    a6 = (a6 + a5) * PB;                                                     \
    a5 = fmaf(m5, a3, a5 + a4) * P5;                                         \
    a4 = (a4 + a3) * PB;                                                     \
    a3 = fmaf(m3, a1, a3 + a2) * P3;                                         \
    a2 = (a2 + a1) * PB;                                                     \
    a1 = fmaf(m1, b1a, a1 + a0) * P1;                                        \
    a0 = (a0 + b1a) * PB;                                                    \
    a7 = na7;                                                                \
    b1_raw = (lane == 0) ? 0.f : b1n;                                        \
    Fp_s = Fp_n;                                                             \
    p1 = bfu(qu.x); p3 = bfu(qu.y); p5 = bfu(qu.z); p7 = bfu(qu.w);          \
    pb = qb;                                                                 \
  } while (0)

__global__ __launch_bounds__(64) void ctc_dp(const ushort4* __restrict__ packed,
                                             const float* __restrict__ blanks,
                                             const int* __restrict__ labels,
                                             const int* __restrict__ widths,
                                             const int* __restrict__ lengths,
                                             float* __restrict__ out) {
  __shared__ ushort4 sP[2][CH][64];  // 2 x 30 x 512B = 30 KiB
  __shared__ float sB[2][64];        // staged blanks
  const int b = blockIdx.x;
  const int lane = threadIdx.x;
  const int Tb = widths[b] >> 3;     // in [1536, 2048]
  const int s_end = 2 * lengths[b];
  const int* lab = labels + (b << 8);
  const int4 lb = *reinterpret_cast<const int4*>(lab + 4 * lane);
  const int pw = __shfl_up(lb.w, 1);
  const float m1 = (lane > 0 && lb.x != pw) ? 1.f : 0.f;
  const float m3 = (lb.y != lb.x) ? 1.f : 0.f;
  const float m5 = (lb.z != lb.y) ? 1.f : 0.f;
  const float m7 = (lb.w != lb.z) ? 1.f : 0.f;

  const char* gp = (const char*)(packed + (size_t)b * (T_ * 64));
  const float* gb = blanks + b * T_;

  asm volatile("s_waitcnt vmcnt(0)" ::: "memory");
  // Stage chunk 0 (rows 0..29 = 15 KiB -> 15 x 1KiB) + blank row.
#pragma unroll
  for (int i = 0; i < 15; ++i)
    __builtin_amdgcn_global_load_lds((gptr_t)(gp + i * 1024 + lane * 16),
                                     (lptr_t)((char*)&sP[0][0][0] + i * 1024),
                                     16, 0, 0);
  __builtin_amdgcn_global_load_lds((gptr_t)(gb + lane), (lptr_t)&sB[0][0], 4, 0, 0);
  asm volatile("s_waitcnt vmcnt(0)" ::: "memory");

  float a0 = 0.f, a1 = 0.f, a2 = 0.f, a3 = 0.f;
  float a4 = 0.f, a5 = 0.f, a6 = 0.f, a7 = 0.f, at = 0.f;
  int F = 0, Fp_s = 0;
  float b1_raw = 0.f;

  if (lane == 0) {  // alpha0 at t=0
    a0 = sB[0][0];
    a1 = bfu(sP[0][0][0].x);
  }
  // Preload probs for row t=1.
  float p1, p3, p5, p7, pb;
  {
    const ushort4 u = sP[0][1][lane];
    pb = sB[0][1];
    p1 = bfu(u.x); p3 = bfu(u.y); p5 = bfu(u.z); p7 = bfu(u.w);
  }

  const int NC = (Tb + CH - 1) / CH;
  for (int tc = 0; tc < NC; ++tc) {
    const int cur = tc & 1;
    const int tbase = tc * CH;
    if (tc + 1 < NC) {  // stage next chunk into the other buffer
      const int t2 = tbase + CH;
#pragma unroll
      for (int i = 0; i < 15; ++i) {
        int rr = t2 + 2 * i;
        rr = (rr > T_ - 2) ? (T_ - 2) : rr;  // clamp: stay inside packed[b]
        __builtin_amdgcn_global_load_lds(
            (gptr_t)(gp + (size_t)rr * 512 + lane * 16),
            (lptr_t)((char*)&sP[cur ^ 1][0][0] + i * 1024), 16, 0, 0);
      }
      __builtin_amdgcn_global_load_lds((gptr_t)(gb + t2 + lane),
                                       (lptr_t)&sB[cur ^ 1][0], 4, 0, 0);
    }
    const int tstart = (tc == 0) ? 1 : tbase;
    const int tend = (Tb < tbase + CH) ? Tb : (tbase + CH);

    for (int tt = tstart; tt < tend - 1; ++tt)
      STEP(&sP[cur][tt + 1 - tbase][lane], &sB[cur][tt + 1 - tbase]);

    // Last step of chunk: consumes next chunk's row 0 (must be resident).
    asm volatile("s_waitcnt vmcnt(0)" ::: "memory");
    STEP(&sP[cur ^ 1][0][lane], &sB[cur ^ 1][0]);
  }

  // loss = -ln2 * logaddexp2(log2 alpha[s_end], log2 alpha[s_end-1])
  const int sm1 = s_end - 1;  // in [127, 511]
  const int j1 = sm1 & 7, l1 = sm1 >> 3;
  const int j0 = s_end & 7;
  const int l0 = (s_end >> 3) > 63 ? 63 : (s_end >> 3);

  float v1 = a0;
  v1 = (j1 == 1) ? a1 : v1; v1 = (j1 == 2) ? a2 : v1;
  v1 = (j1 == 3) ? a3 : v1; v1 = (j1 == 4) ? a4 : v1;
  v1 = (j1 == 5) ? a5 : v1; v1 = (j1 == 6) ? a6 : v1;
  v1 = (j1 == 7) ? a7 : v1;
  float v0 = a0;
  v0 = (j0 == 1) ? a1 : v0; v0 = (j0 == 2) ? a2 : v0;
  v0 = (j0 == 3) ? a3 : v0; v0 = (j0 == 4) ? a4 : v0;
  v0 = (j0 == 5) ? a5 : v0; v0 = (j0 == 6) ? a6 : v0;
  v0 = (j0 == 7) ? a7 : v0;

  const float Ff = (float)F;
  const float lv1 = (v1 > 0.f) ? (lg2(v1) + Ff) : -1.0e30f;
  const float lv0 = (v0 > 0.f) ? (lg2(v0) + Ff) : -1.0e30f;
  const float lvt = (at > 0.f) ? (lg2(at) + Ff) : -1.0e30f;

  const float ge1 = __shfl(lv1, l1);
  const float ge0 = __shfl(lv0, l0);
  const float gt = __shfl(lvt, 63);
  const float aend = (s_end == 512) ? gt : ge0;

  if (lane == 0)
    out[b] = -0.6931471805599453f * le2l(aend, ge1);
}

extern "C" void kernel_launch(void* const* d_in, const int* in_sizes, int n_in,
                              void* d_out, int out_size, void* d_ws, size_t ws_size,
                              hipStream_t stream) {
  const int* labels = (const int*)d_in[0];
  const float* logits = (const float*)d_in[1];
  const int* widths = (const int*)d_in[2];
  const int* lengths = (const int*)d_in[3];
  float* out = (float*)d_out;

  // ws layout: [blanks: B*T fp32 = 256KB][packed: B*T*64 ushort4 = 32MB]
  float* blanks = (float*)d_ws;
  ushort4* packed = (ushort4*)((char*)d_ws + (size_t)B_ * T_ * sizeof(float));

  gather_pack<<<B_ * T_, 64, 0, stream>>>(logits, labels, blanks, packed);
  ctc_dp<<<B_, 64, 0, stream>>>(packed, blanks, labels, widths, lengths, out);
}

// Round 8
// 399.169 us; speedup vs baseline: 1.3794x; 1.0545x over previous
//
#include <hip/hip_runtime.h>
#include <math.h>

#define B_ 32
#define T_ 2048
#define C_ 96
#define L_ 256
#define BLANK 95

__device__ __forceinline__ float ex2(float x) {
  float r; asm("v_exp_f32 %0, %1" : "=v"(r) : "v"(x)); return r;
}
__device__ __forceinline__ float lg2(float x) {
  float r; asm("v_log_f32 %0, %1" : "=v"(r) : "v"(x)); return r;
}
__device__ __forceinline__ float le2l(float x, float y) {  // logaddexp2
  float m = fmaxf(x, y);
  float d = fminf(x, y) - m;
  return m + lg2(1.0f + ex2(d));
}
__device__ __forceinline__ unsigned short f2bf(float f) {  // RNE f32->bf16
  unsigned u = __float_as_uint(f);
  return (unsigned short)((u + 0x7FFFu + ((u >> 16) & 1u)) >> 16);
}
__device__ __forceinline__ float bfu(unsigned short u) {
  return __uint_as_float((unsigned)u << 16);
}
// Wave shift-right-by-1 via DPP (VALU, ~8 cyc) instead of ds_bpermute
// (~120 cyc DS latency). dpp_ctrl 0x138 = WAVE_SHR1; old=0 + bound_ctrl
// false -> lane 0 receives 0.
__device__ __forceinline__ float dpp_shr1_f(float x) {
  return __int_as_float(__builtin_amdgcn_update_dpp(
      0, __float_as_int(x), 0x138, 0xF, 0xF, false));
}
__device__ __forceinline__ int dpp_shr1_i(int x) {
  return __builtin_amdgcn_update_dpp(0, x, 0x138, 0xF, 0xF, false);
}

// ---- Kernel 1: fused softmax + per-lane label-prob gather/pack ----
__global__ __launch_bounds__(64) void gather_pack(const float* __restrict__ logits,
                                                  const int* __restrict__ labels,
                                                  float* __restrict__ blanks,
                                                  ushort4* __restrict__ packed) {
  const int tid = threadIdx.x;
  const int bt = blockIdx.x;  // b*T + t
  const int b = bt >> 11;
  const float* xr = logits + (size_t)bt * C_;
  float xa = xr[tid];
  float xb = (tid < 32) ? xr[64 + tid] : -1.0e30f;
  float m = fmaxf(xa, xb);
#pragma unroll
  for (int off = 32; off >= 1; off >>= 1) m = fmaxf(m, __shfl_xor(m, off));
  float ea = __expf(xa - m);
  float eb = (tid < 32) ? __expf(xb - m) : 0.f;
  float z = ea + eb;
#pragma unroll
  for (int off = 32; off >= 1; off >>= 1) z += __shfl_xor(z, off);
  float rz = 1.0f / z;
  __shared__ float sp[C_];
  sp[tid] = fmaf(ea, rz, 1e-7f);
  if (tid < 32) sp[64 + tid] = fmaf(eb, rz, 1e-7f);
  __syncthreads();
  const int4 lb = *reinterpret_cast<const int4*>(labels + (b << 8) + 4 * tid);
  ushort4 o;
  o.x = f2bf(sp[lb.x]); o.y = f2bf(sp[lb.y]);
  o.z = f2bf(sp[lb.z]); o.w = f2bf(sp[lb.w]);
  packed[(size_t)bt * 64 + tid] = o;
  if (tid == 0) blanks[bt] = sp[BLANK];
}

// ---- Kernel 2: CTC alpha DP, linear domain w/ per-lane 2^F frames ----
// One wave per batch; lane owns states 8l..8l+7 (+ s=512 tail on lane 63).
// true_alpha = a * 2^F. LAGGED pinning (scl = 2^-e_prev): the entry-max
// measurement runs in parallel with the updates. Safe because boundary
// sends are mantissa-normalized (b1_raw < 2) and e >= -60 is clamped:
// worst transient <= 2^101 < 2^128 (see R6 analysis). Dead lanes drift
// F by -60/step so first inflow always has di > 40 -> adopt.
// No LDS anywhere: probs stream HBM->VGPR ring (depth 8), cross-lane via DPP.
#define STEP(QU, QB) do {                                                    \
    const float m8 = fmaxf(fmaxf(fmaxf(a0, a1), fmaxf(a2, a3)),              \
                     fmaxf(fmaxf(a4, a5), fmaxf(fmaxf(a6, a7), at)));        \
    const unsigned ebyte = (__float_as_uint(m8) >> 23) & 255u;               \
    int e_cur = (int)ebyte - 126;                                            \
    e_cur = (e_cur < -60) ? -60 : e_cur;                                     \
    int di = Fp_s - F;                                                       \
    const bool adopt = (b1_raw > 0.f) && (di > 40);                          \
    if (__any(adopt)) { if (adopt) {                                         \
      a0 = ldexpf(a0, -di); a1 = ldexpf(a1, -di); a2 = ldexpf(a2, -di);      \
      a3 = ldexpf(a3, -di); a4 = ldexpf(a4, -di); a5 = ldexpf(a5, -di);      \
      a6 = ldexpf(a6, -di); a7 = ldexpf(a7, -di); at = ldexpf(at, -di);      \
      F = Fp_s; di = 0; e_cur = 0; } }                                       \
    const float b1a = ldexpf(b1_raw, di);                                    \
    const float scl = __uint_as_float((unsigned)(127 - e_prev) << 23);       \
    F += e_prev;                                                             \
    const float P1 = p1 * scl, P3 = p3 * scl, P5 = p5 * scl;                 \
    const float P7 = p7 * scl, PB = pb * scl;                                \
    const float na7 = fmaf(m7, a5, a7 + a6) * P7;                            \
    const int en = (int)((__float_as_uint(na7) >> 23) & 255u) - 126;         \
    const float mant = ldexpf(na7, -en);  /* exact: na7 == mant*2^en */      \
    const int Fs = F + en;                                                   \
    const float b1n = dpp_shr1_f(mant);                                      \
    const int Fp_n = dpp_shr1_i(Fs);                                         \
    at = (at + a7) * PB;                                                     \
    a6 = (a6 + a5) * PB;                                                     \
    a5 = fmaf(m5, a3, a5 + a4) * P5;                                         \
    a4 = (a4 + a3) * PB;                                                     \
    a3 = fmaf(m3, a1, a3 + a2) * P3;                                         \
    a2 = (a2 + a1) * PB;                                                     \
    a1 = fmaf(m1, b1a, a1 + a0) * P1;                                        \
    a0 = (a0 + b1a) * PB;                                                    \
    a7 = na7;                                                                \
    b1_raw = b1n;   /* lane 0 already 0 via DPP old=0 */                     \
    Fp_s = Fp_n;    /* lane 0 gets 0; harmless (b1_raw==0 gates) */          \
    e_prev = e_cur;                                                          \
    p1 = bfu((QU).x); p3 = bfu((QU).y); p5 = bfu((QU).z); p7 = bfu((QU).w);  \
    pb = (QB);                                                               \
  } while (0)

// Slot U of the 8-wide unrolled group at base time tt: consume row tt+U+1
// (held in qU/rU), then reload qU/rU with row tt+U+9 (clamped).
#define SLOT(U) do {                                                         \
    STEP(q##U, r##U);                                                        \
    int trow = tt + 9 + U;                                                   \
    trow = (trow > T_ - 1) ? (T_ - 1) : trow;                                \
    q##U = gp[(size_t)trow * 64 + lane];                                     \
    r##U = gb[trow];                                                         \
  } while (0)

__global__ __launch_bounds__(64) void ctc_dp(const ushort4* __restrict__ packed,
                                             const float* __restrict__ blanks,
                                             const int* __restrict__ labels,
                                             const int* __restrict__ widths,
                                             const int* __restrict__ lengths,
                                             float* __restrict__ out) {
  const int b = blockIdx.x;
  const int lane = threadIdx.x;
  const int Tb = widths[b] >> 3;     // in [1536, 2048]
  const int s_end = 2 * lengths[b];
  const int* lab = labels + (b << 8);
  const int4 lb = *reinterpret_cast<const int4*>(lab + 4 * lane);
  const int pw = __shfl_up(lb.w, 1);  // one-time; DS latency irrelevant here
  const float m1 = (lane > 0 && lb.x != pw) ? 1.f : 0.f;
  const float m3 = (lb.y != lb.x) ? 1.f : 0.f;
  const float m5 = (lb.z != lb.y) ? 1.f : 0.f;
  const float m7 = (lb.w != lb.z) ? 1.f : 0.f;

  const ushort4* gp = packed + (size_t)b * (T_ * 64);
  const float* gb = blanks + b * T_;

  // Row 0 (alpha0), row 1 (first p's), rows 2..9 -> register ring q0..q7.
  const ushort4 u0 = gp[lane];
  const float bl0 = gb[0];
  const ushort4 u1 = gp[64 + lane];
  const float bl1 = gb[1];
  ushort4 q0 = gp[2 * 64 + lane], q1 = gp[3 * 64 + lane];
  ushort4 q2 = gp[4 * 64 + lane], q3 = gp[5 * 64 + lane];
  ushort4 q4 = gp[6 * 64 + lane], q5 = gp[7 * 64 + lane];
  ushort4 q6 = gp[8 * 64 + lane], q7 = gp[9 * 64 + lane];
  float r0 = gb[2], r1 = gb[3], r2 = gb[4], r3 = gb[5];
  float r4 = gb[6], r5 = gb[7], r6 = gb[8], r7 = gb[9];

  float a0 = 0.f, a1 = 0.f, a2 = 0.f, a3 = 0.f;
  float a4 = 0.f, a5 = 0.f, a6 = 0.f, a7 = 0.f, at = 0.f;
  int F = 0, Fp_s = 0, e_prev = 0;
  float b1_raw = 0.f;

  if (lane == 0) {  // alpha0 at t=0
    a0 = bl0;
    a1 = bfu(u0.x);
  }
  float pb = bl1;  // probs for row t=1
  float p1 = bfu(u1.x), p3 = bfu(u1.y), p5 = bfu(u1.z), p7 = bfu(u1.w);

  int tt = 1;
  for (; tt + 8 <= Tb; tt += 8) {
    SLOT(0); SLOT(1); SLOT(2); SLOT(3);
    SLOT(4); SLOT(5); SLOT(6); SLOT(7);
  }
  // Tail: r = Tb - tt in [0, 7]; slot u holds row tt+u+1.
  if (tt + 0 < Tb) STEP(q0, r0);
  if (tt + 1 < Tb) STEP(q1, r1);
  if (tt + 2 < Tb) STEP(q2, r2);
  if (tt + 3 < Tb) STEP(q3, r3);
  if (tt + 4 < Tb) STEP(q4, r4);
  if (tt + 5 < Tb) STEP(q5, r5);
  if (tt + 6 < Tb) STEP(q6, r6);

  // loss = -ln2 * logaddexp2(log2 alpha[s_end], log2 alpha[s_end-1])
  const int sm1 = s_end - 1;  // in [127, 511]
  const int j1 = sm1 & 7, l1 = sm1 >> 3;
  const int j0 = s_end & 7;
  const int l0 = (s_end >> 3) > 63 ? 63 : (s_end >> 3);

  float v1 = a0;
  v1 = (j1 == 1) ? a1 : v1; v1 = (j1 == 2) ? a2 : v1;
  v1 = (j1 == 3) ? a3 : v1; v1 = (j1 == 4) ? a4 : v1;
  v1 = (j1 == 5) ? a5 : v1; v1 = (j1 == 6) ? a6 : v1;
  v1 = (j1 == 7) ? a7 : v1;
  float v0 = a0;
  v0 = (j0 == 1) ? a1 : v0; v0 = (j0 == 2) ? a2 : v0;
  v0 = (j0 == 3) ? a3 : v0; v0 = (j0 == 4) ? a4 : v0;
  v0 = (j0 == 5) ? a5 : v0; v0 = (j0 == 6) ? a6 : v0;
  v0 = (j0 == 7) ? a7 : v0;

  const float Ff = (float)F;
  const float lv1 = (v1 > 0.f) ? (lg2(v1) + Ff) : -1.0e30f;
  const float lv0 = (v0 > 0.f) ? (lg2(v0) + Ff) : -1.0e30f;
  const float lvt = (at > 0.f) ? (lg2(at) + Ff) : -1.0e30f;

  const float ge1 = __shfl(lv1, l1);
  const float ge0 = __shfl(lv0, l0);
  const float gt = __shfl(lvt, 63);
  const float aend = (s_end == 512) ? gt : ge0;

  if (lane == 0)
    out[b] = -0.6931471805599453f * le2l(aend, ge1);
}

extern "C" void kernel_launch(void* const* d_in, const int* in_sizes, int n_in,
                              void* d_out, int out_size, void* d_ws, size_t ws_size,
                              hipStream_t stream) {
  const int* labels = (const int*)d_in[0];
  const float* logits = (const float*)d_in[1];
  const int* widths = (const int*)d_in[2];
  const int* lengths = (const int*)d_in[3];
  float* out = (float*)d_out;

  // ws layout: [blanks: B*T fp32 = 256KB][packed: B*T*64 ushort4 = 32MB]
  float* blanks = (float*)d_ws;
  ushort4* packed = (ushort4*)((char*)d_ws + (size_t)B_ * T_ * sizeof(float));

  gather_pack<<<B_ * T_, 64, 0, stream>>>(logits, labels, blanks, packed);
  ctc_dp<<<B_, 64, 0, stream>>>(packed, blanks, labels, widths, lengths, out);
}

// Round 9
// 397.038 us; speedup vs baseline: 1.3868x; 1.0054x over previous
//
#include <hip/hip_runtime.h>
#include <math.h>

#define B_ 32
#define T_ 2048
#define C_ 96
#define L_ 256
#define BLANK 95

__device__ __forceinline__ float ex2(float x) {
  float r; asm("v_exp_f32 %0, %1" : "=v"(r) : "v"(x)); return r;
}
__device__ __forceinline__ float lg2(float x) {
  float r; asm("v_log_f32 %0, %1" : "=v"(r) : "v"(x)); return r;
}
__device__ __forceinline__ float le2l(float x, float y) {  // logaddexp2
  float m = fmaxf(x, y);
  float d = fminf(x, y) - m;
  return m + lg2(1.0f + ex2(d));
}
__device__ __forceinline__ unsigned short f2bf(float f) {  // RNE f32->bf16
  unsigned u = __float_as_uint(f);
  return (unsigned short)((u + 0x7FFFu + ((u >> 16) & 1u)) >> 16);
}
__device__ __forceinline__ float bfu(unsigned short u) {
  return __uint_as_float((unsigned)u << 16);
}
// Wave shift-right-by-1 via DPP (VALU) instead of ds_bpermute.
__device__ __forceinline__ float dpp_shr1_f(float x) {
  return __int_as_float(__builtin_amdgcn_update_dpp(
      0, __float_as_int(x), 0x138, 0xF, 0xF, false));
}
__device__ __forceinline__ int dpp_shr1_i(int x) {
  return __builtin_amdgcn_update_dpp(0, x, 0x138, 0xF, 0xF, false);
}

// ---- Kernel 1: fused softmax + per-lane label-prob gather/pack ----
// blanks2 is written DUPLICATED x2 so the DP kernel can index it with
// (lane&1) -> lane-varying address -> VMEM vector load (vmcnt, in-order),
// never an s_load (SMEM completes out-of-order; consuming one result
// forces lgkmcnt(0) which drains the whole scalar prefetch pipeline).
__global__ __launch_bounds__(64) void gather_pack(const float* __restrict__ logits,
                                                  const int* __restrict__ labels,
                                                  float* __restrict__ blanks2,
                                                  ushort4* __restrict__ packed) {
  const int tid = threadIdx.x;
  const int bt = blockIdx.x;  // b*T + t
  const int b = bt >> 11;
  const float* xr = logits + (size_t)bt * C_;
  float xa = xr[tid];
  float xb = (tid < 32) ? xr[64 + tid] : -1.0e30f;
  float m = fmaxf(xa, xb);
#pragma unroll
  for (int off = 32; off >= 1; off >>= 1) m = fmaxf(m, __shfl_xor(m, off));
  float ea = __expf(xa - m);
  float eb = (tid < 32) ? __expf(xb - m) : 0.f;
  float z = ea + eb;
#pragma unroll
  for (int off = 32; off >= 1; off >>= 1) z += __shfl_xor(z, off);
  float rz = 1.0f / z;
  __shared__ float sp[C_];
  sp[tid] = fmaf(ea, rz, 1e-7f);
  if (tid < 32) sp[64 + tid] = fmaf(eb, rz, 1e-7f);
  __syncthreads();
  const int4 lb = *reinterpret_cast<const int4*>(labels + (b << 8) + 4 * tid);
  ushort4 o;
  o.x = f2bf(sp[lb.x]); o.y = f2bf(sp[lb.y]);
  o.z = f2bf(sp[lb.z]); o.w = f2bf(sp[lb.w]);
  packed[(size_t)bt * 64 + tid] = o;
  if (tid < 2) blanks2[2 * bt + tid] = sp[BLANK];
}

// ---- Kernel 2: CTC alpha DP, linear domain w/ per-lane 2^F frames ----
// One wave per batch; lane owns states 8l..8l+7 (+ s=512 tail on lane 63).
// true_alpha = a * 2^F. Lagged pinning (scl = 2^-e_prev) runs the max tree
// in parallel with the updates; boundary sends are mantissa-normalized
// (b1_raw < 2) and e >= -60 clamped => all transients < 2^102, finite.
// No LDS; probs stream HBM->VGPR ring (8 rows deep); cross-lane via DPP.
#define STEP(QU, QB) do {                                                    \
    const float m8 = fmaxf(fmaxf(fmaxf(a0, a1), fmaxf(a2, a3)),              \
                     fmaxf(fmaxf(a4, a5), fmaxf(fmaxf(a6, a7), at)));        \
    const unsigned ebyte = (__float_as_uint(m8) >> 23) & 255u;               \
    int e_cur = (int)ebyte - 126;                                            \
    e_cur = (e_cur < -60) ? -60 : e_cur;                                     \
    int di = Fp_s - F;                                                       \
    const bool adopt = (b1_raw > 0.f) && (di > 40);                          \
    if (__any(adopt)) { if (adopt) {                                         \
      a0 = ldexpf(a0, -di); a1 = ldexpf(a1, -di); a2 = ldexpf(a2, -di);      \
      a3 = ldexpf(a3, -di); a4 = ldexpf(a4, -di); a5 = ldexpf(a5, -di);      \
      a6 = ldexpf(a6, -di); a7 = ldexpf(a7, -di); at = ldexpf(at, -di);      \
      F = Fp_s; di = 0; e_cur = 0; } }                                       \
    const float b1a = ldexpf(b1_raw, di);                                    \
    const float scl = __uint_as_float((unsigned)(127 - e_prev) << 23);       \
    F += e_prev;                                                             \
    const float P1 = p1 * scl, P3 = p3 * scl, P5 = p5 * scl;                 \
    const float P7 = p7 * scl, PB = pb * scl;                                \
    const float na7 = fmaf(m7, a5, a7 + a6) * P7;                            \
    const int en = (int)((__float_as_uint(na7) >> 23) & 255u) - 126;         \
    const float mant = ldexpf(na7, -en);  /* exact: na7 == mant*2^en */      \
    const int Fs = F + en;                                                   \
    const float b1n = dpp_shr1_f(mant);                                      \
    const int Fp_n = dpp_shr1_i(Fs);                                         \
    at = (at + a7) * PB;                                                     \
    a6 = (a6 + a5) * PB;                                                     \
    a5 = fmaf(m5, a3, a5 + a4) * P5;                                         \
    a4 = (a4 + a3) * PB;                                                     \
    a3 = fmaf(m3, a1, a3 + a2) * P3;                                         \
    a2 = (a2 + a1) * PB;                                                     \
    a1 = fmaf(m1, b1a, a1 + a0) * P1;                                        \
    a0 = (a0 + b1a) * PB;                                                    \
    a7 = na7;                                                                \
    b1_raw = b1n;   /* lane 0 already 0 via DPP old=0 */                     \
    Fp_s = Fp_n;                                                             \
    e_prev = e_cur;                                                          \
    p1 = bfu((QU).x); p3 = bfu((QU).y); p5 = bfu((QU).z); p7 = bfu((QU).w);  \
    pb = (QB);                                                               \
  } while (0)

// Slot U: consume row tt+U+1 (held in qU/rU), reload row tt+U+9 (clamped).
#define SLOT(U) do {                                                         \
    STEP(q##U, r##U);                                                        \
    int trow = tt + 9 + U;                                                   \
    trow = (trow > T_ - 1) ? (T_ - 1) : trow;                                \
    q##U = gp[(size_t)trow * 64 + lane];                                     \
    r##U = gb[2 * trow + lpar];                                              \
  } while (0)

__global__ __launch_bounds__(64) void ctc_dp(const ushort4* __restrict__ packed,
                                             const float* __restrict__ blanks2,
                                             const int* __restrict__ labels,
                                             const int* __restrict__ widths,
                                             const int* __restrict__ lengths,
                                             float* __restrict__ out) {
  const int b = blockIdx.x;
  const int lane = threadIdx.x;
  const int lpar = lane & 1;         // lane-varying -> forces VMEM load
  const int Tb = widths[b] >> 3;     // in [1536, 2048]
  const int s_end = 2 * lengths[b];
  const int* lab = labels + (b << 8);
  const int4 lb = *reinterpret_cast<const int4*>(lab + 4 * lane);
  const int pw = __shfl_up(lb.w, 1);  // one-time
  const float m1 = (lane > 0 && lb.x != pw) ? 1.f : 0.f;
  const float m3 = (lb.y != lb.x) ? 1.f : 0.f;
  const float m5 = (lb.z != lb.y) ? 1.f : 0.f;
  const float m7 = (lb.w != lb.z) ? 1.f : 0.f;

  const ushort4* gp = packed + (size_t)b * (T_ * 64);
  const float* gb = blanks2 + b * (2 * T_);

  // Row 0 (alpha0), row 1 (first p's), rows 2..9 -> register ring q0..q7.
  const ushort4 u0 = gp[lane];
  const float bl0 = gb[lpar];
  const ushort4 u1 = gp[64 + lane];
  const float bl1 = gb[2 + lpar];
  ushort4 q0 = gp[2 * 64 + lane], q1 = gp[3 * 64 + lane];
  ushort4 q2 = gp[4 * 64 + lane], q3 = gp[5 * 64 + lane];
  ushort4 q4 = gp[6 * 64 + lane], q5 = gp[7 * 64 + lane];
  ushort4 q6 = gp[8 * 64 + lane], q7 = gp[9 * 64 + lane];
  float r0 = gb[2 * 2 + lpar], r1 = gb[2 * 3 + lpar];
  float r2 = gb[2 * 4 + lpar], r3 = gb[2 * 5 + lpar];
  float r4 = gb[2 * 6 + lpar], r5 = gb[2 * 7 + lpar];
  float r6 = gb[2 * 8 + lpar], r7 = gb[2 * 9 + lpar];

  float a0 = 0.f, a1 = 0.f, a2 = 0.f, a3 = 0.f;
  float a4 = 0.f, a5 = 0.f, a6 = 0.f, a7 = 0.f, at = 0.f;
  int F = 0, Fp_s = 0, e_prev = 0;
  float b1_raw = 0.f;

  if (lane == 0) {  // alpha0 at t=0
    a0 = bl0;
    a1 = bfu(u0.x);
  }
  float pb = bl1;  // probs for row t=1
  float p1 = bfu(u1.x), p3 = bfu(u1.y), p5 = bfu(u1.z), p7 = bfu(u1.w);

  int tt = 1;
  for (; tt + 8 <= Tb; tt += 8) {
    SLOT(0); SLOT(1); SLOT(2); SLOT(3);
    SLOT(4); SLOT(5); SLOT(6); SLOT(7);
  }
  // Tail: slot u holds row tt+u+1.
  if (tt + 0 < Tb) STEP(q0, r0);
  if (tt + 1 < Tb) STEP(q1, r1);
  if (tt + 2 < Tb) STEP(q2, r2);
  if (tt + 3 < Tb) STEP(q3, r3);
  if (tt + 4 < Tb) STEP(q4, r4);
  if (tt + 5 < Tb) STEP(q5, r5);
  if (tt + 6 < Tb) STEP(q6, r6);

  // loss = -ln2 * logaddexp2(log2 alpha[s_end], log2 alpha[s_end-1])
  const int sm1 = s_end - 1;  // in [127, 511]
  const int j1 = sm1 & 7, l1 = sm1 >> 3;
  const int j0 = s_end & 7;
  const int l0 = (s_end >> 3) > 63 ? 63 : (s_end >> 3);

  float v1 = a0;
  v1 = (j1 == 1) ? a1 : v1; v1 = (j1 == 2) ? a2 : v1;
  v1 = (j1 == 3) ? a3 : v1; v1 = (j1 == 4) ? a4 : v1;
  v1 = (j1 == 5) ? a5 : v1; v1 = (j1 == 6) ? a6 : v1;
  v1 = (j1 == 7) ? a7 : v1;
  float v0 = a0;
  v0 = (j0 == 1) ? a1 : v0; v0 = (j0 == 2) ? a2 : v0;
  v0 = (j0 == 3) ? a3 : v0; v0 = (j0 == 4) ? a4 : v0;
  v0 = (j0 == 5) ? a5 : v0; v0 = (j0 == 6) ? a6 : v0;
  v0 = (j0 == 7) ? a7 : v0;

  const float Ff = (float)F;
  const float lv1 = (v1 > 0.f) ? (lg2(v1) + Ff) : -1.0e30f;
  const float lv0 = (v0 > 0.f) ? (lg2(v0) + Ff) : -1.0e30f;
  const float lvt = (at > 0.f) ? (lg2(at) + Ff) : -1.0e30f;

  const float ge1 = __shfl(lv1, l1);
  const float ge0 = __shfl(lv0, l0);
  const float gt = __shfl(lvt, 63);
  const float aend = (s_end == 512) ? gt : ge0;

  if (lane == 0)
    out[b] = -0.6931471805599453f * le2l(aend, ge1);
}

extern "C" void kernel_launch(void* const* d_in, const int* in_sizes, int n_in,
                              void* d_out, int out_size, void* d_ws, size_t ws_size,
                              hipStream_t stream) {
  const int* labels = (const int*)d_in[0];
  const float* logits = (const float*)d_in[1];
  const int* widths = (const int*)d_in[2];
  const int* lengths = (const int*)d_in[3];
  float* out = (float*)d_out;

  // ws layout: [blanks2: B*T*2 fp32 = 512KB][packed: B*T*64 ushort4 = 32MB]
  float* blanks2 = (float*)d_ws;
  ushort4* packed = (ushort4*)((char*)d_ws + (size_t)B_ * T_ * 2 * sizeof(float));

  gather_pack<<<B_ * T_, 64, 0, stream>>>(logits, labels, blanks2, packed);
  ctc_dp<<<B_, 64, 0, stream>>>(packed, blanks2, labels, widths, lengths, out);
}

// Round 11
// 237.800 us; speedup vs baseline: 2.3155x; 1.6696x over previous
//
#include <hip/hip_runtime.h>
#include <math.h>

#define B_ 32
#define T_ 2048
#define C_ 96
#define L_ 256
#define BLANK 95

__device__ __forceinline__ float ex2(float x) {
  float r; asm("v_exp_f32 %0, %1" : "=v"(r) : "v"(x)); return r;
}
__device__ __forceinline__ float lg2(float x) {
  float r; asm("v_log_f32 %0, %1" : "=v"(r) : "v"(x)); return r;
}
__device__ __forceinline__ unsigned short f2bf(float f) {  // RNE f32->bf16
  unsigned u = __float_as_uint(f);
  return (unsigned short)((u + 0x7FFFu + ((u >> 16) & 1u)) >> 16);
}
__device__ __forceinline__ float bfu(unsigned short u) {
  return __uint_as_float((unsigned)u << 16);
}
// Wave shifts via DPP (VALU). 0x138 = WAVE_SHR1 (lane i <- lane i-1),
// 0x130 = WAVE_SHL1 (lane i <- lane i+1). old=0 -> boundary lane gets 0.
__device__ __forceinline__ float dpp_shr1_f(float x) {
  return __int_as_float(__builtin_amdgcn_update_dpp(
      0, __float_as_int(x), 0x138, 0xF, 0xF, false));
}
__device__ __forceinline__ int dpp_shr1_i(int x) {
  return __builtin_amdgcn_update_dpp(0, x, 0x138, 0xF, 0xF, false);
}
__device__ __forceinline__ float dpp_shl1_f(float x) {
  return __int_as_float(__builtin_amdgcn_update_dpp(
      0, __float_as_int(x), 0x130, 0xF, 0xF, false));
}
__device__ __forceinline__ int dpp_shl1_i(int x) {
  return __builtin_amdgcn_update_dpp(0, x, 0x130, 0xF, 0xF, false);
}

// ---- Kernel 1: fused softmax + per-lane label-prob gather/pack ----
__global__ __launch_bounds__(64) void gather_pack(const float* __restrict__ logits,
                                                  const int* __restrict__ labels,
                                                  float* __restrict__ blanks2,
                                                  ushort4* __restrict__ packed) {
  const int tid = threadIdx.x;
  const int bt = blockIdx.x;  // b*T + t
  const int b = bt >> 11;
  const float* xr = logits + (size_t)bt * C_;
  float xa = xr[tid];
  float xb = (tid < 32) ? xr[64 + tid] : -1.0e30f;
  float m = fmaxf(xa, xb);
#pragma unroll
  for (int off = 32; off >= 1; off >>= 1) m = fmaxf(m, __shfl_xor(m, off));
  float ea = __expf(xa - m);
  float eb = (tid < 32) ? __expf(xb - m) : 0.f;
  float z = ea + eb;
#pragma unroll
  for (int off = 32; off >= 1; off >>= 1) z += __shfl_xor(z, off);
  float rz = 1.0f / z;
  __shared__ float sp[C_];
  sp[tid] = fmaf(ea, rz, 1e-7f);
  if (tid < 32) sp[64 + tid] = fmaf(eb, rz, 1e-7f);
  __syncthreads();
  const int4 lb = *reinterpret_cast<const int4*>(labels + (b << 8) + 4 * tid);
  ushort4 o;
  o.x = f2bf(sp[lb.x]); o.y = f2bf(sp[lb.y]);
  o.z = f2bf(sp[lb.z]); o.w = f2bf(sp[lb.w]);
  packed[(size_t)bt * 64 + tid] = o;
  if (tid < 2) blanks2[2 * bt + tid] = sp[BLANK];
}

// ---------------- Kernel 2: meet-in-the-middle CTC DP ----------------
// One 128-thread block per batch. Wave 0: alpha forward (rows 1..tm-1).
// Wave 1: beta backward (rows Tb-1..tm). Join: P = sum_s A[tm-1][s]*B[tm-1][s].
// Per-lane 2^F frames; IMMEDIATE pinning (scl = 2^-e_cur, measured this step).
// Sends are mantissa-normalized (< 2). Safety induction: entry*scl <= 2,
// inflow <= 2^25*scl <= 2^85 transient, next step pins it; all < 2^88. Finite.

#define STEPF(QU, QB) do {                                                   \
    const float m8 = fmaxf(fmaxf(fmaxf(a0, a1), fmaxf(a2, a3)),              \
                     fmaxf(fmaxf(a4, a5), fmaxf(fmaxf(a6, a7), at)));        \
    const unsigned ebyte = (__float_as_uint(m8) >> 23) & 255u;               \
    int e_cur = (int)ebyte - 126;                                            \
    e_cur = (e_cur < -60) ? -60 : e_cur;                                     \
    const bool dead0 = (m8 == 0.f);                                          \
    if (dead0) e_cur = 0;                                                    \
    const int di = (b1_raw > 0.f) ? (Fp_s - F) : 0;                          \
    const int shift = dead0 ? di : ((di > 24) ? (di - 24) : 0);              \
    a0 = ldexpf(a0, -shift); a1 = ldexpf(a1, -shift);                        \
    a2 = ldexpf(a2, -shift); a3 = ldexpf(a3, -shift);                        \
    a4 = ldexpf(a4, -shift); a5 = ldexpf(a5, -shift);                        \
    a6 = ldexpf(a6, -shift); a7 = ldexpf(a7, -shift);                        \
    at = ldexpf(at, -shift);                                                 \
    const float b1a = ldexpf(b1_raw, di - shift);                            \
    const float scl = ldexpf(1.0f, -e_cur);                                  \
    F += shift + e_cur;                                                      \
    const float PB = pb * scl, P1 = p1 * scl, P3 = p3 * scl,                 \
                P5 = p5 * scl, P7 = p7 * scl;                                \
    const float na7 = fmaf(m7, a5, a7 + a6) * P7;                            \
    const int en = (int)((__float_as_uint(na7) >> 23) & 255u) - 126;         \
    const float mant = ldexpf(na7, -en);  /* exact: na7 == mant*2^en */      \
    const float b1n = dpp_shr1_f(mant);                                      \
    const int Fp_n = dpp_shr1_i(F + en);                                     \
    at = (at + a7) * PB;                                                     \
    a6 = (a6 + a5) * PB;                                                     \
    a5 = fmaf(m5, a3, a5 + a4) * P5;                                         \
    a4 = (a4 + a3) * PB;                                                     \
    a3 = fmaf(m3, a1, a3 + a2) * P3;                                         \
    a2 = (a2 + a1) * PB;                                                     \
    a1 = fmaf(m1, b1a, a1 + a0) * P1;                                        \
    a0 = (a0 + b1a) * PB;                                                    \
    a7 = na7;                                                                \
    b1_raw = b1n; Fp_s = Fp_n;                                               \
    p1 = bfu((QU).x); p3 = bfu((QU).y); p5 = bfu((QU).z); p7 = bfu((QU).w);  \
    pb = (QB);                                                               \
  } while (0)

#define SLOTF(U) do {                                                        \
    STEPF(q##U, r##U);                                                       \
    int trow = tt + 9 + U;                                                   \
    trow = (trow > T_ - 1) ? (T_ - 1) : trow;                                \
    q##U = gp[(size_t)trow * 64 + lane];                                     \
    r##U = gb[2 * trow + lpar];                                              \
  } while (0)

#define STEPB(QU, QB) do {                                                   \
    const float m8 = fmaxf(fmaxf(fmaxf(b0, b1), fmaxf(b2, b3)),              \
                     fmaxf(fmaxf(b4, b5), fmaxf(fmaxf(b6, b7), bt)));        \
    const unsigned ebyte = (__float_as_uint(m8) >> 23) & 255u;               \
    int e_cur = (int)ebyte - 126;                                            \
    e_cur = (e_cur < -60) ? -60 : e_cur;                                     \
    const bool dead0 = (m8 == 0.f);                                          \
    if (dead0) e_cur = 0;                                                    \
    const float uin = fmaxf(u0, u1);                                         \
    const int di = (uin > 0.f) ? (Fn_s - F) : 0;                             \
    const int shift = dead0 ? di : ((di > 24) ? (di - 24) : 0);              \
    b0 = ldexpf(b0, -shift); b1 = ldexpf(b1, -shift);                        \
    b2 = ldexpf(b2, -shift); b3 = ldexpf(b3, -shift);                        \
    b4 = ldexpf(b4, -shift); b5 = ldexpf(b5, -shift);                        \
    b6 = ldexpf(b6, -shift); b7 = ldexpf(b7, -shift);                        \
    bt = ldexpf(bt, -shift);                                                 \
    const int sh2 = di - shift;                                              \
    const float e0r = ldexpf(u0, sh2), e1r = ldexpf(u1, sh2);                \
    const float scl = ldexpf(1.0f, -e_cur);                                  \
    F += shift + e_cur;                                                      \
    const float PB = pb * scl, P1 = p1 * scl, P3 = p3 * scl,                 \
                P5 = p5 * scl, P7 = p7 * scl, PN = pn1 * scl;                \
    const float bp0 = b0 * PB, bp1 = b1 * P1, bp2 = b2 * PB, bp3 = b3 * P3,  \
                bp4 = b4 * PB, bp5 = b5 * P5, bp6 = b6 * PB, bp7 = b7 * P7,  \
                bpt = bt * PB;                                               \
    const float e0e = (lane == 63) ? bt : e0r;                               \
    const float bp8 = e0e * PB;                                              \
    const float bp9 = e1r * PN;                                              \
    const float nb0 = bp0 + bp1;                                             \
    const float nb1 = fmaf(m3, bp3, bp1 + bp2);                              \
    const float mx01 = fmaxf(nb0, nb1);                                      \
    const int en = (int)((__float_as_uint(mx01) >> 23) & 255u) - 126;        \
    const float u0n = dpp_shl1_f(ldexpf(nb0, -en));                          \
    const float u1n = dpp_shl1_f(ldexpf(nb1, -en));                          \
    const int Fn_n = dpp_shl1_i(F + en);                                     \
    b2 = bp2 + bp3;                                                          \
    b3 = fmaf(m5, bp5, bp3 + bp4);                                           \
    b4 = bp4 + bp5;                                                          \
    b5 = fmaf(m7, bp7, bp5 + bp6);                                           \
    b6 = bp6 + bp7;                                                          \
    b7 = fmaf(mn, bp9, bp7 + bp8);                                           \
    bt = bpt;                                                                \
    b0 = nb0; b1 = nb1;                                                      \
    u0 = u0n; u1 = u1n; Fn_s = Fn_n;                                         \
    p1 = bfu((QU).x); p3 = bfu((QU).y); p5 = bfu((QU).z); p7 = bfu((QU).w);  \
    pb = (QB);                                                               \
    pn1 = dpp_shl1_f(p1);                                                    \
  } while (0)

#define SLOTB(U) do {                                                        \
    STEPB(q##U, r##U);                                                       \
    int trow = tt - 9 - U;                                                   \
    trow = (trow < 0) ? 0 : trow;                                            \
    q##U = gp[(size_t)trow * 64 + lane];                                     \
    r##U = gb[2 * trow + lpar];                                              \
  } while (0)

__global__ __launch_bounds__(128) void ctc_dp(const ushort4* __restrict__ packed,
                                              const float* __restrict__ blanks2,
                                              const int* __restrict__ labels,
                                              const int* __restrict__ widths,
                                              const int* __restrict__ lengths,
                                              float* __restrict__ out) {
  __shared__ float Alog[513];
  __shared__ float Blog[513];
  const int b = blockIdx.x;
  const int tid = threadIdx.x;
  const int wid = tid >> 6;
  const int lane = tid & 63;
  const int lpar = lane & 1;
  const int Tb = widths[b] >> 3;     // in [1536, 2048]
  const int s_end = 2 * lengths[b];
  const int tm = Tb >> 1;            // meet row: join at t = tm-1
  const int* lab = labels + (b << 8);
  const int4 lb = *reinterpret_cast<const int4*>(lab + 4 * lane);
  const int pw = __shfl_up(lb.w, 1);
  const float m1 = (lane > 0 && lb.x != pw) ? 1.f : 0.f;
  const float m3 = (lb.y != lb.x) ? 1.f : 0.f;
  const float m5 = (lb.z != lb.y) ? 1.f : 0.f;
  const float m7 = (lb.w != lb.z) ? 1.f : 0.f;
  const float mdn = __shfl_down(m1, 1);
  const float mn = (lane == 63) ? 0.f : mdn;  // skip mask for s+2 = 8l+9

  const ushort4* gp = packed + (size_t)b * (T_ * 64);
  const float* gb = blanks2 + b * (2 * T_);

  if (wid == 0) {
    // ---------------- forward alpha: rows 0 .. tm-1 ----------------
    const ushort4 u0v = gp[lane];
    const float bl0 = gb[lpar];
    const ushort4 u1v = gp[64 + lane];
    const float bl1 = gb[2 + lpar];
    ushort4 q0 = gp[2 * 64 + lane], q1 = gp[3 * 64 + lane];
    ushort4 q2 = gp[4 * 64 + lane], q3 = gp[5 * 64 + lane];
    ushort4 q4 = gp[6 * 64 + lane], q5 = gp[7 * 64 + lane];
    ushort4 q6 = gp[8 * 64 + lane], q7 = gp[9 * 64 + lane];
    float r0 = gb[2 * 2 + lpar], r1 = gb[2 * 3 + lpar];
    float r2 = gb[2 * 4 + lpar], r3 = gb[2 * 5 + lpar];
    float r4 = gb[2 * 6 + lpar], r5 = gb[2 * 7 + lpar];
    float r6 = gb[2 * 8 + lpar], r7 = gb[2 * 9 + lpar];

    float a0 = 0.f, a1 = 0.f, a2 = 0.f, a3 = 0.f;
    float a4 = 0.f, a5 = 0.f, a6 = 0.f, a7 = 0.f, at = 0.f;
    int F = 0, Fp_s = 0;
    float b1_raw = 0.f;
    if (lane == 0) { a0 = bl0; a1 = bfu(u0v.x); }
    float pb = bl1;
    float p1 = bfu(u1v.x), p3 = bfu(u1v.y), p5 = bfu(u1v.z), p7 = bfu(u1v.w);

    int tt = 1;
    for (; tt + 8 <= tm; tt += 8) {
      SLOTF(0); SLOTF(1); SLOTF(2); SLOTF(3);
      SLOTF(4); SLOTF(5); SLOTF(6); SLOTF(7);
    }
    if (tt + 0 < tm) STEPF(q0, r0);
    if (tt + 1 < tm) STEPF(q1, r1);
    if (tt + 2 < tm) STEPF(q2, r2);
    if (tt + 3 < tm) STEPF(q3, r3);
    if (tt + 4 < tm) STEPF(q4, r4);
    if (tt + 5 < tm) STEPF(q5, r5);
    if (tt + 6 < tm) STEPF(q6, r6);

    const float Ff = (float)F;
    const int sb = 8 * lane;
    Alog[sb + 0] = (a0 > 0.f) ? lg2(a0) + Ff : -1.0e30f;
    Alog[sb + 1] = (a1 > 0.f) ? lg2(a1) + Ff : -1.0e30f;
    Alog[sb + 2] = (a2 > 0.f) ? lg2(a2) + Ff : -1.0e30f;
    Alog[sb + 3] = (a3 > 0.f) ? lg2(a3) + Ff : -1.0e30f;
    Alog[sb + 4] = (a4 > 0.f) ? lg2(a4) + Ff : -1.0e30f;
    Alog[sb + 5] = (a5 > 0.f) ? lg2(a5) + Ff : -1.0e30f;
    Alog[sb + 6] = (a6 > 0.f) ? lg2(a6) + Ff : -1.0e30f;
    Alog[sb + 7] = (a7 > 0.f) ? lg2(a7) + Ff : -1.0e30f;
    if (lane == 63) Alog[512] = (at > 0.f) ? lg2(at) + Ff : -1.0e30f;
  } else {
    // ---------------- backward beta: rows Tb-1 .. tm ----------------
    const ushort4 uiv = gp[(size_t)(Tb - 1) * 64 + lane];
    const float bli = gb[2 * (Tb - 1) + lpar];
    ushort4 q0 = gp[(size_t)(Tb - 2) * 64 + lane], q1 = gp[(size_t)(Tb - 3) * 64 + lane];
    ushort4 q2 = gp[(size_t)(Tb - 4) * 64 + lane], q3 = gp[(size_t)(Tb - 5) * 64 + lane];
    ushort4 q4 = gp[(size_t)(Tb - 6) * 64 + lane], q5 = gp[(size_t)(Tb - 7) * 64 + lane];
    ushort4 q6 = gp[(size_t)(Tb - 8) * 64 + lane], q7 = gp[(size_t)(Tb - 9) * 64 + lane];
    float r0 = gb[2 * (Tb - 2) + lpar], r1 = gb[2 * (Tb - 3) + lpar];
    float r2 = gb[2 * (Tb - 4) + lpar], r3 = gb[2 * (Tb - 5) + lpar];
    float r4 = gb[2 * (Tb - 6) + lpar], r5 = gb[2 * (Tb - 7) + lpar];
    float r6 = gb[2 * (Tb - 8) + lpar], r7 = gb[2 * (Tb - 9) + lpar];

    const int sb = 8 * lane;
    float b0 = (sb + 0 == s_end || sb + 0 == s_end - 1) ? 1.f : 0.f;
    float b1 = (sb + 1 == s_end || sb + 1 == s_end - 1) ? 1.f : 0.f;
    float b2 = (sb + 2 == s_end || sb + 2 == s_end - 1) ? 1.f : 0.f;
    float b3 = (sb + 3 == s_end || sb + 3 == s_end - 1) ? 1.f : 0.f;
    float b4 = (sb + 4 == s_end || sb + 4 == s_end - 1) ? 1.f : 0.f;
    float b5 = (sb + 5 == s_end || sb + 5 == s_end - 1) ? 1.f : 0.f;
    float b6 = (sb + 6 == s_end || sb + 6 == s_end - 1) ? 1.f : 0.f;
    float b7 = (sb + 7 == s_end || sb + 7 == s_end - 1) ? 1.f : 0.f;
    float bt = (lane == 63 && s_end == 512) ? 1.f : 0.f;
    int F = 0, Fn_s = 0;

    float pb = bli;  // probs of row Tb-1 (first consumed)
    float p1 = bfu(uiv.x), p3 = bfu(uiv.y), p5 = bfu(uiv.z), p7 = bfu(uiv.w);
    float u0 = dpp_shl1_f(b0);
    float u1 = dpp_shl1_f(b1);
    float pn1 = dpp_shl1_f(p1);

    int tt = Tb - 1;
    for (; tt - 7 >= tm; tt -= 8) {
      SLOTB(0); SLOTB(1); SLOTB(2); SLOTB(3);
      SLOTB(4); SLOTB(5); SLOTB(6); SLOTB(7);
    }
    if (tt - 0 >= tm) STEPB(q0, r0);
    if (tt - 1 >= tm) STEPB(q1, r1);
    if (tt - 2 >= tm) STEPB(q2, r2);
    if (tt - 3 >= tm) STEPB(q3, r3);
    if (tt - 4 >= tm) STEPB(q4, r4);
    if (tt - 5 >= tm) STEPB(q5, r5);
    if (tt - 6 >= tm) STEPB(q6, r6);

    const float Ff = (float)F;
    Blog[sb + 0] = (b0 > 0.f) ? lg2(b0) + Ff : -1.0e30f;
    Blog[sb + 1] = (b1 > 0.f) ? lg2(b1) + Ff : -1.0e30f;
    Blog[sb + 2] = (b2 > 0.f) ? lg2(b2) + Ff : -1.0e30f;
    Blog[sb + 3] = (b3 > 0.f) ? lg2(b3) + Ff : -1.0e30f;
    Blog[sb + 4] = (b4 > 0.f) ? lg2(b4) + Ff : -1.0e30f;
    Blog[sb + 5] = (b5 > 0.f) ? lg2(b5) + Ff : -1.0e30f;
    Blog[sb + 6] = (b6 > 0.f) ? lg2(b6) + Ff : -1.0e30f;
    Blog[sb + 7] = (b7 > 0.f) ? lg2(b7) + Ff : -1.0e30f;
    if (lane == 63) Blog[512] = (bt > 0.f) ? lg2(bt) + Ff : -1.0e30f;
  }

  __syncthreads();

  if (wid == 0) {
    // log2 P = logsumexp2_s (Alog[s] + Blog[s])
    const int sb = 8 * lane;
    float t0 = Alog[sb + 0] + Blog[sb + 0];
    float t1 = Alog[sb + 1] + Blog[sb + 1];
    float t2 = Alog[sb + 2] + Blog[sb + 2];
    float t3 = Alog[sb + 3] + Blog[sb + 3];
    float t4 = Alog[sb + 4] + Blog[sb + 4];
    float t5 = Alog[sb + 5] + Blog[sb + 5];
    float t6 = Alog[sb + 6] + Blog[sb + 6];
    float t7 = Alog[sb + 7] + Blog[sb + 7];
    float t8 = (lane == 63) ? (Alog[512] + Blog[512]) : -1.0e30f;
    float M = fmaxf(fmaxf(fmaxf(t0, t1), fmaxf(t2, t3)),
                    fmaxf(fmaxf(t4, t5), fmaxf(fmaxf(t6, t7), t8)));
#pragma unroll
    for (int off = 32; off >= 1; off >>= 1) M = fmaxf(M, __shfl_xor(M, off));
    float sm = ex2(t0 - M) + ex2(t1 - M) + ex2(t2 - M) + ex2(t3 - M) +
               ex2(t4 - M) + ex2(t5 - M) + ex2(t6 - M) + ex2(t7 - M) +
               ex2(t8 - M);
#pragma unroll
    for (int off = 32; off >= 1; off >>= 1) sm += __shfl_xor(sm, off);
    if (lane == 0)
      out[b] = -0.6931471805599453f * (M + lg2(sm));
  }
}

extern "C" void kernel_launch(void* const* d_in, const int* in_sizes, int n_in,
                              void* d_out, int out_size, void* d_ws, size_t ws_size,
                              hipStream_t stream) {
  const int* labels = (const int*)d_in[0];
  const float* logits = (const float*)d_in[1];
  const int* widths = (const int*)d_in[2];
  const int* lengths = (const int*)d_in[3];
  float* out = (float*)d_out;

  // ws layout: [blanks2: B*T*2 fp32 = 512KB][packed: B*T*64 ushort4 = 32MB]
  float* blanks2 = (float*)d_ws;
  ushort4* packed = (ushort4*)((char*)d_ws + (size_t)B_ * T_ * 2 * sizeof(float));

  gather_pack<<<B_ * T_, 64, 0, stream>>>(logits, labels, blanks2, packed);
  ctc_dp<<<B_, 128, 0, stream>>>(packed, blanks2, labels, widths, lengths, out);
}

// Round 12
// 210.221 us; speedup vs baseline: 2.6193x; 1.1312x over previous
//
#include <hip/hip_runtime.h>
#include <math.h>

#define B_ 32
#define T_ 2048
#define C_ 96
#define L_ 256
#define BLANK 95

__device__ __forceinline__ float ex2(float x) {
  float r; asm("v_exp_f32 %0, %1" : "=v"(r) : "v"(x)); return r;
}
__device__ __forceinline__ float lg2(float x) {
  float r; asm("v_log_f32 %0, %1" : "=v"(r) : "v"(x)); return r;
}
__device__ __forceinline__ unsigned short f2bf(float f) {  // RNE f32->bf16
  unsigned u = __float_as_uint(f);
  return (unsigned short)((u + 0x7FFFu + ((u >> 16) & 1u)) >> 16);
}
__device__ __forceinline__ float bfu(unsigned short u) {
  return __uint_as_float((unsigned)u << 16);
}
// Wave shifts via DPP (VALU). 0x138 = WAVE_SHR1 (lane i <- lane i-1),
// 0x130 = WAVE_SHL1 (lane i <- lane i+1). old=0 -> boundary lane gets 0.
__device__ __forceinline__ float dpp_shr1_f(float x) {
  return __int_as_float(__builtin_amdgcn_update_dpp(
      0, __float_as_int(x), 0x138, 0xF, 0xF, false));
}
__device__ __forceinline__ int dpp_shr1_i(int x) {
  return __builtin_amdgcn_update_dpp(0, x, 0x138, 0xF, 0xF, false);
}
__device__ __forceinline__ float dpp_shl1_f(float x) {
  return __int_as_float(__builtin_amdgcn_update_dpp(
      0, __float_as_int(x), 0x130, 0xF, 0xF, false));
}
__device__ __forceinline__ int dpp_shl1_i(int x) {
  return __builtin_amdgcn_update_dpp(0, x, 0x130, 0xF, 0xF, false);
}

// ---- Kernel 1: fused softmax + per-lane label-prob gather/pack ----
__global__ __launch_bounds__(64) void gather_pack(const float* __restrict__ logits,
                                                  const int* __restrict__ labels,
                                                  float* __restrict__ blanks2,
                                                  ushort4* __restrict__ packed) {
  const int tid = threadIdx.x;
  const int bt = blockIdx.x;  // b*T + t
  const int b = bt >> 11;
  const float* xr = logits + (size_t)bt * C_;
  float xa = xr[tid];
  float xb = (tid < 32) ? xr[64 + tid] : -1.0e30f;
  float m = fmaxf(xa, xb);
#pragma unroll
  for (int off = 32; off >= 1; off >>= 1) m = fmaxf(m, __shfl_xor(m, off));
  float ea = __expf(xa - m);
  float eb = (tid < 32) ? __expf(xb - m) : 0.f;
  float z = ea + eb;
#pragma unroll
  for (int off = 32; off >= 1; off >>= 1) z += __shfl_xor(z, off);
  float rz = 1.0f / z;
  __shared__ float sp[C_];
  sp[tid] = fmaf(ea, rz, 1e-7f);
  if (tid < 32) sp[64 + tid] = fmaf(eb, rz, 1e-7f);
  __syncthreads();
  const int4 lb = *reinterpret_cast<const int4*>(labels + (b << 8) + 4 * tid);
  ushort4 o;
  o.x = f2bf(sp[lb.x]); o.y = f2bf(sp[lb.y]);
  o.z = f2bf(sp[lb.z]); o.w = f2bf(sp[lb.w]);
  packed[(size_t)bt * 64 + tid] = o;
  if (tid < 2) blanks2[2 * bt + tid] = sp[BLANK];
}

// ---------------- Kernel 2: meet-in-the-middle CTC DP ----------------
// One 128-thread block per batch. Wave 0: alpha forward; wave 1: beta
// backward; join P = sum_s A[tm-1][s]*B[tm-1][s]. Per-lane 2^F frames.
// Pin every 2nd step (p<=1 => growth only via inflow <= 2^25; safety
// induction: all transients < 2^90). Sends mantissa-normalized (<2).
// No dead special case: shift=max(di-24,0) revives dead lanes exactly
// (inflow enters <=2^25, next pin renormalizes; dead F drifts -60/pin).
// Rebase branch: frames of adjacent lanes track within ~11 bits, so
// shift!=0 is rare -> skip the 9 ldexp most steps.

#define REBASE_A() do { if (__any(shift)) {                                  \
      a0 = ldexpf(a0, -shift); a1 = ldexpf(a1, -shift);                      \
      a2 = ldexpf(a2, -shift); a3 = ldexpf(a3, -shift);                      \
      a4 = ldexpf(a4, -shift); a5 = ldexpf(a5, -shift);                      \
      a6 = ldexpf(a6, -shift); a7 = ldexpf(a7, -shift);                      \
      at = ldexpf(at, -shift); } } while (0)

#define STEPF_O(QU, QB) do {                                                 \
    int di = Fp_s - F;                                                       \
    di = (b1_raw > 0.f) ? di : 0;                                            \
    const int shift = (di > 24) ? (di - 24) : 0;                             \
    REBASE_A();                                                              \
    F += shift;                                                              \
    const float b1a = ldexpf(b1_raw, di - shift);                            \
    const float na7 = fmaf(m7, a5, a7 + a6) * p7;                            \
    const int en = (int)((__float_as_uint(na7) >> 23) & 255u) - 126;         \
    const float mant = ldexpf(na7, -en);                                     \
    const float b1n = dpp_shr1_f(mant);                                      \
    const int Fp_n = dpp_shr1_i(F + en);                                     \
    at = (at + a7) * pb;                                                     \
    a6 = (a6 + a5) * pb;                                                     \
    a5 = fmaf(m5, a3, a5 + a4) * p5;                                         \
    a4 = (a4 + a3) * pb;                                                     \
    a3 = fmaf(m3, a1, a3 + a2) * p3;                                         \
    a2 = (a2 + a1) * pb;                                                     \
    a1 = fmaf(m1, b1a, a1 + a0) * p1;                                        \
    a0 = (a0 + b1a) * pb;                                                    \
    a7 = na7;                                                                \
    b1_raw = b1n; Fp_s = Fp_n;                                               \
    p1 = bfu((QU).x); p3 = bfu((QU).y); p5 = bfu((QU).z); p7 = bfu((QU).w);  \
    pb = (QB);                                                               \
  } while (0)

#define STEPF_P(QU, QB) do {                                                 \
    const float mA = fmaxf(fmaxf(a0, a1), a2);                               \
    const float mB = fmaxf(fmaxf(a3, a4), a5);                               \
    const float mC = fmaxf(fmaxf(a6, a7), at);                               \
    const float m8 = fmaxf(fmaxf(mA, mB), mC);                               \
    int e_cur = (int)((__float_as_uint(m8) >> 23) & 255u) - 126;             \
    e_cur = (e_cur < -60) ? -60 : e_cur;                                     \
    const float scl = ldexpf(1.0f, -e_cur);                                  \
    int di = Fp_s - F;                                                       \
    di = (b1_raw > 0.f) ? di : 0;                                            \
    const int shift = (di > 24) ? (di - 24) : 0;                             \
    REBASE_A();                                                              \
    F += shift + e_cur;                                                      \
    const float b1a = ldexpf(b1_raw, di - shift);                            \
    const float PB = pb * scl, P1 = p1 * scl, P3 = p3 * scl,                 \
                P5 = p5 * scl, P7 = p7 * scl;                                \
    const float na7 = fmaf(m7, a5, a7 + a6) * P7;                            \
    const int en = (int)((__float_as_uint(na7) >> 23) & 255u) - 126;         \
    const float mant = ldexpf(na7, -en);                                     \
    const float b1n = dpp_shr1_f(mant);                                      \
    const int Fp_n = dpp_shr1_i(F + en);                                     \
    at = (at + a7) * PB;                                                     \
    a6 = (a6 + a5) * PB;                                                     \
    a5 = fmaf(m5, a3, a5 + a4) * P5;                                         \
    a4 = (a4 + a3) * PB;                                                     \
    a3 = fmaf(m3, a1, a3 + a2) * P3;                                         \
    a2 = (a2 + a1) * PB;                                                     \
    a1 = fmaf(m1, b1a, a1 + a0) * P1;                                        \
    a0 = (a0 + b1a) * PB;                                                    \
    a7 = na7;                                                                \
    b1_raw = b1n; Fp_s = Fp_n;                                               \
    p1 = bfu((QU).x); p3 = bfu((QU).y); p5 = bfu((QU).z); p7 = bfu((QU).w);  \
    pb = (QB);                                                               \
  } while (0)

#define SLOTF(U, SM) do {                                                    \
    SM(q##U, r##U);                                                          \
    int trow = tt + 9 + U;                                                   \
    trow = (trow > T_ - 1) ? (T_ - 1) : trow;                                \
    q##U = gp[(size_t)trow * 64 + lane];                                     \
    r##U = gb[2 * trow + lpar];                                              \
  } while (0)

#define REBASE_B() do { if (__any(shift)) {                                  \
      b0 = ldexpf(b0, -shift); b1 = ldexpf(b1, -shift);                      \
      b2 = ldexpf(b2, -shift); b3 = ldexpf(b3, -shift);                      \
      b4 = ldexpf(b4, -shift); b5 = ldexpf(b5, -shift);                      \
      b6 = ldexpf(b6, -shift); b7 = ldexpf(b7, -shift);                      \
      bt = ldexpf(bt, -shift); } } while (0)

#define STEPB_O(QU, QB) do {                                                 \
    int di = Fn_s - F;                                                       \
    di = (fmaxf(u0, u1) > 0.f) ? di : 0;                                     \
    const int shift = (di > 24) ? (di - 24) : 0;                             \
    REBASE_B();                                                              \
    F += shift;                                                              \
    const int sh2 = di - shift;                                              \
    const float e0r = ldexpf(u0, sh2), e1r = ldexpf(u1, sh2);                \
    const float bp0 = b0 * pb, bp1 = b1 * p1, bp2 = b2 * pb, bp3 = b3 * p3,  \
                bp4 = b4 * pb, bp5 = b5 * p5, bp6 = b6 * pb, bp7 = b7 * p7,  \
                bpt = bt * pb;                                               \
    const float e0e = (lane == 63) ? bt : e0r;                               \
    const float bp8 = e0e * pb;                                              \
    const float bp9 = e1r * pn1;                                             \
    const float nb0 = bp0 + bp1;                                             \
    const float nb1 = fmaf(m3, bp3, bp1 + bp2);                              \
    const float mx01 = fmaxf(nb0, nb1);                                      \
    const int en = (int)((__float_as_uint(mx01) >> 23) & 255u) - 126;        \
    const float u0n = dpp_shl1_f(ldexpf(nb0, -en));                          \
    const float u1n = dpp_shl1_f(ldexpf(nb1, -en));                          \
    const int Fn_n = dpp_shl1_i(F + en);                                     \
    b2 = bp2 + bp3;                                                          \
    b3 = fmaf(m5, bp5, bp3 + bp4);                                           \
    b4 = bp4 + bp5;                                                          \
    b5 = fmaf(m7, bp7, bp5 + bp6);                                           \
    b6 = bp6 + bp7;                                                          \
    b7 = fmaf(mn, bp9, bp7 + bp8);                                           \
    bt = bpt;                                                                \
    b0 = nb0; b1 = nb1;                                                      \
    u0 = u0n; u1 = u1n; Fn_s = Fn_n;                                         \
    p1 = bfu((QU).x); p3 = bfu((QU).y); p5 = bfu((QU).z); p7 = bfu((QU).w);  \
    pb = (QB);                                                               \
    pn1 = dpp_shl1_f(p1);                                                    \
  } while (0)

#define STEPB_P(QU, QB) do {                                                 \
    const float mA = fmaxf(fmaxf(b0, b1), b2);                               \
    const float mB = fmaxf(fmaxf(b3, b4), b5);                               \
    const float mC = fmaxf(fmaxf(b6, b7), bt);                               \
    const float m8 = fmaxf(fmaxf(mA, mB), mC);                               \
    int e_cur = (int)((__float_as_uint(m8) >> 23) & 255u) - 126;             \
    e_cur = (e_cur < -60) ? -60 : e_cur;                                     \
    const float scl = ldexpf(1.0f, -e_cur);                                  \
    int di = Fn_s - F;                                                       \
    di = (fmaxf(u0, u1) > 0.f) ? di : 0;                                     \
    const int shift = (di > 24) ? (di - 24) : 0;                             \
    REBASE_B();                                                              \
    F += shift + e_cur;                                                      \
    const int sh2 = di - shift;                                              \
    const float e0r = ldexpf(u0, sh2), e1r = ldexpf(u1, sh2);                \
    const float PB = pb * scl, P1 = p1 * scl, P3 = p3 * scl,                 \
                P5 = p5 * scl, P7 = p7 * scl, PN = pn1 * scl;                \
    const float bp0 = b0 * PB, bp1 = b1 * P1, bp2 = b2 * PB, bp3 = b3 * P3,  \
                bp4 = b4 * PB, bp5 = b5 * P5, bp6 = b6 * PB, bp7 = b7 * P7,  \
                bpt = bt * PB;                                               \
    const float e0e = (lane == 63) ? bt : e0r;                               \
    const float bp8 = e0e * PB;                                              \
    const float bp9 = e1r * PN;                                              \
    const float nb0 = bp0 + bp1;                                             \
    const float nb1 = fmaf(m3, bp3, bp1 + bp2);                              \
    const float mx01 = fmaxf(nb0, nb1);                                      \
    const int en = (int)((__float_as_uint(mx01) >> 23) & 255u) - 126;        \
    const float u0n = dpp_shl1_f(ldexpf(nb0, -en));                          \
    const float u1n = dpp_shl1_f(ldexpf(nb1, -en));                          \
    const int Fn_n = dpp_shl1_i(F + en);                                     \
    b2 = bp2 + bp3;                                                          \
    b3 = fmaf(m5, bp5, bp3 + bp4);                                           \
    b4 = bp4 + bp5;                                                          \
    b5 = fmaf(m7, bp7, bp5 + bp6);                                           \
    b6 = bp6 + bp7;                                                          \
    b7 = fmaf(mn, bp9, bp7 + bp8);                                           \
    bt = bpt;                                                                \
    b0 = nb0; b1 = nb1;                                                      \
    u0 = u0n; u1 = u1n; Fn_s = Fn_n;                                         \
    p1 = bfu((QU).x); p3 = bfu((QU).y); p5 = bfu((QU).z); p7 = bfu((QU).w);  \
    pb = (QB);                                                               \
    pn1 = dpp_shl1_f(p1);                                                    \
  } while (0)

#define SLOTB(U, SM) do {                                                    \
    SM(q##U, r##U);                                                          \
    int trow = tt - 9 - U;                                                   \
    trow = (trow < 0) ? 0 : trow;                                            \
    q##U = gp[(size_t)trow * 64 + lane];                                     \
    r##U = gb[2 * trow + lpar];                                              \
  } while (0)

__global__ __launch_bounds__(128) void ctc_dp(const ushort4* __restrict__ packed,
                                              const float* __restrict__ blanks2,
                                              const int* __restrict__ labels,
                                              const int* __restrict__ widths,
                                              const int* __restrict__ lengths,
                                              float* __restrict__ out) {
  __shared__ float Alog[513];
  __shared__ float Blog[513];
  const int b = blockIdx.x;
  const int tid = threadIdx.x;
  const int wid = tid >> 6;
  const int lane = tid & 63;
  const int lpar = lane & 1;
  const int Tb = widths[b] >> 3;     // in [1536, 2048]
  const int s_end = 2 * lengths[b];
  const int tm = (Tb * 67) >> 7;     // meet row (fwd/bwd cost-balanced)
  const int* lab = labels + (b << 8);
  const int4 lb = *reinterpret_cast<const int4*>(lab + 4 * lane);
  const int pw = __shfl_up(lb.w, 1);
  const float m1 = (lane > 0 && lb.x != pw) ? 1.f : 0.f;
  const float m3 = (lb.y != lb.x) ? 1.f : 0.f;
  const float m5 = (lb.z != lb.y) ? 1.f : 0.f;
  const float m7 = (lb.w != lb.z) ? 1.f : 0.f;
  const float mdn = __shfl_down(m1, 1);
  const float mn = (lane == 63) ? 0.f : mdn;  // skip mask for s+2 = 8l+9

  const ushort4* gp = packed + (size_t)b * (T_ * 64);
  const float* gb = blanks2 + b * (2 * T_);

  if (wid == 0) {
    // ---------------- forward alpha: rows 0 .. tm-1 ----------------
    const ushort4 u0v = gp[lane];
    const float bl0 = gb[lpar];
    const ushort4 u1v = gp[64 + lane];
    const float bl1 = gb[2 + lpar];
    ushort4 q0 = gp[2 * 64 + lane], q1 = gp[3 * 64 + lane];
    ushort4 q2 = gp[4 * 64 + lane], q3 = gp[5 * 64 + lane];
    ushort4 q4 = gp[6 * 64 + lane], q5 = gp[7 * 64 + lane];
    ushort4 q6 = gp[8 * 64 + lane], q7 = gp[9 * 64 + lane];
    float r0 = gb[2 * 2 + lpar], r1 = gb[2 * 3 + lpar];
    float r2 = gb[2 * 4 + lpar], r3 = gb[2 * 5 + lpar];
    float r4 = gb[2 * 6 + lpar], r5 = gb[2 * 7 + lpar];
    float r6 = gb[2 * 8 + lpar], r7 = gb[2 * 9 + lpar];

    float a0 = 0.f, a1 = 0.f, a2 = 0.f, a3 = 0.f;
    float a4 = 0.f, a5 = 0.f, a6 = 0.f, a7 = 0.f, at = 0.f;
    int F = 0, Fp_s = 0;
    float b1_raw = 0.f;
    if (lane == 0) { a0 = bl0; a1 = bfu(u0v.x); }
    float pb = bl1;
    float p1 = bfu(u1v.x), p3 = bfu(u1v.y), p5 = bfu(u1v.z), p7 = bfu(u1v.w);

    int tt = 1;
    for (; tt + 8 <= tm; tt += 8) {
      SLOTF(0, STEPF_O); SLOTF(1, STEPF_P);
      SLOTF(2, STEPF_O); SLOTF(3, STEPF_P);
      SLOTF(4, STEPF_O); SLOTF(5, STEPF_P);
      SLOTF(6, STEPF_O); SLOTF(7, STEPF_P);
    }
    if (tt + 0 < tm) STEPF_P(q0, r0);
    if (tt + 1 < tm) STEPF_P(q1, r1);
    if (tt + 2 < tm) STEPF_P(q2, r2);
    if (tt + 3 < tm) STEPF_P(q3, r3);
    if (tt + 4 < tm) STEPF_P(q4, r4);
    if (tt + 5 < tm) STEPF_P(q5, r5);
    if (tt + 6 < tm) STEPF_P(q6, r6);

    const float Ff = (float)F;
    const int sb = 8 * lane;
    Alog[sb + 0] = (a0 > 0.f) ? lg2(a0) + Ff : -1.0e30f;
    Alog[sb + 1] = (a1 > 0.f) ? lg2(a1) + Ff : -1.0e30f;
    Alog[sb + 2] = (a2 > 0.f) ? lg2(a2) + Ff : -1.0e30f;
    Alog[sb + 3] = (a3 > 0.f) ? lg2(a3) + Ff : -1.0e30f;
    Alog[sb + 4] = (a4 > 0.f) ? lg2(a4) + Ff : -1.0e30f;
    Alog[sb + 5] = (a5 > 0.f) ? lg2(a5) + Ff : -1.0e30f;
    Alog[sb + 6] = (a6 > 0.f) ? lg2(a6) + Ff : -1.0e30f;
    Alog[sb + 7] = (a7 > 0.f) ? lg2(a7) + Ff : -1.0e30f;
    if (lane == 63) Alog[512] = (at > 0.f) ? lg2(at) + Ff : -1.0e30f;
  } else {
    // ---------------- backward beta: rows Tb-1 .. tm ----------------
    const ushort4 uiv = gp[(size_t)(Tb - 1) * 64 + lane];
    const float bli = gb[2 * (Tb - 1) + lpar];
    ushort4 q0 = gp[(size_t)(Tb - 2) * 64 + lane], q1 = gp[(size_t)(Tb - 3) * 64 + lane];
    ushort4 q2 = gp[(size_t)(Tb - 4) * 64 + lane], q3 = gp[(size_t)(Tb - 5) * 64 + lane];
    ushort4 q4 = gp[(size_t)(Tb - 6) * 64 + lane], q5 = gp[(size_t)(Tb - 7) * 64 + lane];
    ushort4 q6 = gp[(size_t)(Tb - 8) * 64 + lane], q7 = gp[(size_t)(Tb - 9) * 64 + lane];
    float r0 = gb[2 * (Tb - 2) + lpar], r1 = gb[2 * (Tb - 3) + lpar];
    float r2 = gb[2 * (Tb - 4) + lpar], r3 = gb[2 * (Tb - 5) + lpar];
    float r4 = gb[2 * (Tb - 6) + lpar], r5 = gb[2 * (Tb - 7) + lpar];
    float r6 = gb[2 * (Tb - 8) + lpar], r7 = gb[2 * (Tb - 9) + lpar];

    const int sb = 8 * lane;
    float b0 = (sb + 0 == s_end || sb + 0 == s_end - 1) ? 1.f : 0.f;
    float b1 = (sb + 1 == s_end || sb + 1 == s_end - 1) ? 1.f : 0.f;
    float b2 = (sb + 2 == s_end || sb + 2 == s_end - 1) ? 1.f : 0.f;
    float b3 = (sb + 3 == s_end || sb + 3 == s_end - 1) ? 1.f : 0.f;
    float b4 = (sb + 4 == s_end || sb + 4 == s_end - 1) ? 1.f : 0.f;
    float b5 = (sb + 5 == s_end || sb + 5 == s_end - 1) ? 1.f : 0.f;
    float b6 = (sb + 6 == s_end || sb + 6 == s_end - 1) ? 1.f : 0.f;
    float b7 = (sb + 7 == s_end || sb + 7 == s_end - 1) ? 1.f : 0.f;
    float bt = (lane == 63 && s_end == 512) ? 1.f : 0.f;
    int F = 0, Fn_s = 0;

    float pb = bli;  // probs of row Tb-1 (first consumed)
    float p1 = bfu(uiv.x), p3 = bfu(uiv.y), p5 = bfu(uiv.z), p7 = bfu(uiv.w);
    float u0 = dpp_shl1_f(b0);
    float u1 = dpp_shl1_f(b1);
    float pn1 = dpp_shl1_f(p1);

    int tt = Tb - 1;
    for (; tt - 7 >= tm; tt -= 8) {
      SLOTB(0, STEPB_O); SLOTB(1, STEPB_P);
      SLOTB(2, STEPB_O); SLOTB(3, STEPB_P);
      SLOTB(4, STEPB_O); SLOTB(5, STEPB_P);
      SLOTB(6, STEPB_O); SLOTB(7, STEPB_P);
    }
    if (tt - 0 >= tm) STEPB_P(q0, r0);
    if (tt - 1 >= tm) STEPB_P(q1, r1);
    if (tt - 2 >= tm) STEPB_P(q2, r2);
    if (tt - 3 >= tm) STEPB_P(q3, r3);
    if (tt - 4 >= tm) STEPB_P(q4, r4);
    if (tt - 5 >= tm) STEPB_P(q5, r5);
    if (tt - 6 >= tm) STEPB_P(q6, r6);

    const float Ff = (float)F;
    Blog[sb + 0] = (b0 > 0.f) ? lg2(b0) + Ff : -1.0e30f;
    Blog[sb + 1] = (b1 > 0.f) ? lg2(b1) + Ff : -1.0e30f;
    Blog[sb + 2] = (b2 > 0.f) ? lg2(b2) + Ff : -1.0e30f;
    Blog[sb + 3] = (b3 > 0.f) ? lg2(b3) + Ff : -1.0e30f;
    Blog[sb + 4] = (b4 > 0.f) ? lg2(b4) + Ff : -1.0e30f;
    Blog[sb + 5] = (b5 > 0.f) ? lg2(b5) + Ff : -1.0e30f;
    Blog[sb + 6] = (b6 > 0.f) ? lg2(b6) + Ff : -1.0e30f;
    Blog[sb + 7] = (b7 > 0.f) ? lg2(b7) + Ff : -1.0e30f;
    if (lane == 63) Blog[512] = (bt > 0.f) ? lg2(bt) + Ff : -1.0e30f;
  }

  __syncthreads();

  if (wid == 0) {
    // log2 P = logsumexp2_s (Alog[s] + Blog[s])
    const int sb = 8 * lane;
    float t0 = Alog[sb + 0] + Blog[sb + 0];
    float t1 = Alog[sb + 1] + Blog[sb + 1];
    float t2 = Alog[sb + 2] + Blog[sb + 2];
    float t3 = Alog[sb + 3] + Blog[sb + 3];
    float t4 = Alog[sb + 4] + Blog[sb + 4];
    float t5 = Alog[sb + 5] + Blog[sb + 5];
    float t6 = Alog[sb + 6] + Blog[sb + 6];
    float t7 = Alog[sb + 7] + Blog[sb + 7];
    float t8 = (lane == 63) ? (Alog[512] + Blog[512]) : -1.0e30f;
    float M = fmaxf(fmaxf(fmaxf(t0, t1), fmaxf(t2, t3)),
                    fmaxf(fmaxf(t4, t5), fmaxf(fmaxf(t6, t7), t8)));
#pragma unroll
    for (int off = 32; off >= 1; off >>= 1) M = fmaxf(M, __shfl_xor(M, off));
    float sm = ex2(t0 - M) + ex2(t1 - M) + ex2(t2 - M) + ex2(t3 - M) +
               ex2(t4 - M) + ex2(t5 - M) + ex2(t6 - M) + ex2(t7 - M) +
               ex2(t8 - M);
#pragma unroll
    for (int off = 32; off >= 1; off >>= 1) sm += __shfl_xor(sm, off);
    if (lane == 0)
      out[b] = -0.6931471805599453f * (M + lg2(sm));
  }
}

extern "C" void kernel_launch(void* const* d_in, const int* in_sizes, int n_in,
                              void* d_out, int out_size, void* d_ws, size_t ws_size,
                              hipStream_t stream) {
  const int* labels = (const int*)d_in[0];
  const float* logits = (const float*)d_in[1];
  const int* widths = (const int*)d_in[2];
  const int* lengths = (const int*)d_in[3];
  float* out = (float*)d_out;

  // ws layout: [blanks2: B*T*2 fp32 = 512KB][packed: B*T*64 ushort4 = 32MB]
  float* blanks2 = (float*)d_ws;
  ushort4* packed = (ushort4*)((char*)d_ws + (size_t)B_ * T_ * 2 * sizeof(float));

  gather_pack<<<B_ * T_, 64, 0, stream>>>(logits, labels, blanks2, packed);
  ctc_dp<<<B_, 128, 0, stream>>>(packed, blanks2, labels, widths, lengths, out);
}

// Round 13
// 207.257 us; speedup vs baseline: 2.6567x; 1.0143x over previous
//
#include <hip/hip_runtime.h>
#include <math.h>

#define B_ 32
#define T_ 2048
#define C_ 96
#define L_ 256
#define BLANK 95

__device__ __forceinline__ float ex2(float x) {
  float r; asm("v_exp_f32 %0, %1" : "=v"(r) : "v"(x)); return r;
}
__device__ __forceinline__ float lg2(float x) {
  float r; asm("v_log_f32 %0, %1" : "=v"(r) : "v"(x)); return r;
}
__device__ __forceinline__ unsigned short f2bf(float f) {  // RNE f32->bf16
  unsigned u = __float_as_uint(f);
  return (unsigned short)((u + 0x7FFFu + ((u >> 16) & 1u)) >> 16);
}
__device__ __forceinline__ float bfu(unsigned short u) {
  return __uint_as_float((unsigned)u << 16);
}
// Wave shifts via DPP (VALU). 0x138 = WAVE_SHR1 (lane i <- lane i-1),
// 0x130 = WAVE_SHL1 (lane i <- lane i+1). old=0 -> boundary lane gets 0.
__device__ __forceinline__ float dpp_shr1_f(float x) {
  return __int_as_float(__builtin_amdgcn_update_dpp(
      0, __float_as_int(x), 0x138, 0xF, 0xF, false));
}
__device__ __forceinline__ int dpp_shr1_i(int x) {
  return __builtin_amdgcn_update_dpp(0, x, 0x138, 0xF, 0xF, false);
}
__device__ __forceinline__ float dpp_shl1_f(float x) {
  return __int_as_float(__builtin_amdgcn_update_dpp(
      0, __float_as_int(x), 0x130, 0xF, 0xF, false));
}
__device__ __forceinline__ int dpp_shl1_i(int x) {
  return __builtin_amdgcn_update_dpp(0, x, 0x130, 0xF, 0xF, false);
}

// ---- Kernel 1: fused softmax + per-lane label-prob gather/pack ----
__global__ __launch_bounds__(64) void gather_pack(const float* __restrict__ logits,
                                                  const int* __restrict__ labels,
                                                  float* __restrict__ blanks2,
                                                  ushort4* __restrict__ packed) {
  const int tid = threadIdx.x;
  const int bt = blockIdx.x;  // b*T + t
  const int b = bt >> 11;
  const float* xr = logits + (size_t)bt * C_;
  float xa = xr[tid];
  float xb = (tid < 32) ? xr[64 + tid] : -1.0e30f;
  float m = fmaxf(xa, xb);
#pragma unroll
  for (int off = 32; off >= 1; off >>= 1) m = fmaxf(m, __shfl_xor(m, off));
  float ea = __expf(xa - m);
  float eb = (tid < 32) ? __expf(xb - m) : 0.f;
  float z = ea + eb;
#pragma unroll
  for (int off = 32; off >= 1; off >>= 1) z += __shfl_xor(z, off);
  float rz = 1.0f / z;
  __shared__ float sp[C_];
  sp[tid] = fmaf(ea, rz, 1e-7f);
  if (tid < 32) sp[64 + tid] = fmaf(eb, rz, 1e-7f);
  __syncthreads();
  const int4 lb = *reinterpret_cast<const int4*>(labels + (b << 8) + 4 * tid);
  ushort4 o;
  o.x = f2bf(sp[lb.x]); o.y = f2bf(sp[lb.y]);
  o.z = f2bf(sp[lb.z]); o.w = f2bf(sp[lb.w]);
  packed[(size_t)bt * 64 + tid] = o;
  if (tid < 2) blanks2[2 * bt + tid] = sp[BLANK];
}

// ---------------- Kernel 2: meet-in-the-middle CTC DP ----------------
// One 128-thread block per batch. Wave 0: alpha forward; wave 1: beta
// backward; join P = sum_s A[tm-1][s]*B[tm-1][s]. Per-lane 2^F frames.
// Pin every 2nd step; sends mantissa-normalized (<2); shift=max(di-24,0)
// revives dead lanes exactly. STEP BODY IS 100% BRANCH-FREE: the rebase
// is unconditional (9 parallel v_ldexp, exact at shift=0) so the compiler
// never sees a control-flow join inside the hot loop (conservative
// waitcnt-at-join was the suspected fixed ~440cyc/step cost).

#define REBASE_A() do {                                                      \
      a0 = ldexpf(a0, -shift); a1 = ldexpf(a1, -shift);                      \
      a2 = ldexpf(a2, -shift); a3 = ldexpf(a3, -shift);                      \
      a4 = ldexpf(a4, -shift); a5 = ldexpf(a5, -shift);                      \
      a6 = ldexpf(a6, -shift); a7 = ldexpf(a7, -shift);                      \
      at = ldexpf(at, -shift); } while (0)

#define STEPF_O(QU, QB) do {                                                 \
    int di = Fp_s - F;                                                       \
    di = (b1_raw > 0.f) ? di : 0;                                            \
    const int shift = (di > 24) ? (di - 24) : 0;                             \
    REBASE_A();                                                              \
    F += shift;                                                              \
    const float b1a = ldexpf(b1_raw, di - shift);                            \
    const float na7 = fmaf(m7, a5, a7 + a6) * p7;                            \
    const int en = (int)((__float_as_uint(na7) >> 23) & 255u) - 126;         \
    const float mant = ldexpf(na7, -en);                                     \
    const float b1n = dpp_shr1_f(mant);                                      \
    const int Fp_n = dpp_shr1_i(F + en);                                     \
    at = (at + a7) * pb;                                                     \
    a6 = (a6 + a5) * pb;                                                     \
    a5 = fmaf(m5, a3, a5 + a4) * p5;                                         \
    a4 = (a4 + a3) * pb;                                                     \
    a3 = fmaf(m3, a1, a3 + a2) * p3;                                         \
    a2 = (a2 + a1) * pb;                                                     \
    a1 = fmaf(m1, b1a, a1 + a0) * p1;                                        \
    a0 = (a0 + b1a) * pb;                                                    \
    a7 = na7;                                                                \
    b1_raw = b1n; Fp_s = Fp_n;                                               \
    p1 = bfu((QU).x); p3 = bfu((QU).y); p5 = bfu((QU).z); p7 = bfu((QU).w);  \
    pb = (QB);                                                               \
  } while (0)

#define STEPF_P(QU, QB) do {                                                 \
    const float mA = fmaxf(fmaxf(a0, a1), a2);                               \
    const float mB = fmaxf(fmaxf(a3, a4), a5);                               \
    const float mC = fmaxf(fmaxf(a6, a7), at);                               \
    const float m8 = fmaxf(fmaxf(mA, mB), mC);                               \
    int e_cur = (int)((__float_as_uint(m8) >> 23) & 255u) - 126;             \
    e_cur = (e_cur < -60) ? -60 : e_cur;                                     \
    const float scl = ldexpf(1.0f, -e_cur);                                  \
    int di = Fp_s - F;                                                       \
    di = (b1_raw > 0.f) ? di : 0;                                            \
    const int shift = (di > 24) ? (di - 24) : 0;                             \
    REBASE_A();                                                              \
    F += shift + e_cur;                                                      \
    const float b1a = ldexpf(b1_raw, di - shift);                            \
    const float PB = pb * scl, P1 = p1 * scl, P3 = p3 * scl,                 \
                P5 = p5 * scl, P7 = p7 * scl;                                \
    const float na7 = fmaf(m7, a5, a7 + a6) * P7;                            \
    const int en = (int)((__float_as_uint(na7) >> 23) & 255u) - 126;         \
    const float mant = ldexpf(na7, -en);                                     \
    const float b1n = dpp_shr1_f(mant);                                      \
    const int Fp_n = dpp_shr1_i(F + en);                                     \
    at = (at + a7) * PB;                                                     \
    a6 = (a6 + a5) * PB;                                                     \
    a5 = fmaf(m5, a3, a5 + a4) * P5;                                         \
    a4 = (a4 + a3) * PB;                                                     \
    a3 = fmaf(m3, a1, a3 + a2) * P3;                                         \
    a2 = (a2 + a1) * PB;                                                     \
    a1 = fmaf(m1, b1a, a1 + a0) * P1;                                        \
    a0 = (a0 + b1a) * PB;                                                    \
    a7 = na7;                                                                \
    b1_raw = b1n; Fp_s = Fp_n;                                               \
    p1 = bfu((QU).x); p3 = bfu((QU).y); p5 = bfu((QU).z); p7 = bfu((QU).w);  \
    pb = (QB);                                                               \
  } while (0)

#define SLOTF(U, SM) do {                                                    \
    SM(q##U, r##U);                                                          \
    int trow = tt + 9 + U;                                                   \
    trow = (trow > T_ - 1) ? (T_ - 1) : trow;                                \
    q##U = gp[(size_t)trow * 64 + lane];                                     \
    r##U = gb[2 * trow + lpar];                                              \
  } while (0)

#define REBASE_B() do {                                                      \
      b0 = ldexpf(b0, -shift); b1 = ldexpf(b1, -shift);                      \
      b2 = ldexpf(b2, -shift); b3 = ldexpf(b3, -shift);                      \
      b4 = ldexpf(b4, -shift); b5 = ldexpf(b5, -shift);                      \
      b6 = ldexpf(b6, -shift); b7 = ldexpf(b7, -shift);                      \
      bt = ldexpf(bt, -shift); } while (0)

#define STEPB_O(QU, QB) do {                                                 \
    int di = Fn_s - F;                                                       \
    di = (fmaxf(u0, u1) > 0.f) ? di : 0;                                     \
    const int shift = (di > 24) ? (di - 24) : 0;                             \
    REBASE_B();                                                              \
    F += shift;                                                              \
    const int sh2 = di - shift;                                              \
    const float e0r = ldexpf(u0, sh2), e1r = ldexpf(u1, sh2);                \
    const float bp0 = b0 * pb, bp1 = b1 * p1, bp2 = b2 * pb, bp3 = b3 * p3,  \
                bp4 = b4 * pb, bp5 = b5 * p5, bp6 = b6 * pb, bp7 = b7 * p7,  \
                bpt = bt * pb;                                               \
    const float e0e = (lane == 63) ? bt : e0r;                               \
    const float bp8 = e0e * pb;                                              \
    const float bp9 = e1r * pn1;                                             \
    const float nb0 = bp0 + bp1;                                             \
    const float nb1 = fmaf(m3, bp3, bp1 + bp2);                              \
    const float mx01 = fmaxf(nb0, nb1);                                      \
    const int en = (int)((__float_as_uint(mx01) >> 23) & 255u) - 126;        \
    const float u0n = dpp_shl1_f(ldexpf(nb0, -en));                          \
    const float u1n = dpp_shl1_f(ldexpf(nb1, -en));                          \
    const int Fn_n = dpp_shl1_i(F + en);                                     \
    b2 = bp2 + bp3;                                                          \
    b3 = fmaf(m5, bp5, bp3 + bp4);                                           \
    b4 = bp4 + bp5;                                                          \
    b5 = fmaf(m7, bp7, bp5 + bp6);                                           \
    b6 = bp6 + bp7;                                                          \
    b7 = fmaf(mn, bp9, bp7 + bp8);                                           \
    bt = bpt;                                                                \
    b0 = nb0; b1 = nb1;                                                      \
    u0 = u0n; u1 = u1n; Fn_s = Fn_n;                                         \
    p1 = bfu((QU).x); p3 = bfu((QU).y); p5 = bfu((QU).z); p7 = bfu((QU).w);  \
    pb = (QB);                                                               \
    pn1 = dpp_shl1_f(p1);                                                    \
  } while (0)

#define STEPB_P(QU, QB) do {                                                 \
    const float mA = fmaxf(fmaxf(b0, b1), b2);                               \
    const float mB = fmaxf(fmaxf(b3, b4), b5);                               \
    const float mC = fmaxf(fmaxf(b6, b7), bt);                               \
    const float m8 = fmaxf(fmaxf(mA, mB), mC);                               \
    int e_cur = (int)((__float_as_uint(m8) >> 23) & 255u) - 126;             \
    e_cur = (e_cur < -60) ? -60 : e_cur;                                     \
    const float scl = ldexpf(1.0f, -e_cur);                                  \
    int di = Fn_s - F;                                                       \
    di = (fmaxf(u0, u1) > 0.f) ? di : 0;                                     \
    const int shift = (di > 24) ? (di - 24) : 0;                             \
    REBASE_B();                                                              \
    F += shift + e_cur;                                                      \
    const int sh2 = di - shift;                                              \
    const float e0r = ldexpf(u0, sh2), e1r = ldexpf(u1, sh2);                \
    const float PB = pb * scl, P1 = p1 * scl, P3 = p3 * scl,                 \
                P5 = p5 * scl, P7 = p7 * scl, PN = pn1 * scl;                \
    const float bp0 = b0 * PB, bp1 = b1 * P1, bp2 = b2 * PB, bp3 = b3 * P3,  \
                bp4 = b4 * PB, bp5 = b5 * P5, bp6 = b6 * PB, bp7 = b7 * P7,  \
                bpt = bt * PB;                                               \
    const float e0e = (lane == 63) ? bt : e0r;                               \
    const float bp8 = e0e * PB;                                              \
    const float bp9 = e1r * PN;                                              \
    const float nb0 = bp0 + bp1;                                             \
    const float nb1 = fmaf(m3, bp3, bp1 + bp2);                              \
    const float mx01 = fmaxf(nb0, nb1);                                      \
    const int en = (int)((__float_as_uint(mx01) >> 23) & 255u) - 126;        \
    const float u0n = dpp_shl1_f(ldexpf(nb0, -en));                          \
    const float u1n = dpp_shl1_f(ldexpf(nb1, -en));                          \
    const int Fn_n = dpp_shl1_i(F + en);                                     \
    b2 = bp2 + bp3;                                                          \
    b3 = fmaf(m5, bp5, bp3 + bp4);                                           \
    b4 = bp4 + bp5;                                                          \
    b5 = fmaf(m7, bp7, bp5 + bp6);                                           \
    b6 = bp6 + bp7;                                                          \
    b7 = fmaf(mn, bp9, bp7 + bp8);                                           \
    bt = bpt;                                                                \
    b0 = nb0; b1 = nb1;                                                      \
    u0 = u0n; u1 = u1n; Fn_s = Fn_n;                                         \
    p1 = bfu((QU).x); p3 = bfu((QU).y); p5 = bfu((QU).z); p7 = bfu((QU).w);  \
    pb = (QB);                                                               \
    pn1 = dpp_shl1_f(p1);                                                    \
  } while (0)

#define SLOTB(U, SM) do {                                                    \
    SM(q##U, r##U);                                                          \
    int trow = tt - 9 - U;                                                   \
    trow = (trow < 0) ? 0 : trow;                                            \
    q##U = gp[(size_t)trow * 64 + lane];                                     \
    r##U = gb[2 * trow + lpar];                                              \
  } while (0)

__global__ __launch_bounds__(128) void ctc_dp(const ushort4* __restrict__ packed,
                                              const float* __restrict__ blanks2,
                                              const int* __restrict__ labels,
                                              const int* __restrict__ widths,
                                              const int* __restrict__ lengths,
                                              float* __restrict__ out) {
  __shared__ float Alog[513];
  __shared__ float Blog[513];
  const int b = blockIdx.x;
  const int tid = threadIdx.x;
  const int wid = tid >> 6;
  const int lane = tid & 63;
  const int lpar = lane & 1;
  const int Tb = widths[b] >> 3;     // in [1536, 2048]
  const int s_end = 2 * lengths[b];
  const int tm = (Tb * 67) >> 7;     // meet row (fwd/bwd cost-balanced)
  const int* lab = labels + (b << 8);
  const int4 lb = *reinterpret_cast<const int4*>(lab + 4 * lane);
  const int pw = __shfl_up(lb.w, 1);
  const float m1 = (lane > 0 && lb.x != pw) ? 1.f : 0.f;
  const float m3 = (lb.y != lb.x) ? 1.f : 0.f;
  const float m5 = (lb.z != lb.y) ? 1.f : 0.f;
  const float m7 = (lb.w != lb.z) ? 1.f : 0.f;
  const float mdn = __shfl_down(m1, 1);
  const float mn = (lane == 63) ? 0.f : mdn;  // skip mask for s+2 = 8l+9

  const ushort4* gp = packed + (size_t)b * (T_ * 64);
  const float* gb = blanks2 + b * (2 * T_);

  if (wid == 0) {
    // ---------------- forward alpha: rows 0 .. tm-1 ----------------
    const ushort4 u0v = gp[lane];
    const float bl0 = gb[lpar];
    const ushort4 u1v = gp[64 + lane];
    const float bl1 = gb[2 + lpar];
    ushort4 q0 = gp[2 * 64 + lane], q1 = gp[3 * 64 + lane];
    ushort4 q2 = gp[4 * 64 + lane], q3 = gp[5 * 64 + lane];
    ushort4 q4 = gp[6 * 64 + lane], q5 = gp[7 * 64 + lane];
    ushort4 q6 = gp[8 * 64 + lane], q7 = gp[9 * 64 + lane];
    float r0 = gb[2 * 2 + lpar], r1 = gb[2 * 3 + lpar];
    float r2 = gb[2 * 4 + lpar], r3 = gb[2 * 5 + lpar];
    float r4 = gb[2 * 6 + lpar], r5 = gb[2 * 7 + lpar];
    float r6 = gb[2 * 8 + lpar], r7 = gb[2 * 9 + lpar];

    float a0 = 0.f, a1 = 0.f, a2 = 0.f, a3 = 0.f;
    float a4 = 0.f, a5 = 0.f, a6 = 0.f, a7 = 0.f, at = 0.f;
    int F = 0, Fp_s = 0;
    float b1_raw = 0.f;
    if (lane == 0) { a0 = bl0; a1 = bfu(u0v.x); }
    float pb = bl1;
    float p1 = bfu(u1v.x), p3 = bfu(u1v.y), p5 = bfu(u1v.z), p7 = bfu(u1v.w);

    int tt = 1;
    for (; tt + 8 <= tm; tt += 8) {
      SLOTF(0, STEPF_O); SLOTF(1, STEPF_P);
      SLOTF(2, STEPF_O); SLOTF(3, STEPF_P);
      SLOTF(4, STEPF_O); SLOTF(5, STEPF_P);
      SLOTF(6, STEPF_O); SLOTF(7, STEPF_P);
    }
    if (tt + 0 < tm) STEPF_P(q0, r0);
    if (tt + 1 < tm) STEPF_P(q1, r1);
    if (tt + 2 < tm) STEPF_P(q2, r2);
    if (tt + 3 < tm) STEPF_P(q3, r3);
    if (tt + 4 < tm) STEPF_P(q4, r4);
    if (tt + 5 < tm) STEPF_P(q5, r5);
    if (tt + 6 < tm) STEPF_P(q6, r6);

    const float Ff = (float)F;
    const int sb = 8 * lane;
    Alog[sb + 0] = (a0 > 0.f) ? lg2(a0) + Ff : -1.0e30f;
    Alog[sb + 1] = (a1 > 0.f) ? lg2(a1) + Ff : -1.0e30f;
    Alog[sb + 2] = (a2 > 0.f) ? lg2(a2) + Ff : -1.0e30f;
    Alog[sb + 3] = (a3 > 0.f) ? lg2(a3) + Ff : -1.0e30f;
    Alog[sb + 4] = (a4 > 0.f) ? lg2(a4) + Ff : -1.0e30f;
    Alog[sb + 5] = (a5 > 0.f) ? lg2(a5) + Ff : -1.0e30f;
    Alog[sb + 6] = (a6 > 0.f) ? lg2(a6) + Ff : -1.0e30f;
    Alog[sb + 7] = (a7 > 0.f) ? lg2(a7) + Ff : -1.0e30f;
    if (lane == 63) Alog[512] = (at > 0.f) ? lg2(at) + Ff : -1.0e30f;
  } else {
    // ---------------- backward beta: rows Tb-1 .. tm ----------------
    const ushort4 uiv = gp[(size_t)(Tb - 1) * 64 + lane];
    const float bli = gb[2 * (Tb - 1) + lpar];
    ushort4 q0 = gp[(size_t)(Tb - 2) * 64 + lane], q1 = gp[(size_t)(Tb - 3) * 64 + lane];
    ushort4 q2 = gp[(size_t)(Tb - 4) * 64 + lane], q3 = gp[(size_t)(Tb - 5) * 64 + lane];
    ushort4 q4 = gp[(size_t)(Tb - 6) * 64 + lane], q5 = gp[(size_t)(Tb - 7) * 64 + lane];
    ushort4 q6 = gp[(size_t)(Tb - 8) * 64 + lane], q7 = gp[(size_t)(Tb - 9) * 64 + lane];
    float r0 = gb[2 * (Tb - 2) + lpar], r1 = gb[2 * (Tb - 3) + lpar];
    float r2 = gb[2 * (Tb - 4) + lpar], r3 = gb[2 * (Tb - 5) + lpar];
    float r4 = gb[2 * (Tb - 6) + lpar], r5 = gb[2 * (Tb - 7) + lpar];
    float r6 = gb[2 * (Tb - 8) + lpar], r7 = gb[2 * (Tb - 9) + lpar];

    const int sb = 8 * lane;
    float b0 = (sb + 0 == s_end || sb + 0 == s_end - 1) ? 1.f : 0.f;
    float b1 = (sb + 1 == s_end || sb + 1 == s_end - 1) ? 1.f : 0.f;
    float b2 = (sb + 2 == s_end || sb + 2 == s_end - 1) ? 1.f : 0.f;
    float b3 = (sb + 3 == s_end || sb + 3 == s_end - 1) ? 1.f : 0.f;
    float b4 = (sb + 4 == s_end || sb + 4 == s_end - 1) ? 1.f : 0.f;
    float b5 = (sb + 5 == s_end || sb + 5 == s_end - 1) ? 1.f : 0.f;
    float b6 = (sb + 6 == s_end || sb + 6 == s_end - 1) ? 1.f : 0.f;
    float b7 = (sb + 7 == s_end || sb + 7 == s_end - 1) ? 1.f : 0.f;
    float bt = (lane == 63 && s_end == 512) ? 1.f : 0.f;
    int F = 0, Fn_s = 0;

    float pb = bli;  // probs of row Tb-1 (first consumed)
    float p1 = bfu(uiv.x), p3 = bfu(uiv.y), p5 = bfu(uiv.z), p7 = bfu(uiv.w);
    float u0 = dpp_shl1_f(b0);
    float u1 = dpp_shl1_f(b1);
    float pn1 = dpp_shl1_f(p1);

    int tt = Tb - 1;
    for (; tt - 7 >= tm; tt -= 8) {
      SLOTB(0, STEPB_O); SLOTB(1, STEPB_P);
      SLOTB(2, STEPB_O); SLOTB(3, STEPB_P);
      SLOTB(4, STEPB_O); SLOTB(5, STEPB_P);
      SLOTB(6, STEPB_O); SLOTB(7, STEPB_P);
    }
    if (tt - 0 >= tm) STEPB_P(q0, r0);
    if (tt - 1 >= tm) STEPB_P(q1, r1);
    if (tt - 2 >= tm) STEPB_P(q2, r2);
    if (tt - 3 >= tm) STEPB_P(q3, r3);
    if (tt - 4 >= tm) STEPB_P(q4, r4);
    if (tt - 5 >= tm) STEPB_P(q5, r5);
    if (tt - 6 >= tm) STEPB_P(q6, r6);

    const float Ff = (float)F;
    Blog[sb + 0] = (b0 > 0.f) ? lg2(b0) + Ff : -1.0e30f;
    Blog[sb + 1] = (b1 > 0.f) ? lg2(b1) + Ff : -1.0e30f;
    Blog[sb + 2] = (b2 > 0.f) ? lg2(b2) + Ff : -1.0e30f;
    Blog[sb + 3] = (b3 > 0.f) ? lg2(b3) + Ff : -1.0e30f;
    Blog[sb + 4] = (b4 > 0.f) ? lg2(b4) + Ff : -1.0e30f;
    Blog[sb + 5] = (b5 > 0.f) ? lg2(b5) + Ff : -1.0e30f;
    Blog[sb + 6] = (b6 > 0.f) ? lg2(b6) + Ff : -1.0e30f;
    Blog[sb + 7] = (b7 > 0.f) ? lg2(b7) + Ff : -1.0e30f;
    if (lane == 63) Blog[512] = (bt > 0.f) ? lg2(bt) + Ff : -1.0e30f;
  }

  __syncthreads();

  if (wid == 0) {
    // log2 P = logsumexp2_s (Alog[s] + Blog[s])
    const int sb = 8 * lane;
    float t0 = Alog[sb + 0] + Blog[sb + 0];
    float t1 = Alog[sb + 1] + Blog[sb + 1];
    float t2 = Alog[sb + 2] + Blog[sb + 2];
    float t3 = Alog[sb + 3] + Blog[sb + 3];
    float t4 = Alog[sb + 4] + Blog[sb + 4];
    float t5 = Alog[sb + 5] + Blog[sb + 5];
    float t6 = Alog[sb + 6] + Blog[sb + 6];
    float t7 = Alog[sb + 7] + Blog[sb + 7];
    float t8 = (lane == 63) ? (Alog[512] + Blog[512]) : -1.0e30f;
    float M = fmaxf(fmaxf(fmaxf(t0, t1), fmaxf(t2, t3)),
                    fmaxf(fmaxf(t4, t5), fmaxf(fmaxf(t6, t7), t8)));
#pragma unroll
    for (int off = 32; off >= 1; off >>= 1) M = fmaxf(M, __shfl_xor(M, off));
    float sm = ex2(t0 - M) + ex2(t1 - M) + ex2(t2 - M) + ex2(t3 - M) +
               ex2(t4 - M) + ex2(t5 - M) + ex2(t6 - M) + ex2(t7 - M) +
               ex2(t8 - M);
#pragma unroll
    for (int off = 32; off >= 1; off >>= 1) sm += __shfl_xor(sm, off);
    if (lane == 0)
      out[b] = -0.6931471805599453f * (M + lg2(sm));
  }
}

extern "C" void kernel_launch(void* const* d_in, const int* in_sizes, int n_in,
                              void* d_out, int out_size, void* d_ws, size_t ws_size,
                              hipStream_t stream) {
  const int* labels = (const int*)d_in[0];
  const float* logits = (const float*)d_in[1];
  const int* widths = (const int*)d_in[2];
  const int* lengths = (const int*)d_in[3];
  float* out = (float*)d_out;

  // ws layout: [blanks2: B*T*2 fp32 = 512KB][packed: B*T*64 ushort4 = 32MB]
  float* blanks2 = (float*)d_ws;
  ushort4* packed = (ushort4*)((char*)d_ws + (size_t)B_ * T_ * 2 * sizeof(float));

  gather_pack<<<B_ * T_, 64, 0, stream>>>(logits, labels, blanks2, packed);
  ctc_dp<<<B_, 128, 0, stream>>>(packed, blanks2, labels, widths, lengths, out);
}

// Round 14
// 177.914 us; speedup vs baseline: 3.0949x; 1.1649x over previous
//
#include <hip/hip_runtime.h>
#include <math.h>

#define B_ 32
#define T_ 2048
#define C_ 96
#define L_ 256
#define BLANK 95

__device__ __forceinline__ float ex2(float x) {
  float r; asm("v_exp_f32 %0, %1" : "=v"(r) : "v"(x)); return r;
}
__device__ __forceinline__ float lg2(float x) {
  float r; asm("v_log_f32 %0, %1" : "=v"(r) : "v"(x)); return r;
}
__device__ __forceinline__ unsigned short f2bf(float f) {  // RNE f32->bf16
  unsigned u = __float_as_uint(f);
  return (unsigned short)((u + 0x7FFFu + ((u >> 16) & 1u)) >> 16);
}
__device__ __forceinline__ float bfu(unsigned short u) {
  return __uint_as_float((unsigned)u << 16);
}
// Wave shifts via DPP (VALU). 0x138 = WAVE_SHR1, 0x130 = WAVE_SHL1.
__device__ __forceinline__ float dpp_shr1_f(float x) {
  return __int_as_float(__builtin_amdgcn_update_dpp(
      0, __float_as_int(x), 0x138, 0xF, 0xF, false));
}
__device__ __forceinline__ int dpp_shr1_i(int x) {
  return __builtin_amdgcn_update_dpp(0, x, 0x138, 0xF, 0xF, false);
}
__device__ __forceinline__ float dpp_shl1_f(float x) {
  return __int_as_float(__builtin_amdgcn_update_dpp(
      0, __float_as_int(x), 0x130, 0xF, 0xF, false));
}
__device__ __forceinline__ int dpp_shl1_i(int x) {
  return __builtin_amdgcn_update_dpp(0, x, 0x130, 0xF, 0xF, false);
}
// Broadcast lane J of a float VGPR to an SGPR (no memory counters).
#define RL(V, J) __int_as_float(__builtin_amdgcn_readlane(__float_as_int(V), (J)))

// ---- Kernel 1: fused softmax + per-lane label-prob gather/pack ----
__global__ __launch_bounds__(64) void gather_pack(const float* __restrict__ logits,
                                                  const int* __restrict__ labels,
                                                  float* __restrict__ blanks2,
                                                  ushort4* __restrict__ packed) {
  const int tid = threadIdx.x;
  const int bt = blockIdx.x;  // b*T + t
  const int b = bt >> 11;
  const float* xr = logits + (size_t)bt * C_;
  float xa = xr[tid];
  float xb = (tid < 32) ? xr[64 + tid] : -1.0e30f;
  float m = fmaxf(xa, xb);
#pragma unroll
  for (int off = 32; off >= 1; off >>= 1) m = fmaxf(m, __shfl_xor(m, off));
  float ea = __expf(xa - m);
  float eb = (tid < 32) ? __expf(xb - m) : 0.f;
  float z = ea + eb;
#pragma unroll
  for (int off = 32; off >= 1; off >>= 1) z += __shfl_xor(z, off);
  float rz = 1.0f / z;
  __shared__ float sp[C_];
  sp[tid] = fmaf(ea, rz, 1e-7f);
  if (tid < 32) sp[64 + tid] = fmaf(eb, rz, 1e-7f);
  __syncthreads();
  const int4 lb = *reinterpret_cast<const int4*>(labels + (b << 8) + 4 * tid);
  ushort4 o;
  o.x = f2bf(sp[lb.x]); o.y = f2bf(sp[lb.y]);
  o.z = f2bf(sp[lb.z]); o.w = f2bf(sp[lb.w]);
  packed[(size_t)bt * 64 + tid] = o;
  if (tid < 2) blanks2[2 * bt + tid] = sp[BLANK];
}

// ---------------- Kernel 2: meet-in-the-middle CTC DP ----------------
// One 128-thread block per batch; wave0 fwd alpha, wave1 bwd beta, join at
// row tm-1. Per-lane 2^F frames, pin every 2nd step, mantissa-normalized
// sends, branch-free step body (R13 numerics, absmax 0).
// Memory: 16-deep VGPR ring of packed prob rows (16 VMEM loads in flight,
// ~16 steps of slack >> HBM latency) and blanks loaded 8-rows-per-register
// (one VMEM load per 8 steps, lane&7-indexed), extracted per step via
// v_readlane -> SGPR (no memory counter on the extract).

#define REBASE_A() do {                                                      \
      a0 = ldexpf(a0, -shift); a1 = ldexpf(a1, -shift);                      \
      a2 = ldexpf(a2, -shift); a3 = ldexpf(a3, -shift);                      \
      a4 = ldexpf(a4, -shift); a5 = ldexpf(a5, -shift);                      \
      a6 = ldexpf(a6, -shift); a7 = ldexpf(a7, -shift);                      \
      at = ldexpf(at, -shift); } while (0)

#define STEPF_O(QU, QB) do {                                                 \
    int di = Fp_s - F;                                                       \
    di = (b1_raw > 0.f) ? di : 0;                                            \
    const int shift = (di > 24) ? (di - 24) : 0;                             \
    REBASE_A();                                                              \
    F += shift;                                                              \
    const float b1a = ldexpf(b1_raw, di - shift);                            \
    const float na7 = fmaf(m7, a5, a7 + a6) * p7;                            \
    const int en = (int)((__float_as_uint(na7) >> 23) & 255u) - 126;         \
    const float mant = ldexpf(na7, -en);                                     \
    const float b1n = dpp_shr1_f(mant);                                      \
    const int Fp_n = dpp_shr1_i(F + en);                                     \
    at = (at + a7) * pb;                                                     \
    a6 = (a6 + a5) * pb;                                                     \
    a5 = fmaf(m5, a3, a5 + a4) * p5;                                         \
    a4 = (a4 + a3) * pb;                                                     \
    a3 = fmaf(m3, a1, a3 + a2) * p3;                                         \
    a2 = (a2 + a1) * pb;                                                     \
    a1 = fmaf(m1, b1a, a1 + a0) * p1;                                        \
    a0 = (a0 + b1a) * pb;                                                    \
    a7 = na7;                                                                \
    b1_raw = b1n; Fp_s = Fp_n;                                               \
    p1 = bfu((QU).x); p3 = bfu((QU).y); p5 = bfu((QU).z); p7 = bfu((QU).w);  \
    pb = (QB);                                                               \
  } while (0)

#define STEPF_P(QU, QB) do {                                                 \
    const float mA = fmaxf(fmaxf(a0, a1), a2);                               \
    const float mB = fmaxf(fmaxf(a3, a4), a5);                               \
    const float mC = fmaxf(fmaxf(a6, a7), at);                               \
    const float m8 = fmaxf(fmaxf(mA, mB), mC);                               \
    int e_cur = (int)((__float_as_uint(m8) >> 23) & 255u) - 126;             \
    e_cur = (e_cur < -60) ? -60 : e_cur;                                     \
    const float scl = ldexpf(1.0f, -e_cur);                                  \
    int di = Fp_s - F;                                                       \
    di = (b1_raw > 0.f) ? di : 0;                                            \
    const int shift = (di > 24) ? (di - 24) : 0;                             \
    REBASE_A();                                                              \
    F += shift + e_cur;                                                      \
    const float b1a = ldexpf(b1_raw, di - shift);                            \
    const float PB = pb * scl, P1 = p1 * scl, P3 = p3 * scl,                 \
                P5 = p5 * scl, P7 = p7 * scl;                                \
    const float na7 = fmaf(m7, a5, a7 + a6) * P7;                            \
    const int en = (int)((__float_as_uint(na7) >> 23) & 255u) - 126;         \
    const float mant = ldexpf(na7, -en);                                     \
    const float b1n = dpp_shr1_f(mant);                                      \
    const int Fp_n = dpp_shr1_i(F + en);                                     \
    at = (at + a7) * PB;                                                     \
    a6 = (a6 + a5) * PB;                                                     \
    a5 = fmaf(m5, a3, a5 + a4) * P5;                                         \
    a4 = (a4 + a3) * PB;                                                     \
    a3 = fmaf(m3, a1, a3 + a2) * P3;                                         \
    a2 = (a2 + a1) * PB;                                                     \
    a1 = fmaf(m1, b1a, a1 + a0) * P1;                                        \
    a0 = (a0 + b1a) * PB;                                                    \
    a7 = na7;                                                                \
    b1_raw = b1n; Fp_s = Fp_n;                                               \
    p1 = bfu((QU).x); p3 = bfu((QU).y); p5 = bfu((QU).z); p7 = bfu((QU).w);  \
    pb = (QB);                                                               \
  } while (0)

// Slot U (fwd): step installs row tt+1+U; reload row tt+17+U (clamped).
#define SLOTF(U, SM, RB) do {                                                \
    SM(q##U, RL(RB, (U) & 7));                                               \
    int trow = tt + 17 + U;                                                  \
    trow = (trow > T_ - 1) ? (T_ - 1) : trow;                                \
    q##U = gp[(size_t)trow * 64 + lane];                                     \
  } while (0)

#define REBASE_B() do {                                                      \
      b0 = ldexpf(b0, -shift); b1 = ldexpf(b1, -shift);                      \
      b2 = ldexpf(b2, -shift); b3 = ldexpf(b3, -shift);                      \
      b4 = ldexpf(b4, -shift); b5 = ldexpf(b5, -shift);                      \
      b6 = ldexpf(b6, -shift); b7 = ldexpf(b7, -shift);                      \
      bt = ldexpf(bt, -shift); } while (0)

#define STEPB_O(QU, QB) do {                                                 \
    int di = Fn_s - F;                                                       \
    di = (fmaxf(u0, u1) > 0.f) ? di : 0;                                     \
    const int shift = (di > 24) ? (di - 24) : 0;                             \
    REBASE_B();                                                              \
    F += shift;                                                              \
    const int sh2 = di - shift;                                              \
    const float e0r = ldexpf(u0, sh2), e1r = ldexpf(u1, sh2);                \
    const float bp0 = b0 * pb, bp1 = b1 * p1, bp2 = b2 * pb, bp3 = b3 * p3,  \
                bp4 = b4 * pb, bp5 = b5 * p5, bp6 = b6 * pb, bp7 = b7 * p7,  \
                bpt = bt * pb;                                               \
    const float e0e = (lane == 63) ? bt : e0r;                               \
    const float bp8 = e0e * pb;                                              \
    const float bp9 = e1r * pn1;                                             \
    const float nb0 = bp0 + bp1;                                             \
    const float nb1 = fmaf(m3, bp3, bp1 + bp2);                              \
    const float mx01 = fmaxf(nb0, nb1);                                      \
    const int en = (int)((__float_as_uint(mx01) >> 23) & 255u) - 126;        \
    const float u0n = dpp_shl1_f(ldexpf(nb0, -en));                          \
    const float u1n = dpp_shl1_f(ldexpf(nb1, -en));                          \
    const int Fn_n = dpp_shl1_i(F + en);                                     \
    b2 = bp2 + bp3;                                                          \
    b3 = fmaf(m5, bp5, bp3 + bp4);                                           \
    b4 = bp4 + bp5;                                                          \
    b5 = fmaf(m7, bp7, bp5 + bp6);                                           \
    b6 = bp6 + bp7;                                                          \
    b7 = fmaf(mn, bp9, bp7 + bp8);                                           \
    bt = bpt;                                                                \
    b0 = nb0; b1 = nb1;                                                      \
    u0 = u0n; u1 = u1n; Fn_s = Fn_n;                                         \
    p1 = bfu((QU).x); p3 = bfu((QU).y); p5 = bfu((QU).z); p7 = bfu((QU).w);  \
    pb = (QB);                                                               \
    pn1 = dpp_shl1_f(p1);                                                    \
  } while (0)

#define STEPB_P(QU, QB) do {                                                 \
    const float mA = fmaxf(fmaxf(b0, b1), b2);                               \
    const float mB = fmaxf(fmaxf(b3, b4), b5);                               \
    const float mC = fmaxf(fmaxf(b6, b7), bt);                               \
    const float m8 = fmaxf(fmaxf(mA, mB), mC);                               \
    int e_cur = (int)((__float_as_uint(m8) >> 23) & 255u) - 126;             \
    e_cur = (e_cur < -60) ? -60 : e_cur;                                     \
    const float scl = ldexpf(1.0f, -e_cur);                                  \
    int di = Fn_s - F;                                                       \
    di = (fmaxf(u0, u1) > 0.f) ? di : 0;                                     \
    const int shift = (di > 24) ? (di - 24) : 0;                             \
    REBASE_B();                                                              \
    F += shift + e_cur;                                                      \
    const int sh2 = di - shift;                                              \
    const float e0r = ldexpf(u0, sh2), e1r = ldexpf(u1, sh2);                \
    const float PB = pb * scl, P1 = p1 * scl, P3 = p3 * scl,                 \
                P5 = p5 * scl, P7 = p7 * scl, PN = pn1 * scl;                \
    const float bp0 = b0 * PB, bp1 = b1 * P1, bp2 = b2 * PB, bp3 = b3 * P3,  \
                bp4 = b4 * PB, bp5 = b5 * P5, bp6 = b6 * PB, bp7 = b7 * P7,  \
                bpt = bt * PB;                                               \
    const float e0e = (lane == 63) ? bt : e0r;                               \
    const float bp8 = e0e * PB;                                              \
    const float bp9 = e1r * PN;                                              \
    const float nb0 = bp0 + bp1;                                             \
    const float nb1 = fmaf(m3, bp3, bp1 + bp2);                              \
    const float mx01 = fmaxf(nb0, nb1);                                      \
    const int en = (int)((__float_as_uint(mx01) >> 23) & 255u) - 126;        \
    const float u0n = dpp_shl1_f(ldexpf(nb0, -en));                          \
    const float u1n = dpp_shl1_f(ldexpf(nb1, -en));                          \
    const int Fn_n = dpp_shl1_i(F + en);                                     \
    b2 = bp2 + bp3;                                                          \
    b3 = fmaf(m5, bp5, bp3 + bp4);                                           \
    b4 = bp4 + bp5;                                                          \
    b5 = fmaf(m7, bp7, bp5 + bp6);                                           \
    b6 = bp6 + bp7;                                                          \
    b7 = fmaf(mn, bp9, bp7 + bp8);                                           \
    bt = bpt;                                                                \
    b0 = nb0; b1 = nb1;                                                      \
    u0 = u0n; u1 = u1n; Fn_s = Fn_n;                                         \
    p1 = bfu((QU).x); p3 = bfu((QU).y); p5 = bfu((QU).z); p7 = bfu((QU).w);  \
    pb = (QB);                                                               \
    pn1 = dpp_shl1_f(p1);                                                    \
  } while (0)

// Slot U (bwd): step installs row tt-1-U; reload row tt-17-U (clamped).
#define SLOTB(U, SM, RB) do {                                                \
    SM(q##U, RL(RB, (U) & 7));                                               \
    int trow = tt - 17 - U;                                                  \
    trow = (trow < 0) ? 0 : trow;                                            \
    q##U = gp[(size_t)trow * 64 + lane];                                     \
  } while (0)

__global__ __launch_bounds__(128) void ctc_dp(const ushort4* __restrict__ packed,
                                              const float* __restrict__ blanks2,
                                              const int* __restrict__ labels,
                                              const int* __restrict__ widths,
                                              const int* __restrict__ lengths,
                                              float* __restrict__ out) {
  __shared__ float Alog[513];
  __shared__ float Blog[513];
  const int b = blockIdx.x;
  const int tid = threadIdx.x;
  const int wid = tid >> 6;
  const int lane = tid & 63;
  const int l8 = lane & 7;
  const int lpar = lane & 1;
  const int Tb = widths[b] >> 3;     // in [1536, 2048]
  const int s_end = 2 * lengths[b];
  const int tm = (Tb * 67) >> 7;     // meet row (fwd/bwd cost-balanced)
  const int* lab = labels + (b << 8);
  const int4 lb = *reinterpret_cast<const int4*>(lab + 4 * lane);
  const int pw = __shfl_up(lb.w, 1);
  const float m1 = (lane > 0 && lb.x != pw) ? 1.f : 0.f;
  const float m3 = (lb.y != lb.x) ? 1.f : 0.f;
  const float m5 = (lb.z != lb.y) ? 1.f : 0.f;
  const float m7 = (lb.w != lb.z) ? 1.f : 0.f;
  const float mdn = __shfl_down(m1, 1);
  const float mn = (lane == 63) ? 0.f : mdn;  // skip mask for s+2 = 8l+9

  const ushort4* gp = packed + (size_t)b * (T_ * 64);
  const float* gb = blanks2 + b * (2 * T_);

  if (wid == 0) {
    // ---------------- forward alpha: rows 0 .. tm-1 ----------------
    const ushort4 u0v = gp[lane];
    const float bl0 = gb[lpar];
    const ushort4 u1v = gp[64 + lane];
    const float bl1 = gb[2 + lpar];
    // 16-deep prob ring: rows 2..17.
    ushort4 q0 = gp[2 * 64 + lane],  q1 = gp[3 * 64 + lane];
    ushort4 q2 = gp[4 * 64 + lane],  q3 = gp[5 * 64 + lane];
    ushort4 q4 = gp[6 * 64 + lane],  q5 = gp[7 * 64 + lane];
    ushort4 q6 = gp[8 * 64 + lane],  q7 = gp[9 * 64 + lane];
    ushort4 q8 = gp[10 * 64 + lane], q9 = gp[11 * 64 + lane];
    ushort4 q10 = gp[12 * 64 + lane], q11 = gp[13 * 64 + lane];
    ushort4 q12 = gp[14 * 64 + lane], q13 = gp[15 * 64 + lane];
    ushort4 q14 = gp[16 * 64 + lane], q15 = gp[17 * 64 + lane];
    // Blank blocks: lane&7-indexed, rows 2..9 and 10..17.
    float rbA0 = gb[2 * (2 + l8)];
    float rbA1 = gb[2 * (10 + l8)];

    float a0 = 0.f, a1 = 0.f, a2 = 0.f, a3 = 0.f;
    float a4 = 0.f, a5 = 0.f, a6 = 0.f, a7 = 0.f, at = 0.f;
    int F = 0, Fp_s = 0;
    float b1_raw = 0.f;
    if (lane == 0) { a0 = bl0; a1 = bfu(u0v.x); }
    float pb = bl1;
    float p1 = bfu(u1v.x), p3 = bfu(u1v.y), p5 = bfu(u1v.z), p7 = bfu(u1v.w);

    int tt = 1;
    for (; tt + 16 <= tm; tt += 16) {
      int rrow0 = tt + 17 + l8; rrow0 = (rrow0 > T_ - 1) ? (T_ - 1) : rrow0;
      int rrow1 = tt + 25 + l8; rrow1 = (rrow1 > T_ - 1) ? (T_ - 1) : rrow1;
      const float rbB0 = gb[2 * rrow0];
      const float rbB1 = gb[2 * rrow1];
      SLOTF(0, STEPF_O, rbA0);  SLOTF(1, STEPF_P, rbA0);
      SLOTF(2, STEPF_O, rbA0);  SLOTF(3, STEPF_P, rbA0);
      SLOTF(4, STEPF_O, rbA0);  SLOTF(5, STEPF_P, rbA0);
      SLOTF(6, STEPF_O, rbA0);  SLOTF(7, STEPF_P, rbA0);
      SLOTF(8, STEPF_O, rbA1);  SLOTF(9, STEPF_P, rbA1);
      SLOTF(10, STEPF_O, rbA1); SLOTF(11, STEPF_P, rbA1);
      SLOTF(12, STEPF_O, rbA1); SLOTF(13, STEPF_P, rbA1);
      SLOTF(14, STEPF_O, rbA1); SLOTF(15, STEPF_P, rbA1);
      rbA0 = rbB0; rbA1 = rbB1;
    }
    if (tt + 0 < tm)  STEPF_P(q0,  RL(rbA0, 0));
    if (tt + 1 < tm)  STEPF_P(q1,  RL(rbA0, 1));
    if (tt + 2 < tm)  STEPF_P(q2,  RL(rbA0, 2));
    if (tt + 3 < tm)  STEPF_P(q3,  RL(rbA0, 3));
    if (tt + 4 < tm)  STEPF_P(q4,  RL(rbA0, 4));
    if (tt + 5 < tm)  STEPF_P(q5,  RL(rbA0, 5));
    if (tt + 6 < tm)  STEPF_P(q6,  RL(rbA0, 6));
    if (tt + 7 < tm)  STEPF_P(q7,  RL(rbA0, 7));
    if (tt + 8 < tm)  STEPF_P(q8,  RL(rbA1, 0));
    if (tt + 9 < tm)  STEPF_P(q9,  RL(rbA1, 1));
    if (tt + 10 < tm) STEPF_P(q10, RL(rbA1, 2));
    if (tt + 11 < tm) STEPF_P(q11, RL(rbA1, 3));
    if (tt + 12 < tm) STEPF_P(q12, RL(rbA1, 4));
    if (tt + 13 < tm) STEPF_P(q13, RL(rbA1, 5));
    if (tt + 14 < tm) STEPF_P(q14, RL(rbA1, 6));

    const float Ff = (float)F;
    const int sb = 8 * lane;
    Alog[sb + 0] = (a0 > 0.f) ? lg2(a0) + Ff : -1.0e30f;
    Alog[sb + 1] = (a1 > 0.f) ? lg2(a1) + Ff : -1.0e30f;
    Alog[sb + 2] = (a2 > 0.f) ? lg2(a2) + Ff : -1.0e30f;
    Alog[sb + 3] = (a3 > 0.f) ? lg2(a3) + Ff : -1.0e30f;
    Alog[sb + 4] = (a4 > 0.f) ? lg2(a4) + Ff : -1.0e30f;
    Alog[sb + 5] = (a5 > 0.f) ? lg2(a5) + Ff : -1.0e30f;
    Alog[sb + 6] = (a6 > 0.f) ? lg2(a6) + Ff : -1.0e30f;
    Alog[sb + 7] = (a7 > 0.f) ? lg2(a7) + Ff : -1.0e30f;
    if (lane == 63) Alog[512] = (at > 0.f) ? lg2(at) + Ff : -1.0e30f;
  } else {
    // ---------------- backward beta: rows Tb-1 .. tm ----------------
    const ushort4 uiv = gp[(size_t)(Tb - 1) * 64 + lane];
    const float bli = gb[2 * (Tb - 1) + lpar];
    ushort4 q0 = gp[(size_t)(Tb - 2) * 64 + lane],  q1 = gp[(size_t)(Tb - 3) * 64 + lane];
    ushort4 q2 = gp[(size_t)(Tb - 4) * 64 + lane],  q3 = gp[(size_t)(Tb - 5) * 64 + lane];
    ushort4 q4 = gp[(size_t)(Tb - 6) * 64 + lane],  q5 = gp[(size_t)(Tb - 7) * 64 + lane];
    ushort4 q6 = gp[(size_t)(Tb - 8) * 64 + lane],  q7 = gp[(size_t)(Tb - 9) * 64 + lane];
    ushort4 q8 = gp[(size_t)(Tb - 10) * 64 + lane], q9 = gp[(size_t)(Tb - 11) * 64 + lane];
    ushort4 q10 = gp[(size_t)(Tb - 12) * 64 + lane], q11 = gp[(size_t)(Tb - 13) * 64 + lane];
    ushort4 q12 = gp[(size_t)(Tb - 14) * 64 + lane], q13 = gp[(size_t)(Tb - 15) * 64 + lane];
    ushort4 q14 = gp[(size_t)(Tb - 16) * 64 + lane], q15 = gp[(size_t)(Tb - 17) * 64 + lane];
    float rbA0 = gb[2 * (Tb - 2 - l8)];
    float rbA1 = gb[2 * (Tb - 10 - l8)];

    const int sb = 8 * lane;
    float b0 = (sb + 0 == s_end || sb + 0 == s_end - 1) ? 1.f : 0.f;
    float b1 = (sb + 1 == s_end || sb + 1 == s_end - 1) ? 1.f : 0.f;
    float b2 = (sb + 2 == s_end || sb + 2 == s_end - 1) ? 1.f : 0.f;
    float b3 = (sb + 3 == s_end || sb + 3 == s_end - 1) ? 1.f : 0.f;
    float b4 = (sb + 4 == s_end || sb + 4 == s_end - 1) ? 1.f : 0.f;
    float b5 = (sb + 5 == s_end || sb + 5 == s_end - 1) ? 1.f : 0.f;
    float b6 = (sb + 6 == s_end || sb + 6 == s_end - 1) ? 1.f : 0.f;
    float b7 = (sb + 7 == s_end || sb + 7 == s_end - 1) ? 1.f : 0.f;
    float bt = (lane == 63 && s_end == 512) ? 1.f : 0.f;
    int F = 0, Fn_s = 0;

    float pb = bli;  // probs of row Tb-1 (first consumed)
    float p1 = bfu(uiv.x), p3 = bfu(uiv.y), p5 = bfu(uiv.z), p7 = bfu(uiv.w);
    float u0 = dpp_shl1_f(b0);
    float u1 = dpp_shl1_f(b1);
    float pn1 = dpp_shl1_f(p1);

    int tt = Tb - 1;
    for (; tt - 15 >= tm; tt -= 16) {
      int rrow0 = tt - 17 - l8; rrow0 = (rrow0 < 0) ? 0 : rrow0;
      int rrow1 = tt - 25 - l8; rrow1 = (rrow1 < 0) ? 0 : rrow1;
      const float rbB0 = gb[2 * rrow0];
      const float rbB1 = gb[2 * rrow1];
      SLOTB(0, STEPB_O, rbA0);  SLOTB(1, STEPB_P, rbA0);
      SLOTB(2, STEPB_O, rbA0);  SLOTB(3, STEPB_P, rbA0);
      SLOTB(4, STEPB_O, rbA0);  SLOTB(5, STEPB_P, rbA0);
      SLOTB(6, STEPB_O, rbA0);  SLOTB(7, STEPB_P, rbA0);
      SLOTB(8, STEPB_O, rbA1);  SLOTB(9, STEPB_P, rbA1);
      SLOTB(10, STEPB_O, rbA1); SLOTB(11, STEPB_P, rbA1);
      SLOTB(12, STEPB_O, rbA1); SLOTB(13, STEPB_P, rbA1);
      SLOTB(14, STEPB_O, rbA1); SLOTB(15, STEPB_P, rbA1);
      rbA0 = rbB0; rbA1 = rbB1;
    }
    if (tt - 0 >= tm)  STEPB_P(q0,  RL(rbA0, 0));
    if (tt - 1 >= tm)  STEPB_P(q1,  RL(rbA0, 1));
    if (tt - 2 >= tm)  STEPB_P(q2,  RL(rbA0, 2));
    if (tt - 3 >= tm)  STEPB_P(q3,  RL(rbA0, 3));
    if (tt - 4 >= tm)  STEPB_P(q4,  RL(rbA0, 4));
    if (tt - 5 >= tm)  STEPB_P(q5,  RL(rbA0, 5));
    if (tt - 6 >= tm)  STEPB_P(q6,  RL(rbA0, 6));
    if (tt - 7 >= tm)  STEPB_P(q7,  RL(rbA0, 7));
    if (tt - 8 >= tm)  STEPB_P(q8,  RL(rbA1, 0));
    if (tt - 9 >= tm)  STEPB_P(q9,  RL(rbA1, 1));
    if (tt - 10 >= tm) STEPB_P(q10, RL(rbA1, 2));
    if (tt - 11 >= tm) STEPB_P(q11, RL(rbA1, 3));
    if (tt - 12 >= tm) STEPB_P(q12, RL(rbA1, 4));
    if (tt - 13 >= tm) STEPB_P(q13, RL(rbA1, 5));
    if (tt - 14 >= tm) STEPB_P(q14, RL(rbA1, 6));

    const float Ff = (float)F;
    Blog[sb + 0] = (b0 > 0.f) ? lg2(b0) + Ff : -1.0e30f;
    Blog[sb + 1] = (b1 > 0.f) ? lg2(b1) + Ff : -1.0e30f;
    Blog[sb + 2] = (b2 > 0.f) ? lg2(b2) + Ff : -1.0e30f;
    Blog[sb + 3] = (b3 > 0.f) ? lg2(b3) + Ff : -1.0e30f;
    Blog[sb + 4] = (b4 > 0.f) ? lg2(b4) + Ff : -1.0e30f;
    Blog[sb + 5] = (b5 > 0.f) ? lg2(b5) + Ff : -1.0e30f;
    Blog[sb + 6] = (b6 > 0.f) ? lg2(b6) + Ff : -1.0e30f;
    Blog[sb + 7] = (b7 > 0.f) ? lg2(b7) + Ff : -1.0e30f;
    if (lane == 63) Blog[512] = (bt > 0.f) ? lg2(bt) + Ff : -1.0e30f;
  }

  __syncthreads();

  if (wid == 0) {
    // log2 P = logsumexp2_s (Alog[s] + Blog[s])
    const int sb = 8 * lane;
    float t0 = Alog[sb + 0] + Blog[sb + 0];
    float t1 = Alog[sb + 1] + Blog[sb + 1];
    float t2 = Alog[sb + 2] + Blog[sb + 2];
    float t3 = Alog[sb + 3] + Blog[sb + 3];
    float t4 = Alog[sb + 4] + Blog[sb + 4];
    float t5 = Alog[sb + 5] + Blog[sb + 5];
    float t6 = Alog[sb + 6] + Blog[sb + 6];
    float t7 = Alog[sb + 7] + Blog[sb + 7];
    float t8 = (lane == 63) ? (Alog[512] + Blog[512]) : -1.0e30f;
    float M = fmaxf(fmaxf(fmaxf(t0, t1), fmaxf(t2, t3)),
                    fmaxf(fmaxf(t4, t5), fmaxf(fmaxf(t6, t7), t8)));
#pragma unroll
    for (int off = 32; off >= 1; off >>= 1) M = fmaxf(M, __shfl_xor(M, off));
    float sm = ex2(t0 - M) + ex2(t1 - M) + ex2(t2 - M) + ex2(t3 - M) +
               ex2(t4 - M) + ex2(t5 - M) + ex2(t6 - M) + ex2(t7 - M) +
               ex2(t8 - M);
#pragma unroll
    for (int off = 32; off >= 1; off >>= 1) sm += __shfl_xor(sm, off);
    if (lane == 0)
      out[b] = -0.6931471805599453f * (M + lg2(sm));
  }
}

extern "C" void kernel_launch(void* const* d_in, const int* in_sizes, int n_in,
                              void* d_out, int out_size, void* d_ws, size_t ws_size,
                              hipStream_t stream) {
  const int* labels = (const int*)d_in[0];
  const float* logits = (const float*)d_in[1];
  const int* widths = (const int*)d_in[2];
  const int* lengths = (const int*)d_in[3];
  float* out = (float*)d_out;

  // ws layout: [blanks2: B*T*2 fp32 = 512KB][packed: B*T*64 ushort4 = 32MB]
  float* blanks2 = (float*)d_ws;
  ushort4* packed = (ushort4*)((char*)d_ws + (size_t)B_ * T_ * 2 * sizeof(float));

  gather_pack<<<B_ * T_, 64, 0, stream>>>(logits, labels, blanks2, packed);
  ctc_dp<<<B_, 128, 0, stream>>>(packed, blanks2, labels, widths, lengths, out);
}

// Round 15
// 136.645 us; speedup vs baseline: 4.0296x; 1.3020x over previous
//
#include <hip/hip_runtime.h>
#include <math.h>

#define B_ 32
#define T_ 2048
#define C_ 96
#define L_ 256
#define BLANK 95

__device__ __forceinline__ float ex2(float x) {
  float r; asm("v_exp_f32 %0, %1" : "=v"(r) : "v"(x)); return r;
}
__device__ __forceinline__ float lg2(float x) {
  float r; asm("v_log_f32 %0, %1" : "=v"(r) : "v"(x)); return r;
}
__device__ __forceinline__ unsigned short f2bf(float f) {  // RNE f32->bf16
  unsigned u = __float_as_uint(f);
  return (unsigned short)((u + 0x7FFFu + ((u >> 16) & 1u)) >> 16);
}
__device__ __forceinline__ float bfu(unsigned short u) {
  return __uint_as_float((unsigned)u << 16);
}
// Wave shifts via DPP (VALU). 0x138 = WAVE_SHR1, 0x130 = WAVE_SHL1.
__device__ __forceinline__ float dpp_shr1_f(float x) {
  return __int_as_float(__builtin_amdgcn_update_dpp(
      0, __float_as_int(x), 0x138, 0xF, 0xF, false));
}
__device__ __forceinline__ int dpp_shr1_i(int x) {
  return __builtin_amdgcn_update_dpp(0, x, 0x138, 0xF, 0xF, false);
}
__device__ __forceinline__ float dpp_shl1_f(float x) {
  return __int_as_float(__builtin_amdgcn_update_dpp(
      0, __float_as_int(x), 0x130, 0xF, 0xF, false));
}
__device__ __forceinline__ int dpp_shl1_i(int x) {
  return __builtin_amdgcn_update_dpp(0, x, 0x130, 0xF, 0xF, false);
}
#define RL(V, J) __int_as_float(__builtin_amdgcn_readlane(__float_as_int(V), (J)))

// ---- Kernel 1: fused softmax + per-lane label-prob gather/pack ----
__global__ __launch_bounds__(64) void gather_pack(const float* __restrict__ logits,
                                                  const int* __restrict__ labels,
                                                  float* __restrict__ blanks2,
                                                  ushort4* __restrict__ packed) {
  const int tid = threadIdx.x;
  const int bt = blockIdx.x;  // b*T + t
  const int b = bt >> 11;
  const float* xr = logits + (size_t)bt * C_;
  float xa = xr[tid];
  float xb = (tid < 32) ? xr[64 + tid] : -1.0e30f;
  float m = fmaxf(xa, xb);
#pragma unroll
  for (int off = 32; off >= 1; off >>= 1) m = fmaxf(m, __shfl_xor(m, off));
  float ea = __expf(xa - m);
  float eb = (tid < 32) ? __expf(xb - m) : 0.f;
  float z = ea + eb;
#pragma unroll
  for (int off = 32; off >= 1; off >>= 1) z += __shfl_xor(z, off);
  float rz = 1.0f / z;
  __shared__ float sp[C_];
  sp[tid] = fmaf(ea, rz, 1e-7f);
  if (tid < 32) sp[64 + tid] = fmaf(eb, rz, 1e-7f);
  __syncthreads();
  const int4 lb = *reinterpret_cast<const int4*>(labels + (b << 8) + 4 * tid);
  ushort4 o;
  o.x = f2bf(sp[lb.x]); o.y = f2bf(sp[lb.y]);
  o.z = f2bf(sp[lb.z]); o.w = f2bf(sp[lb.w]);
  packed[(size_t)bt * 64 + tid] = o;
  if (tid < 2) blanks2[2 * bt + tid] = sp[BLANK];
}

// ---------------- Kernel 2: meet-in-the-middle CTC DP ----------------
// Grouped-frame protocol: frames (per-lane 2^F) are FROZEN within groups
// of 8 steps -> the per-step frame reconciliation chain (di/shift/rebase/
// norm + F-exchange DPP) disappears from the lean step. A SYNC block every
// 8 steps pins magnitudes (exact 2^-e), aligns frames to within D=4 of the
// sender (two DPP exchange rounds), and converts the in-flight boundary
// value into the new frame (clamped at 1e18 for the pathological cascade).
// Growth within a group <= 2^(9+8*4+8) from a post-sync start of <=2; all
// values provably < 2^128. Bwd ships premultiplied products (bp0-equiv and
// nb1*p1_next) so the receiver needs no pn1 DPP.

#define LEANF(QU, QB, DI) do {                                               \
    const float b1a = ldexpf(b1_raw, (DI));                                  \
    const float na7 = fmaf(m7, a5, a7 + a6) * p7;                            \
    const float b1n = dpp_shr1_f(na7);                                       \
    at = (at + a7) * pb;                                                     \
    a6 = (a6 + a5) * pb;                                                     \
    a5 = fmaf(m5, a3, a5 + a4) * p5;                                         \
    a4 = (a4 + a3) * pb;                                                     \
    a3 = fmaf(m3, a1, a3 + a2) * p3;                                         \
    a2 = (a2 + a1) * pb;                                                     \
    a1 = fmaf(m1, b1a, a1 + a0) * p1;                                        \
    a0 = (a0 + b1a) * pb;                                                    \
    a7 = na7;                                                                \
    b1_raw = b1n;                                                            \
    p1 = bfu((QU).x); p3 = bfu((QU).y); p5 = bfu((QU).z); p7 = bfu((QU).w);  \
    pb = (QB);                                                               \
  } while (0)

#define SYNCF do {                                                           \
    const float mA = fmaxf(fmaxf(a0, a1), a2);                               \
    const float mB = fmaxf(fmaxf(a3, a4), a5);                               \
    const float mC = fmaxf(fmaxf(a6, a7), at);                               \
    const float m8 = fmaxf(fmaxf(mA, mB), mC);                               \
    int e = (int)((__float_as_uint(m8) >> 23) & 255u) - 126;                 \
    e = (e < -60) ? -60 : e;                                                 \
    const float scl = ldexpf(1.0f, -e);                                      \
    a0 *= scl; a1 *= scl; a2 *= scl; a3 *= scl; a4 *= scl;                   \
    a5 *= scl; a6 *= scl; a7 *= scl; at *= scl;                              \
    F += e;                                                                  \
    const int Fp1 = dpp_shr1_i(F);                                           \
    const int d1 = g0 ? 0 : (Fp1 - F);                                       \
    const int s1 = (d1 > 4) ? (d1 - 4) : 0;                                  \
    a0 = ldexpf(a0, -s1); a1 = ldexpf(a1, -s1); a2 = ldexpf(a2, -s1);        \
    a3 = ldexpf(a3, -s1); a4 = ldexpf(a4, -s1); a5 = ldexpf(a5, -s1);        \
    a6 = ldexpf(a6, -s1); a7 = ldexpf(a7, -s1); at = ldexpf(at, -s1);        \
    F += s1;                                                                 \
    const int Fp2 = dpp_shr1_i(F);                                           \
    const int d2 = g0 ? 0 : (Fp2 - F);                                       \
    const int s2 = (d2 > 4) ? (d2 - 4) : 0;                                  \
    a0 = ldexpf(a0, -s2); a1 = ldexpf(a1, -s2); a2 = ldexpf(a2, -s2);        \
    a3 = ldexpf(a3, -s2); a4 = ldexpf(a4, -s2); a5 = ldexpf(a5, -s2);        \
    a6 = ldexpf(a6, -s2); a7 = ldexpf(a7, -s2); at = ldexpf(at, -s2);        \
    F += s2;                                                                 \
    const int di_c = di_g - (e + s1 + s2);                                   \
    b1_raw = fminf(ldexpf(b1_raw, di_c), 1e18f);                             \
    di_g = d2 - s2;                                                          \
  } while (0)

#define SLOTF(U, DI, RB) do {                                                \
    LEANF(q##U, RL(RB, (U) & 7), DI);                                        \
    int trow = tt + 17 + U;                                                  \
    trow = (trow > T_ - 1) ? (T_ - 1) : trow;                                \
    q##U = gp[(size_t)trow * 64 + lane];                                     \
  } while (0)

// Bwd lean: receives u0 = sender's nb0 (beta[8l+8]) and v = sender's
// nb1*p1_next (= beta[8l+9]*p_t[8l+9], since blank probs are row-shared
// and sender's p1 IS receiver's pn1).
#define LEANB(QU, QB, DI) do {                                               \
    const float x0 = ldexpf(u0, (DI));                                       \
    const float yv = ldexpf(v, (DI));                                        \
    const float bp0 = b0 * pb, bp1 = b1 * p1, bp2 = b2 * pb, bp3 = b3 * p3,  \
                bp4 = b4 * pb, bp5 = b5 * p5, bp6 = b6 * pb, bp7 = b7 * p7,  \
                bpt = bt * pb;                                               \
    const float x0e = g63 ? bpt : (x0 * pb);                                 \
    const float nb0 = bp0 + bp1;                                             \
    const float nb1 = fmaf(m3, bp3, bp1 + bp2);                              \
    b2 = bp2 + bp3;                                                          \
    b3 = fmaf(m5, bp5, bp3 + bp4);                                           \
    b4 = bp4 + bp5;                                                          \
    b5 = fmaf(m7, bp7, bp5 + bp6);                                           \
    b6 = bp6 + bp7;                                                          \
    b7 = fmaf(mn, yv, bp7 + x0e);                                            \
    bt = bpt;                                                                \
    b0 = nb0; b1 = nb1;                                                      \
    p1 = bfu((QU).x); p3 = bfu((QU).y); p5 = bfu((QU).z); p7 = bfu((QU).w);  \
    pb = (QB);                                                               \
    u0 = dpp_shl1_f(nb0);                                                    \
    v = dpp_shl1_f(nb1 * p1);                                                \
  } while (0)

#define SYNCB do {                                                           \
    const float mA = fmaxf(fmaxf(b0, b1), b2);                               \
    const float mB = fmaxf(fmaxf(b3, b4), b5);                               \
    const float mC = fmaxf(fmaxf(b6, b7), bt);                               \
    const float m8 = fmaxf(fmaxf(mA, mB), mC);                               \
    int e = (int)((__float_as_uint(m8) >> 23) & 255u) - 126;                 \
    e = (e < -60) ? -60 : e;                                                 \
    const float scl = ldexpf(1.0f, -e);                                      \
    b0 *= scl; b1 *= scl; b2 *= scl; b3 *= scl; b4 *= scl;                   \
    b5 *= scl; b6 *= scl; b7 *= scl; bt *= scl;                              \
    F += e;                                                                  \
    const int Fp1 = dpp_shl1_i(F);                                           \
    const int d1 = g63 ? 0 : (Fp1 - F);                                      \
    const int s1 = (d1 > 4) ? (d1 - 4) : 0;                                  \
    b0 = ldexpf(b0, -s1); b1 = ldexpf(b1, -s1); b2 = ldexpf(b2, -s1);        \
    b3 = ldexpf(b3, -s1); b4 = ldexpf(b4, -s1); b5 = ldexpf(b5, -s1);        \
    b6 = ldexpf(b6, -s1); b7 = ldexpf(b7, -s1); bt = ldexpf(bt, -s1);        \
    F += s1;                                                                 \
    const int Fp2 = dpp_shl1_i(F);                                           \
    const int d2 = g63 ? 0 : (Fp2 - F);                                      \
    const int s2 = (d2 > 4) ? (d2 - 4) : 0;                                  \
    b0 = ldexpf(b0, -s2); b1 = ldexpf(b1, -s2); b2 = ldexpf(b2, -s2);        \
    b3 = ldexpf(b3, -s2); b4 = ldexpf(b4, -s2); b5 = ldexpf(b5, -s2);        \
    b6 = ldexpf(b6, -s2); b7 = ldexpf(b7, -s2); bt = ldexpf(bt, -s2);        \
    F += s2;                                                                 \
    const int di_c = di_g - (e + s1 + s2);                                   \
    u0 = fminf(ldexpf(u0, di_c), 1e18f);                                     \
    v = fminf(ldexpf(v, di_c), 1e18f);                                       \
    di_g = d2 - s2;                                                          \
  } while (0)

#define SLOTB(U, DI, RB) do {                                                \
    LEANB(q##U, RL(RB, (U) & 7), DI);                                        \
    int trow = tt - 17 - U;                                                  \
    trow = (trow < 0) ? 0 : trow;                                            \
    q##U = gp[(size_t)trow * 64 + lane];                                     \
  } while (0)

__global__ __launch_bounds__(128) void ctc_dp(const ushort4* __restrict__ packed,
                                              const float* __restrict__ blanks2,
                                              const int* __restrict__ labels,
                                              const int* __restrict__ widths,
                                              const int* __restrict__ lengths,
                                              float* __restrict__ out) {
  __shared__ float Alog[513];
  __shared__ float Blog[513];
  const int b = blockIdx.x;
  const int tid = threadIdx.x;
  const int wid = tid >> 6;
  const int lane = tid & 63;
  const int l8 = lane & 7;
  const int lpar = lane & 1;
  const bool g0 = (lane == 0);
  const bool g63 = (lane == 63);
  const int Tb = widths[b] >> 3;     // in [1536, 2048]
  const int s_end = 2 * lengths[b];
  const int tm = (Tb * 67) >> 7;     // meet row (fwd/bwd cost-balanced)
  const int* lab = labels + (b << 8);
  const int4 lb = *reinterpret_cast<const int4*>(lab + 4 * lane);
  const int pw = __shfl_up(lb.w, 1);
  const float m1 = (lane > 0 && lb.x != pw) ? 1.f : 0.f;
  const float m3 = (lb.y != lb.x) ? 1.f : 0.f;
  const float m5 = (lb.z != lb.y) ? 1.f : 0.f;
  const float m7 = (lb.w != lb.z) ? 1.f : 0.f;
  const float mdn = __shfl_down(m1, 1);
  const float mn = g63 ? 0.f : mdn;  // skip mask for s+2 = 8l+9

  const ushort4* gp = packed + (size_t)b * (T_ * 64);
  const float* gb = blanks2 + b * (2 * T_);

  if (wid == 0) {
    // ---------------- forward alpha: rows 0 .. tm-1 ----------------
    const ushort4 u0v = gp[lane];
    const float bl0 = gb[lpar];
    const ushort4 u1v = gp[64 + lane];
    const float bl1 = gb[2 + lpar];
    ushort4 q0 = gp[2 * 64 + lane],  q1 = gp[3 * 64 + lane];
    ushort4 q2 = gp[4 * 64 + lane],  q3 = gp[5 * 64 + lane];
    ushort4 q4 = gp[6 * 64 + lane],  q5 = gp[7 * 64 + lane];
    ushort4 q6 = gp[8 * 64 + lane],  q7 = gp[9 * 64 + lane];
    ushort4 q8 = gp[10 * 64 + lane], q9 = gp[11 * 64 + lane];
    ushort4 q10 = gp[12 * 64 + lane], q11 = gp[13 * 64 + lane];
    ushort4 q12 = gp[14 * 64 + lane], q13 = gp[15 * 64 + lane];
    ushort4 q14 = gp[16 * 64 + lane], q15 = gp[17 * 64 + lane];
    float rbA0 = gb[2 * (2 + l8)];
    float rbA1 = gb[2 * (10 + l8)];

    float a0 = 0.f, a1 = 0.f, a2 = 0.f, a3 = 0.f;
    float a4 = 0.f, a5 = 0.f, a6 = 0.f, a7 = 0.f, at = 0.f;
    int F = 0, di_g = 0;
    float b1_raw = 0.f;
    if (g0) { a0 = bl0; a1 = bfu(u0v.x); }
    float pb = bl1;
    float p1 = bfu(u1v.x), p3 = bfu(u1v.y), p5 = bfu(u1v.z), p7 = bfu(u1v.w);

    int tt = 1;
    for (; tt + 16 <= tm; tt += 16) {
      int rrow0 = tt + 17 + l8; rrow0 = (rrow0 > T_ - 1) ? (T_ - 1) : rrow0;
      int rrow1 = tt + 25 + l8; rrow1 = (rrow1 > T_ - 1) ? (T_ - 1) : rrow1;
      const float rbB0 = gb[2 * rrow0];
      const float rbB1 = gb[2 * rrow1];
      SLOTF(0, 0, rbA0);     SLOTF(1, di_g, rbA0);
      SLOTF(2, di_g, rbA0);  SLOTF(3, di_g, rbA0);
      SLOTF(4, di_g, rbA0);  SLOTF(5, di_g, rbA0);
      SLOTF(6, di_g, rbA0);  SLOTF(7, di_g, rbA0);
      SYNCF;
      SLOTF(8, 0, rbA1);     SLOTF(9, di_g, rbA1);
      SLOTF(10, di_g, rbA1); SLOTF(11, di_g, rbA1);
      SLOTF(12, di_g, rbA1); SLOTF(13, di_g, rbA1);
      SLOTF(14, di_g, rbA1); SLOTF(15, di_g, rbA1);
      SYNCF;
      rbA0 = rbB0; rbA1 = rbB1;
    }
    if (tt + 0 < tm) LEANF(q0, RL(rbA0, 0), 0);
    if (tt + 1 < tm) LEANF(q1, RL(rbA0, 1), di_g);
    if (tt + 2 < tm) LEANF(q2, RL(rbA0, 2), di_g);
    if (tt + 3 < tm) LEANF(q3, RL(rbA0, 3), di_g);
    if (tt + 4 < tm) LEANF(q4, RL(rbA0, 4), di_g);
    if (tt + 5 < tm) LEANF(q5, RL(rbA0, 5), di_g);
    if (tt + 6 < tm) LEANF(q6, RL(rbA0, 6), di_g);
    if (tt + 7 < tm) LEANF(q7, RL(rbA0, 7), di_g);
    SYNCF;
    if (tt + 8 < tm)  LEANF(q8,  RL(rbA1, 0), 0);
    if (tt + 9 < tm)  LEANF(q9,  RL(rbA1, 1), di_g);
    if (tt + 10 < tm) LEANF(q10, RL(rbA1, 2), di_g);
    if (tt + 11 < tm) LEANF(q11, RL(rbA1, 3), di_g);
    if (tt + 12 < tm) LEANF(q12, RL(rbA1, 4), di_g);
    if (tt + 13 < tm) LEANF(q13, RL(rbA1, 5), di_g);
    if (tt + 14 < tm) LEANF(q14, RL(rbA1, 6), di_g);

    const float Ff = (float)F;
    const int sb = 8 * lane;
    Alog[sb + 0] = (a0 > 0.f) ? lg2(a0) + Ff : -1.0e30f;
    Alog[sb + 1] = (a1 > 0.f) ? lg2(a1) + Ff : -1.0e30f;
    Alog[sb + 2] = (a2 > 0.f) ? lg2(a2) + Ff : -1.0e30f;
    Alog[sb + 3] = (a3 > 0.f) ? lg2(a3) + Ff : -1.0e30f;
    Alog[sb + 4] = (a4 > 0.f) ? lg2(a4) + Ff : -1.0e30f;
    Alog[sb + 5] = (a5 > 0.f) ? lg2(a5) + Ff : -1.0e30f;
    Alog[sb + 6] = (a6 > 0.f) ? lg2(a6) + Ff : -1.0e30f;
    Alog[sb + 7] = (a7 > 0.f) ? lg2(a7) + Ff : -1.0e30f;
    if (g63) Alog[512] = (at > 0.f) ? lg2(at) + Ff : -1.0e30f;
  } else {
    // ---------------- backward beta: rows Tb-1 .. tm ----------------
    const ushort4 uiv = gp[(size_t)(Tb - 1) * 64 + lane];
    const float bli = gb[2 * (Tb - 1) + lpar];
    ushort4 q0 = gp[(size_t)(Tb - 2) * 64 + lane],  q1 = gp[(size_t)(Tb - 3) * 64 + lane];
    ushort4 q2 = gp[(size_t)(Tb - 4) * 64 + lane],  q3 = gp[(size_t)(Tb - 5) * 64 + lane];
    ushort4 q4 = gp[(size_t)(Tb - 6) * 64 + lane],  q5 = gp[(size_t)(Tb - 7) * 64 + lane];
    ushort4 q6 = gp[(size_t)(Tb - 8) * 64 + lane],  q7 = gp[(size_t)(Tb - 9) * 64 + lane];
    ushort4 q8 = gp[(size_t)(Tb - 10) * 64 + lane], q9 = gp[(size_t)(Tb - 11) * 64 + lane];
    ushort4 q10 = gp[(size_t)(Tb - 12) * 64 + lane], q11 = gp[(size_t)(Tb - 13) * 64 + lane];
    ushort4 q12 = gp[(size_t)(Tb - 14) * 64 + lane], q13 = gp[(size_t)(Tb - 15) * 64 + lane];
    ushort4 q14 = gp[(size_t)(Tb - 16) * 64 + lane], q15 = gp[(size_t)(Tb - 17) * 64 + lane];
    float rbA0 = gb[2 * (Tb - 2 - l8)];
    float rbA1 = gb[2 * (Tb - 10 - l8)];

    const int sb = 8 * lane;
    float b0 = (sb + 0 == s_end || sb + 0 == s_end - 1) ? 1.f : 0.f;
    float b1 = (sb + 1 == s_end || sb + 1 == s_end - 1) ? 1.f : 0.f;
    float b2 = (sb + 2 == s_end || sb + 2 == s_end - 1) ? 1.f : 0.f;
    float b3 = (sb + 3 == s_end || sb + 3 == s_end - 1) ? 1.f : 0.f;
    float b4 = (sb + 4 == s_end || sb + 4 == s_end - 1) ? 1.f : 0.f;
    float b5 = (sb + 5 == s_end || sb + 5 == s_end - 1) ? 1.f : 0.f;
    float b6 = (sb + 6 == s_end || sb + 6 == s_end - 1) ? 1.f : 0.f;
    float b7 = (sb + 7 == s_end || sb + 7 == s_end - 1) ? 1.f : 0.f;
    float bt = (g63 && s_end == 512) ? 1.f : 0.f;
    int F = 0, di_g = 0;

    float pb = bli;  // probs of row Tb-1 (first consumed)
    float p1 = bfu(uiv.x), p3 = bfu(uiv.y), p5 = bfu(uiv.z), p7 = bfu(uiv.w);
    float u0 = dpp_shl1_f(b0);
    float v = dpp_shl1_f(b1 * p1);

    int tt = Tb - 1;
    for (; tt - 15 >= tm; tt -= 16) {
      int rrow0 = tt - 17 - l8; rrow0 = (rrow0 < 0) ? 0 : rrow0;
      int rrow1 = tt - 25 - l8; rrow1 = (rrow1 < 0) ? 0 : rrow1;
      const float rbB0 = gb[2 * rrow0];
      const float rbB1 = gb[2 * rrow1];
      SLOTB(0, 0, rbA0);     SLOTB(1, di_g, rbA0);
      SLOTB(2, di_g, rbA0);  SLOTB(3, di_g, rbA0);
      SLOTB(4, di_g, rbA0);  SLOTB(5, di_g, rbA0);
      SLOTB(6, di_g, rbA0);  SLOTB(7, di_g, rbA0);
      SYNCB;
      SLOTB(8, 0, rbA1);     SLOTB(9, di_g, rbA1);
      SLOTB(10, di_g, rbA1); SLOTB(11, di_g, rbA1);
      SLOTB(12, di_g, rbA1); SLOTB(13, di_g, rbA1);
      SLOTB(14, di_g, rbA1); SLOTB(15, di_g, rbA1);
      SYNCB;
      rbA0 = rbB0; rbA1 = rbB1;
    }
    if (tt - 0 >= tm) LEANB(q0, RL(rbA0, 0), 0);
    if (tt - 1 >= tm) LEANB(q1, RL(rbA0, 1), di_g);
    if (tt - 2 >= tm) LEANB(q2, RL(rbA0, 2), di_g);
    if (tt - 3 >= tm) LEANB(q3, RL(rbA0, 3), di_g);
    if (tt - 4 >= tm) LEANB(q4, RL(rbA0, 4), di_g);
    if (tt - 5 >= tm) LEANB(q5, RL(rbA0, 5), di_g);
    if (tt - 6 >= tm) LEANB(q6, RL(rbA0, 6), di_g);
    if (tt - 7 >= tm) LEANB(q7, RL(rbA0, 7), di_g);
    SYNCB;
    if (tt - 8 >= tm)  LEANB(q8,  RL(rbA1, 0), 0);
    if (tt - 9 >= tm)  LEANB(q9,  RL(rbA1, 1), di_g);
    if (tt - 10 >= tm) LEANB(q10, RL(rbA1, 2), di_g);
    if (tt - 11 >= tm) LEANB(q11, RL(rbA1, 3), di_g);
    if (tt - 12 >= tm) LEANB(q12, RL(rbA1, 4), di_g);
    if (tt - 13 >= tm) LEANB(q13, RL(rbA1, 5), di_g);
    if (tt - 14 >= tm) LEANB(q14, RL(rbA1, 6), di_g);

    const float Ff = (float)F;
    Blog[sb + 0] = (b0 > 0.f) ? lg2(b0) + Ff : -1.0e30f;
    Blog[sb + 1] = (b1 > 0.f) ? lg2(b1) + Ff : -1.0e30f;
    Blog[sb + 2] = (b2 > 0.f) ? lg2(b2) + Ff : -1.0e30f;
    Blog[sb + 3] = (b3 > 0.f) ? lg2(b3) + Ff : -1.0e30f;
    Blog[sb + 4] = (b4 > 0.f) ? lg2(b4) + Ff : -1.0e30f;
    Blog[sb + 5] = (b5 > 0.f) ? lg2(b5) + Ff : -1.0e30f;
    Blog[sb + 6] = (b6 > 0.f) ? lg2(b6) + Ff : -1.0e30f;
    Blog[sb + 7] = (b7 > 0.f) ? lg2(b7) + Ff : -1.0e30f;
    if (g63) Blog[512] = (bt > 0.f) ? lg2(bt) + Ff : -1.0e30f;
  }

  __syncthreads();

  if (wid == 0) {
    // log2 P = logsumexp2_s (Alog[s] + Blog[s])
    const int sb = 8 * lane;
    float t0 = Alog[sb + 0] + Blog[sb + 0];
    float t1 = Alog[sb + 1] + Blog[sb + 1];
    float t2 = Alog[sb + 2] + Blog[sb + 2];
    float t3 = Alog[sb + 3] + Blog[sb + 3];
    float t4 = Alog[sb + 4] + Blog[sb + 4];
    float t5 = Alog[sb + 5] + Blog[sb + 5];
    float t6 = Alog[sb + 6] + Blog[sb + 6];
    float t7 = Alog[sb + 7] + Blog[sb + 7];
    float t8 = g63 ? (Alog[512] + Blog[512]) : -1.0e30f;
    float M = fmaxf(fmaxf(fmaxf(t0, t1), fmaxf(t2, t3)),
                    fmaxf(fmaxf(t4, t5), fmaxf(fmaxf(t6, t7), t8)));
#pragma unroll
    for (int off = 32; off >= 1; off >>= 1) M = fmaxf(M, __shfl_xor(M, off));
    float sm = ex2(t0 - M) + ex2(t1 - M) + ex2(t2 - M) + ex2(t3 - M) +
               ex2(t4 - M) + ex2(t5 - M) + ex2(t6 - M) + ex2(t7 - M) +
               ex2(t8 - M);
#pragma unroll
    for (int off = 32; off >= 1; off >>= 1) sm += __shfl_xor(sm, off);
    if (lane == 0)
      out[b] = -0.6931471805599453f * (M + lg2(sm));
  }
}

extern "C" void kernel_launch(void* const* d_in, const int* in_sizes, int n_in,
                              void* d_out, int out_size, void* d_ws, size_t ws_size,
                              hipStream_t stream) {
  const int* labels = (const int*)d_in[0];
  const float* logits = (const float*)d_in[1];
  const int* widths = (const int*)d_in[2];
  const int* lengths = (const int*)d_in[3];
  float* out = (float*)d_out;

  // ws layout: [blanks2: B*T*2 fp32 = 512KB][packed: B*T*64 ushort4 = 32MB]
  float* blanks2 = (float*)d_ws;
  ushort4* packed = (ushort4*)((char*)d_ws + (size_t)B_ * T_ * 2 * sizeof(float));

  gather_pack<<<B_ * T_, 64, 0, stream>>>(logits, labels, blanks2, packed);
  ctc_dp<<<B_, 128, 0, stream>>>(packed, blanks2, labels, widths, lengths, out);
}

// Round 17
// 119.724 us; speedup vs baseline: 4.5991x; 1.1413x over previous
//
#include <hip/hip_runtime.h>
#include <math.h>

#define B_ 32
#define T_ 2048
#define C_ 96
#define L_ 256
#define BLANK 95

__device__ __forceinline__ float ex2(float x) {
  float r; asm("v_exp_f32 %0, %1" : "=v"(r) : "v"(x)); return r;
}
__device__ __forceinline__ float lg2(float x) {
  float r; asm("v_log_f32 %0, %1" : "=v"(r) : "v"(x)); return r;
}
__device__ __forceinline__ unsigned short f2bf(float f) {  // RNE f32->bf16
  unsigned u = __float_as_uint(f);
  return (unsigned short)((u + 0x7FFFu + ((u >> 16) & 1u)) >> 16);
}
__device__ __forceinline__ float bfu(unsigned short u) {
  return __uint_as_float((unsigned)u << 16);
}
// Wave shifts via DPP (VALU). 0x138 = WAVE_SHR1, 0x130 = WAVE_SHL1.
__device__ __forceinline__ float dpp_shr1_f(float x) {
  return __int_as_float(__builtin_amdgcn_update_dpp(
      0, __float_as_int(x), 0x138, 0xF, 0xF, false));
}
__device__ __forceinline__ int dpp_shr1_i(int x) {
  return __builtin_amdgcn_update_dpp(0, x, 0x138, 0xF, 0xF, false);
}
__device__ __forceinline__ float dpp_shl1_f(float x) {
  return __int_as_float(__builtin_amdgcn_update_dpp(
      0, __float_as_int(x), 0x130, 0xF, 0xF, false));
}
__device__ __forceinline__ int dpp_shl1_i(int x) {
  return __builtin_amdgcn_update_dpp(0, x, 0x130, 0xF, 0xF, false);
}
#define RL(V, J) __int_as_float(__builtin_amdgcn_readlane(__float_as_int(V), (J)))

// ---- Kernel 1: fused softmax + per-lane label-prob gather/pack ----
__global__ __launch_bounds__(64) void gather_pack(const float* __restrict__ logits,
                                                  const int* __restrict__ labels,
                                                  float* __restrict__ blanks2,
                                                  ushort4* __restrict__ packed) {
  const int tid = threadIdx.x;
  const int bt = blockIdx.x;  // b*T + t
  const int b = bt >> 11;
  const float* xr = logits + (size_t)bt * C_;
  float xa = xr[tid];
  float xb = (tid < 32) ? xr[64 + tid] : -1.0e30f;
  float m = fmaxf(xa, xb);
#pragma unroll
  for (int off = 32; off >= 1; off >>= 1) m = fmaxf(m, __shfl_xor(m, off));
  float ea = __expf(xa - m);
  float eb = (tid < 32) ? __expf(xb - m) : 0.f;
  float z = ea + eb;
#pragma unroll
  for (int off = 32; off >= 1; off >>= 1) z += __shfl_xor(z, off);
  float rz = 1.0f / z;
  __shared__ float sp[C_];
  sp[tid] = fmaf(ea, rz, 1e-7f);
  if (tid < 32) sp[64 + tid] = fmaf(eb, rz, 1e-7f);
  __syncthreads();
  const int4 lb = *reinterpret_cast<const int4*>(labels + (b << 8) + 4 * tid);
  ushort4 o;
  o.x = f2bf(sp[lb.x]); o.y = f2bf(sp[lb.y]);
  o.z = f2bf(sp[lb.z]); o.w = f2bf(sp[lb.w]);
  packed[(size_t)bt * 64 + tid] = o;
  if (tid < 2) blanks2[2 * bt + tid] = sp[BLANK];
}

// ---------------- Kernel 2: meet-in-the-middle CTC DP ----------------
// Grouped-frame protocol, groups of 16: frames frozen in-group; SYNC every
// 16 steps pins via ONE merged exact rebase ldexp(a, -(e+s1+s2)) and aligns
// frames (two DPP F-exchange rounds, D=4). e is UNCLAMPED (e >= -126
// naturally): the merged ldexp rebase is exact for any shift, so the pin
// always fully renormalizes -- no decay ratchet (R16's -100 clamp lost to
// the typical ~106-bit/group decay and flushed the whole frontier).
// Dead lanes: alignment rounds pull their F to within 4 of the sender
// every sync, so di_g <= 4 and revival inflow lands correctly scaled.
// In-flight conversion clamped at 1e9 (2^30): worst in-group cascade gain
// 2^64 from a 2^30 start = 2^95 < 2^128 -> provably finite.
// Row clamps removed: fwd reads rows <= tm+16 <= 1089 < 2048; bwd reads
// rows >= tm-17 >= 786 > 0 (tm = 0.523*Tb, Tb in [1536,2048]).

#define LEANF(QU, QB, DI) do {                                               \
    const float b1a = ldexpf(b1_raw, (DI));                                  \
    const float na7 = fmaf(m7, a5, a7 + a6) * p7;                            \
    const float b1n = dpp_shr1_f(na7);                                       \
    at = (at + a7) * pb;                                                     \
    a6 = (a6 + a5) * pb;                                                     \
    a5 = fmaf(m5, a3, a5 + a4) * p5;                                         \
    a4 = (a4 + a3) * pb;                                                     \
    a3 = fmaf(m3, a1, a3 + a2) * p3;                                         \
    a2 = (a2 + a1) * pb;                                                     \
    a1 = fmaf(m1, b1a, a1 + a0) * p1;                                        \
    a0 = (a0 + b1a) * pb;                                                    \
    a7 = na7;                                                                \
    b1_raw = b1n;                                                            \
    p1 = bfu((QU).x); p3 = bfu((QU).y); p5 = bfu((QU).z); p7 = bfu((QU).w);  \
    pb = (QB);                                                               \
  } while (0)

#define SYNCF do {                                                           \
    const float mA = fmaxf(fmaxf(a0, a1), a2);                               \
    const float mB = fmaxf(fmaxf(a3, a4), a5);                               \
    const float mC = fmaxf(fmaxf(a6, a7), at);                               \
    const float m8 = fmaxf(fmaxf(mA, mB), mC);                               \
    const int e = (int)((__float_as_uint(m8) >> 23) & 255u) - 126;           \
    F += e;                                                                  \
    const int Fp1 = dpp_shr1_i(F);                                           \
    const int d1 = g0 ? 0 : (Fp1 - F);                                       \
    const int s1 = (d1 > 4) ? (d1 - 4) : 0;                                  \
    F += s1;                                                                 \
    const int Fp2 = dpp_shr1_i(F);                                           \
    const int d2 = g0 ? 0 : (Fp2 - F);                                       \
    const int s2 = (d2 > 4) ? (d2 - 4) : 0;                                  \
    F += s2;                                                                 \
    const int sh = e + s1 + s2;                                              \
    a0 = ldexpf(a0, -sh); a1 = ldexpf(a1, -sh); a2 = ldexpf(a2, -sh);        \
    a3 = ldexpf(a3, -sh); a4 = ldexpf(a4, -sh); a5 = ldexpf(a5, -sh);        \
    a6 = ldexpf(a6, -sh); a7 = ldexpf(a7, -sh); at = ldexpf(at, -sh);        \
    b1_raw = fminf(ldexpf(b1_raw, di_g - sh), 1e9f);                         \
    di_g = d2 - s2;                                                          \
  } while (0)

#define SLOTF(U, DI, RB) do {                                                \
    LEANF(q##U, RL(RB, (U) & 7), DI);                                        \
    q##U = gp[(size_t)(tt + 17 + U) * 64 + lane];                            \
  } while (0)

// Bwd lean: u0 = sender's nb0 (beta[8l+8]); v = sender's nb1*p1_next
// (= beta[8l+9]*p_t[8l+9]).
#define LEANB(QU, QB, DI) do {                                               \
    const float x0 = ldexpf(u0, (DI));                                       \
    const float yv = ldexpf(v, (DI));                                        \
    const float bp0 = b0 * pb, bp1 = b1 * p1, bp2 = b2 * pb, bp3 = b3 * p3,  \
                bp4 = b4 * pb, bp5 = b5 * p5, bp6 = b6 * pb, bp7 = b7 * p7,  \
                bpt = bt * pb;                                               \
    const float x0e = g63 ? bpt : (x0 * pb);                                 \
    const float nb0 = bp0 + bp1;                                             \
    const float nb1 = fmaf(m3, bp3, bp1 + bp2);                              \
    b2 = bp2 + bp3;                                                          \
    b3 = fmaf(m5, bp5, bp3 + bp4);                                           \
    b4 = bp4 + bp5;                                                          \
    b5 = fmaf(m7, bp7, bp5 + bp6);                                           \
    b6 = bp6 + bp7;                                                          \
    b7 = fmaf(mn, yv, bp7 + x0e);                                            \
    bt = bpt;                                                                \
    b0 = nb0; b1 = nb1;                                                      \
    p1 = bfu((QU).x); p3 = bfu((QU).y); p5 = bfu((QU).z); p7 = bfu((QU).w);  \
    pb = (QB);                                                               \
    u0 = dpp_shl1_f(nb0);                                                    \
    v = dpp_shl1_f(nb1 * p1);                                                \
  } while (0)

#define SYNCB do {                                                           \
    const float mA = fmaxf(fmaxf(b0, b1), b2);                               \
    const float mB = fmaxf(fmaxf(b3, b4), b5);                               \
    const float mC = fmaxf(fmaxf(b6, b7), bt);                               \
    const float m8 = fmaxf(fmaxf(mA, mB), mC);                               \
    const int e = (int)((__float_as_uint(m8) >> 23) & 255u) - 126;           \
    F += e;                                                                  \
    const int Fp1 = dpp_shl1_i(F);                                           \
    const int d1 = g63 ? 0 : (Fp1 - F);                                      \
    const int s1 = (d1 > 4) ? (d1 - 4) : 0;                                  \
    F += s1;                                                                 \
    const int Fp2 = dpp_shl1_i(F);                                           \
    const int d2 = g63 ? 0 : (Fp2 - F);                                      \
    const int s2 = (d2 > 4) ? (d2 - 4) : 0;                                  \
    F += s2;                                                                 \
    const int sh = e + s1 + s2;                                              \
    b0 = ldexpf(b0, -sh); b1 = ldexpf(b1, -sh); b2 = ldexpf(b2, -sh);        \
    b3 = ldexpf(b3, -sh); b4 = ldexpf(b4, -sh); b5 = ldexpf(b5, -sh);        \
    b6 = ldexpf(b6, -sh); b7 = ldexpf(b7, -sh); bt = ldexpf(bt, -sh);        \
    u0 = fminf(ldexpf(u0, di_g - sh), 1e9f);                                 \
    v = fminf(ldexpf(v, di_g - sh), 1e9f);                                   \
    di_g = d2 - s2;                                                          \
  } while (0)

#define SLOTB(U, DI, RB) do {                                                \
    LEANB(q##U, RL(RB, (U) & 7), DI);                                        \
    q##U = gp[(size_t)(tt - 17 - U) * 64 + lane];                            \
  } while (0)

__global__ __launch_bounds__(128) void ctc_dp(const ushort4* __restrict__ packed,
                                              const float* __restrict__ blanks2,
                                              const int* __restrict__ labels,
                                              const int* __restrict__ widths,
                                              const int* __restrict__ lengths,
                                              float* __restrict__ out) {
  __shared__ float Alog[513];
  __shared__ float Blog[513];
  const int b = blockIdx.x;
  const int tid = threadIdx.x;
  const int wid = tid >> 6;
  const int lane = tid & 63;
  const int l8 = lane & 7;
  const int lpar = lane & 1;
  const bool g0 = (lane == 0);
  const bool g63 = (lane == 63);
  const int Tb = widths[b] >> 3;     // in [1536, 2048]
  const int s_end = 2 * lengths[b];
  const int tm = (Tb * 67) >> 7;     // meet row (fwd/bwd cost-balanced)
  const int* lab = labels + (b << 8);
  const int4 lb = *reinterpret_cast<const int4*>(lab + 4 * lane);
  const int pw = __shfl_up(lb.w, 1);
  const float m1 = (lane > 0 && lb.x != pw) ? 1.f : 0.f;
  const float m3 = (lb.y != lb.x) ? 1.f : 0.f;
  const float m5 = (lb.z != lb.y) ? 1.f : 0.f;
  const float m7 = (lb.w != lb.z) ? 1.f : 0.f;
  const float mdn = __shfl_down(m1, 1);
  const float mn = g63 ? 0.f : mdn;  // skip mask for s+2 = 8l+9

  const ushort4* gp = packed + (size_t)b * (T_ * 64);
  const float* gb = blanks2 + b * (2 * T_);

  if (wid == 0) {
    // ---------------- forward alpha: rows 0 .. tm-1 ----------------
    const ushort4 u0v = gp[lane];
    const float bl0 = gb[lpar];
    const ushort4 u1v = gp[64 + lane];
    const float bl1 = gb[2 + lpar];
    ushort4 q0 = gp[2 * 64 + lane],  q1 = gp[3 * 64 + lane];
    ushort4 q2 = gp[4 * 64 + lane],  q3 = gp[5 * 64 + lane];
    ushort4 q4 = gp[6 * 64 + lane],  q5 = gp[7 * 64 + lane];
    ushort4 q6 = gp[8 * 64 + lane],  q7 = gp[9 * 64 + lane];
    ushort4 q8 = gp[10 * 64 + lane], q9 = gp[11 * 64 + lane];
    ushort4 q10 = gp[12 * 64 + lane], q11 = gp[13 * 64 + lane];
    ushort4 q12 = gp[14 * 64 + lane], q13 = gp[15 * 64 + lane];
    ushort4 q14 = gp[16 * 64 + lane], q15 = gp[17 * 64 + lane];
    float rbA0 = gb[2 * (2 + l8)];
    float rbA1 = gb[2 * (10 + l8)];

    float a0 = 0.f, a1 = 0.f, a2 = 0.f, a3 = 0.f;
    float a4 = 0.f, a5 = 0.f, a6 = 0.f, a7 = 0.f, at = 0.f;
    int F = 0, di_g = 0;
    float b1_raw = 0.f;
    if (g0) { a0 = bl0; a1 = bfu(u0v.x); }
    float pb = bl1;
    float p1 = bfu(u1v.x), p3 = bfu(u1v.y), p5 = bfu(u1v.z), p7 = bfu(u1v.w);

    int tt = 1;
    for (; tt + 16 <= tm; tt += 16) {
      const float rbB0 = gb[2 * (tt + 17 + l8)];
      const float rbB1 = gb[2 * (tt + 25 + l8)];
      SLOTF(0, 0, rbA0);     SLOTF(1, di_g, rbA0);
      SLOTF(2, di_g, rbA0);  SLOTF(3, di_g, rbA0);
      SLOTF(4, di_g, rbA0);  SLOTF(5, di_g, rbA0);
      SLOTF(6, di_g, rbA0);  SLOTF(7, di_g, rbA0);
      SLOTF(8, di_g, rbA1);  SLOTF(9, di_g, rbA1);
      SLOTF(10, di_g, rbA1); SLOTF(11, di_g, rbA1);
      SLOTF(12, di_g, rbA1); SLOTF(13, di_g, rbA1);
      SLOTF(14, di_g, rbA1); SLOTF(15, di_g, rbA1);
      SYNCF;
      rbA0 = rbB0; rbA1 = rbB1;
    }
    if (tt + 0 < tm)  LEANF(q0,  RL(rbA0, 0), 0);
    if (tt + 1 < tm)  LEANF(q1,  RL(rbA0, 1), di_g);
    if (tt + 2 < tm)  LEANF(q2,  RL(rbA0, 2), di_g);
    if (tt + 3 < tm)  LEANF(q3,  RL(rbA0, 3), di_g);
    if (tt + 4 < tm)  LEANF(q4,  RL(rbA0, 4), di_g);
    if (tt + 5 < tm)  LEANF(q5,  RL(rbA0, 5), di_g);
    if (tt + 6 < tm)  LEANF(q6,  RL(rbA0, 6), di_g);
    if (tt + 7 < tm)  LEANF(q7,  RL(rbA0, 7), di_g);
    if (tt + 8 < tm)  LEANF(q8,  RL(rbA1, 0), di_g);
    if (tt + 9 < tm)  LEANF(q9,  RL(rbA1, 1), di_g);
    if (tt + 10 < tm) LEANF(q10, RL(rbA1, 2), di_g);
    if (tt + 11 < tm) LEANF(q11, RL(rbA1, 3), di_g);
    if (tt + 12 < tm) LEANF(q12, RL(rbA1, 4), di_g);
    if (tt + 13 < tm) LEANF(q13, RL(rbA1, 5), di_g);
    if (tt + 14 < tm) LEANF(q14, RL(rbA1, 6), di_g);

    const float Ff = (float)F;
    const int sb = 8 * lane;
    Alog[sb + 0] = (a0 > 0.f) ? lg2(a0) + Ff : -1.0e30f;
    Alog[sb + 1] = (a1 > 0.f) ? lg2(a1) + Ff : -1.0e30f;
    Alog[sb + 2] = (a2 > 0.f) ? lg2(a2) + Ff : -1.0e30f;
    Alog[sb + 3] = (a3 > 0.f) ? lg2(a3) + Ff : -1.0e30f;
    Alog[sb + 4] = (a4 > 0.f) ? lg2(a4) + Ff : -1.0e30f;
    Alog[sb + 5] = (a5 > 0.f) ? lg2(a5) + Ff : -1.0e30f;
    Alog[sb + 6] = (a6 > 0.f) ? lg2(a6) + Ff : -1.0e30f;
    Alog[sb + 7] = (a7 > 0.f) ? lg2(a7) + Ff : -1.0e30f;
    if (g63) Alog[512] = (at > 0.f) ? lg2(at) + Ff : -1.0e30f;
  } else {
    // ---------------- backward beta: rows Tb-1 .. tm ----------------
    const ushort4 uiv = gp[(size_t)(Tb - 1) * 64 + lane];
    const float bli = gb[2 * (Tb - 1) + lpar];
    ushort4 q0 = gp[(size_t)(Tb - 2) * 64 + lane],  q1 = gp[(size_t)(Tb - 3) * 64 + lane];
    ushort4 q2 = gp[(size_t)(Tb - 4) * 64 + lane],  q3 = gp[(size_t)(Tb - 5) * 64 + lane];
    ushort4 q4 = gp[(size_t)(Tb - 6) * 64 + lane],  q5 = gp[(size_t)(Tb - 7) * 64 + lane];
    ushort4 q6 = gp[(size_t)(Tb - 8) * 64 + lane],  q7 = gp[(size_t)(Tb - 9) * 64 + lane];
    ushort4 q8 = gp[(size_t)(Tb - 10) * 64 + lane], q9 = gp[(size_t)(Tb - 11) * 64 + lane];
    ushort4 q10 = gp[(size_t)(Tb - 12) * 64 + lane], q11 = gp[(size_t)(Tb - 13) * 64 + lane];
    ushort4 q12 = gp[(size_t)(Tb - 14) * 64 + lane], q13 = gp[(size_t)(Tb - 15) * 64 + lane];
    ushort4 q14 = gp[(size_t)(Tb - 16) * 64 + lane], q15 = gp[(size_t)(Tb - 17) * 64 + lane];
    float rbA0 = gb[2 * (Tb - 2 - l8)];
    float rbA1 = gb[2 * (Tb - 10 - l8)];

    const int sb = 8 * lane;
    float b0 = (sb + 0 == s_end || sb + 0 == s_end - 1) ? 1.f : 0.f;
    float b1 = (sb + 1 == s_end || sb + 1 == s_end - 1) ? 1.f : 0.f;
    float b2 = (sb + 2 == s_end || sb + 2 == s_end - 1) ? 1.f : 0.f;
    float b3 = (sb + 3 == s_end || sb + 3 == s_end - 1) ? 1.f : 0.f;
    float b4 = (sb + 4 == s_end || sb + 4 == s_end - 1) ? 1.f : 0.f;
    float b5 = (sb + 5 == s_end || sb + 5 == s_end - 1) ? 1.f : 0.f;
    float b6 = (sb + 6 == s_end || sb + 6 == s_end - 1) ? 1.f : 0.f;
    float b7 = (sb + 7 == s_end || sb + 7 == s_end - 1) ? 1.f : 0.f;
    float bt = (g63 && s_end == 512) ? 1.f : 0.f;
    int F = 0, di_g = 0;

    float pb = bli;  // probs of row Tb-1 (first consumed)
    float p1 = bfu(uiv.x), p3 = bfu(uiv.y), p5 = bfu(uiv.z), p7 = bfu(uiv.w);
    float u0 = dpp_shl1_f(b0);
    float v = dpp_shl1_f(b1 * p1);

    int tt = Tb - 1;
    for (; tt - 15 >= tm; tt -= 16) {
      const float rbB0 = gb[2 * (tt - 17 - l8)];
      const float rbB1 = gb[2 * (tt - 25 - l8)];
      SLOTB(0, 0, rbA0);     SLOTB(1, di_g, rbA0);
      SLOTB(2, di_g, rbA0);  SLOTB(3, di_g, rbA0);
      SLOTB(4, di_g, rbA0);  SLOTB(5, di_g, rbA0);
      SLOTB(6, di_g, rbA0);  SLOTB(7, di_g, rbA0);
      SLOTB(8, di_g, rbA1);  SLOTB(9, di_g, rbA1);
      SLOTB(10, di_g, rbA1); SLOTB(11, di_g, rbA1);
      SLOTB(12, di_g, rbA1); SLOTB(13, di_g, rbA1);
      SLOTB(14, di_g, rbA1); SLOTB(15, di_g, rbA1);
      SYNCB;
      rbA0 = rbB0; rbA1 = rbB1;
    }
    if (tt - 0 >= tm)  LEANB(q0,  RL(rbA0, 0), 0);
    if (tt - 1 >= tm)  LEANB(q1,  RL(rbA0, 1), di_g);
    if (tt - 2 >= tm)  LEANB(q2,  RL(rbA0, 2), di_g);
    if (tt - 3 >= tm)  LEANB(q3,  RL(rbA0, 3), di_g);
    if (tt - 4 >= tm)  LEANB(q4,  RL(rbA0, 4), di_g);
    if (tt - 5 >= tm)  LEANB(q5,  RL(rbA0, 5), di_g);
    if (tt - 6 >= tm)  LEANB(q6,  RL(rbA0, 6), di_g);
    if (tt - 7 >= tm)  LEANB(q7,  RL(rbA0, 7), di_g);
    if (tt - 8 >= tm)  LEANB(q8,  RL(rbA1, 0), di_g);
    if (tt - 9 >= tm)  LEANB(q9,  RL(rbA1, 1), di_g);
    if (tt - 10 >= tm) LEANB(q10, RL(rbA1, 2), di_g);
    if (tt - 11 >= tm) LEANB(q11, RL(rbA1, 3), di_g);
    if (tt - 12 >= tm) LEANB(q12, RL(rbA1, 4), di_g);
    if (tt - 13 >= tm) LEANB(q13, RL(rbA1, 5), di_g);
    if (tt - 14 >= tm) LEANB(q14, RL(rbA1, 6), di_g);

    const float Ff = (float)F;
    Blog[sb + 0] = (b0 > 0.f) ? lg2(b0) + Ff : -1.0e30f;
    Blog[sb + 1] = (b1 > 0.f) ? lg2(b1) + Ff : -1.0e30f;
    Blog[sb + 2] = (b2 > 0.f) ? lg2(b2) + Ff : -1.0e30f;
    Blog[sb + 3] = (b3 > 0.f) ? lg2(b3) + Ff : -1.0e30f;
    Blog[sb + 4] = (b4 > 0.f) ? lg2(b4) + Ff : -1.0e30f;
    Blog[sb + 5] = (b5 > 0.f) ? lg2(b5) + Ff : -1.0e30f;
    Blog[sb + 6] = (b6 > 0.f) ? lg2(b6) + Ff : -1.0e30f;
    Blog[sb + 7] = (b7 > 0.f) ? lg2(b7) + Ff : -1.0e30f;
    if (g63) Blog[512] = (bt > 0.f) ? lg2(bt) + Ff : -1.0e30f;
  }

  __syncthreads();

  if (wid == 0) {
    // log2 P = logsumexp2_s (Alog[s] + Blog[s])
    const int sb = 8 * lane;
    float t0 = Alog[sb + 0] + Blog[sb + 0];
    float t1 = Alog[sb + 1] + Blog[sb + 1];
    float t2 = Alog[sb + 2] + Blog[sb + 2];
    float t3 = Alog[sb + 3] + Blog[sb + 3];
    float t4 = Alog[sb + 4] + Blog[sb + 4];
    float t5 = Alog[sb + 5] + Blog[sb + 5];
    float t6 = Alog[sb + 6] + Blog[sb + 6];
    float t7 = Alog[sb + 7] + Blog[sb + 7];
    float t8 = g63 ? (Alog[512] + Blog[512]) : -1.0e30f;
    float M = fmaxf(fmaxf(fmaxf(t0, t1), fmaxf(t2, t3)),
                    fmaxf(fmaxf(t4, t5), fmaxf(fmaxf(t6, t7), t8)));
#pragma unroll
    for (int off = 32; off >= 1; off >>= 1) M = fmaxf(M, __shfl_xor(M, off));
    float sm = ex2(t0 - M) + ex2(t1 - M) + ex2(t2 - M) + ex2(t3 - M) +
               ex2(t4 - M) + ex2(t5 - M) + ex2(t6 - M) + ex2(t7 - M) +
               ex2(t8 - M);
#pragma unroll
    for (int off = 32; off >= 1; off >>= 1) sm += __shfl_xor(sm, off);
    if (lane == 0)
      out[b] = -0.6931471805599453f * (M + lg2(sm));
  }
}

extern "C" void kernel_launch(void* const* d_in, const int* in_sizes, int n_in,
                              void* d_out, int out_size, void* d_ws, size_t ws_size,
                              hipStream_t stream) {
  const int* labels = (const int*)d_in[0];
  const float* logits = (const float*)d_in[1];
  const int* widths = (const int*)d_in[2];
  const int* lengths = (const int*)d_in[3];
  float* out = (float*)d_out;

  // ws layout: [blanks2: B*T*2 fp32 = 512KB][packed: B*T*64 ushort4 = 32MB]
  float* blanks2 = (float*)d_ws;
  ushort4* packed = (ushort4*)((char*)d_ws + (size_t)B_ * T_ * 2 * sizeof(float));

  gather_pack<<<B_ * T_, 64, 0, stream>>>(logits, labels, blanks2, packed);
  ctc_dp<<<B_, 128, 0, stream>>>(packed, blanks2, labels, widths, lengths, out);
}

// Round 19
// 115.950 us; speedup vs baseline: 4.7488x; 1.0325x over previous
//
#include <hip/hip_runtime.h>
#include <math.h>

#define B_ 32
#define T_ 2048
#define C_ 96
#define L_ 256
#define BLANK 95

__device__ __forceinline__ float ex2(float x) {
  float r; asm("v_exp_f32 %0, %1" : "=v"(r) : "v"(x)); return r;
}
__device__ __forceinline__ float lg2(float x) {
  float r; asm("v_log_f32 %0, %1" : "=v"(r) : "v"(x)); return r;
}
__device__ __forceinline__ unsigned short f2bf(float f) {  // RNE f32->bf16
  unsigned u = __float_as_uint(f);
  return (unsigned short)((u + 0x7FFFu + ((u >> 16) & 1u)) >> 16);
}
__device__ __forceinline__ float bfu(unsigned short u) {
  return __uint_as_float((unsigned)u << 16);
}
// Wave shifts via DPP (VALU). 0x138 = WAVE_SHR1, 0x130 = WAVE_SHL1.
__device__ __forceinline__ float dpp_shr1_f(float x) {
  return __int_as_float(__builtin_amdgcn_update_dpp(
      0, __float_as_int(x), 0x138, 0xF, 0xF, false));
}
__device__ __forceinline__ int dpp_shr1_i(int x) {
  return __builtin_amdgcn_update_dpp(0, x, 0x138, 0xF, 0xF, false);
}
__device__ __forceinline__ float dpp_shl1_f(float x) {
  return __int_as_float(__builtin_amdgcn_update_dpp(
      0, __float_as_int(x), 0x130, 0xF, 0xF, false));
}
__device__ __forceinline__ int dpp_shl1_i(int x) {
  return __builtin_amdgcn_update_dpp(0, x, 0x130, 0xF, 0xF, false);
}
#define RL(V, J) __int_as_float(__builtin_amdgcn_readlane(__float_as_int(V), (J)))

// ---- Kernel 1: fused softmax + per-lane label-prob gather/pack ----
__global__ __launch_bounds__(64) void gather_pack(const float* __restrict__ logits,
                                                  const int* __restrict__ labels,
                                                  float* __restrict__ blanks2,
                                                  ushort4* __restrict__ packed) {
  const int tid = threadIdx.x;
  const int bt = blockIdx.x;  // b*T + t
  const int b = bt >> 11;
  const float* xr = logits + (size_t)bt * C_;
  float xa = xr[tid];
  float xb = (tid < 32) ? xr[64 + tid] : -1.0e30f;
  float m = fmaxf(xa, xb);
#pragma unroll
  for (int off = 32; off >= 1; off >>= 1) m = fmaxf(m, __shfl_xor(m, off));
  float ea = __expf(xa - m);
  float eb = (tid < 32) ? __expf(xb - m) : 0.f;
  float z = ea + eb;
#pragma unroll
  for (int off = 32; off >= 1; off >>= 1) z += __shfl_xor(z, off);
  float rz = 1.0f / z;
  __shared__ float sp[C_];
  sp[tid] = fmaf(ea, rz, 1e-7f);
  if (tid < 32) sp[64 + tid] = fmaf(eb, rz, 1e-7f);
  __syncthreads();
  const int4 lb = *reinterpret_cast<const int4*>(labels + (b << 8) + 4 * tid);
  ushort4 o;
  o.x = f2bf(sp[lb.x]); o.y = f2bf(sp[lb.y]);
  o.z = f2bf(sp[lb.z]); o.w = f2bf(sp[lb.w]);
  packed[(size_t)bt * 64 + tid] = o;
  if (tid < 2) blanks2[2 * bt + tid] = sp[BLANK];
}

// ---------------- Kernel 2: meet-in-the-middle CTC DP ----------------
// Grouped-frame protocol, groups of 16, INFLOW-AWARE PIN:
//   e = max(exponent(resident max), exponent(b1_raw) + di_g)
// The pin accounts for the in-flight boundary value, so the conversion
// co = di_g - sh always satisfies exp(b1_raw)+co <= 0: converted inflow
// <= 2 EXACTLY (ldexp by integer) -- no clamp, no mass loss, no overflow.
// di_g = d2 - s2 <= 4 (restored R17 invariant): in-group cascade gain
// <= 2^4/hop, <= 6 hops/group -> residents <= 2^25. Provably finite.
// Residents are flushed only when >= 2^126 below the inflow (negligible
// true mass). Dead lanes (all-zero, no inflow) drift F down ~126/group;
// alignment rounds (s1,s2, D=4) pull them back each sync.
// Row bounds at tm = 0.5547*Tb: fwd rows <= tm+16 <= 1152 < 2048;
// bwd rows >= tm-17 >= 834 > 0 (Tb in [1536, 2048]).

#define LEANF(QU, QB, DI) do {                                               \
    const float b1a = ldexpf(b1_raw, (DI));                                  \
    const float na7 = fmaf(m7, a5, a7 + a6) * p7;                            \
    const float b1n = dpp_shr1_f(na7);                                       \
    at = (at + a7) * pb;                                                     \
    a6 = (a6 + a5) * pb;                                                     \
    a5 = fmaf(m5, a3, a5 + a4) * p5;                                         \
    a4 = (a4 + a3) * pb;                                                     \
    a3 = fmaf(m3, a1, a3 + a2) * p3;                                         \
    a2 = (a2 + a1) * pb;                                                     \
    a1 = fmaf(m1, b1a, a1 + a0) * p1;                                        \
    a0 = (a0 + b1a) * pb;                                                    \
    a7 = na7;                                                                \
    b1_raw = b1n;                                                            \
    p1 = bfu((QU).x); p3 = bfu((QU).y); p5 = bfu((QU).z); p7 = bfu((QU).w);  \
    pb = (QB);                                                               \
  } while (0)

#define SYNCF do {                                                           \
    const float mA = fmaxf(fmaxf(a0, a1), a2);                               \
    const float mB = fmaxf(fmaxf(a3, a4), a5);                               \
    const float mC = fmaxf(fmaxf(a6, a7), at);                               \
    const float m8 = fmaxf(fmaxf(mA, mB), mC);                               \
    const int e_res = (int)((__float_as_uint(m8) >> 23) & 255u) - 126;       \
    const int e_in =                                                         \
        (int)((__float_as_uint(b1_raw) >> 23) & 255u) - 126 + di_g;          \
    const int e = (e_res > e_in) ? e_res : e_in;                             \
    F += e;                                                                  \
    const int Fp1 = dpp_shr1_i(F);                                           \
    const int d1 = g0 ? 0 : (Fp1 - F);                                       \
    const int s1 = (d1 > 4) ? (d1 - 4) : 0;                                  \
    F += s1;                                                                 \
    const int Fp2 = dpp_shr1_i(F);                                           \
    const int d2 = g0 ? 0 : (Fp2 - F);                                       \
    const int s2 = (d2 > 4) ? (d2 - 4) : 0;                                  \
    F += s2;                                                                 \
    const int sh = e + s1 + s2;                                              \
    a0 = ldexpf(a0, -sh); a1 = ldexpf(a1, -sh); a2 = ldexpf(a2, -sh);        \
    a3 = ldexpf(a3, -sh); a4 = ldexpf(a4, -sh); a5 = ldexpf(a5, -sh);        \
    a6 = ldexpf(a6, -sh); a7 = ldexpf(a7, -sh); at = ldexpf(at, -sh);        \
    b1_raw = ldexpf(b1_raw, di_g - sh);                                      \
    di_g = d2 - s2;                                                          \
  } while (0)

#define SLOTF(U, DI, RB) do {                                                \
    LEANF(q##U, RL(RB, (U) & 7), DI);                                        \
    q##U = gp[(size_t)(tt + 17 + U) * 64 + lane];                            \
  } while (0)

// Bwd lean: u0 = sender's nb0 (beta[8l+8]); v = sender's nb1*p1_next
// (= beta[8l+9]*p_t[8l+9]).
#define LEANB(QU, QB, DI) do {                                               \
    const float x0 = ldexpf(u0, (DI));                                       \
    const float yv = ldexpf(v, (DI));                                        \
    const float bp0 = b0 * pb, bp1 = b1 * p1, bp2 = b2 * pb, bp3 = b3 * p3,  \
                bp4 = b4 * pb, bp5 = b5 * p5, bp6 = b6 * pb, bp7 = b7 * p7,  \
                bpt = bt * pb;                                               \
    const float x0e = g63 ? bpt : (x0 * pb);                                 \
    const float nb0 = bp0 + bp1;                                             \
    const float nb1 = fmaf(m3, bp3, bp1 + bp2);                              \
    b2 = bp2 + bp3;                                                          \
    b3 = fmaf(m5, bp5, bp3 + bp4);                                           \
    b4 = bp4 + bp5;                                                          \
    b5 = fmaf(m7, bp7, bp5 + bp6);                                           \
    b6 = bp6 + bp7;                                                          \
    b7 = fmaf(mn, yv, bp7 + x0e);                                            \
    bt = bpt;                                                                \
    b0 = nb0; b1 = nb1;                                                      \
    p1 = bfu((QU).x); p3 = bfu((QU).y); p5 = bfu((QU).z); p7 = bfu((QU).w);  \
    pb = (QB);                                                               \
    u0 = dpp_shl1_f(nb0);                                                    \
    v = dpp_shl1_f(nb1 * p1);                                                \
  } while (0)

#define SYNCB do {                                                           \
    const float mA = fmaxf(fmaxf(b0, b1), b2);                               \
    const float mB = fmaxf(fmaxf(b3, b4), b5);                               \
    const float mC = fmaxf(fmaxf(b6, b7), bt);                               \
    const float m8 = fmaxf(fmaxf(mA, mB), mC);                               \
    const float mi = fmaxf(u0, v);                                           \
    const int e_res = (int)((__float_as_uint(m8) >> 23) & 255u) - 126;       \
    const int e_in =                                                         \
        (int)((__float_as_uint(mi) >> 23) & 255u) - 126 + di_g;              \
    const int e = (e_res > e_in) ? e_res : e_in;                             \
    F += e;                                                                  \
    const int Fp1 = dpp_shl1_i(F);                                           \
    const int d1 = g63 ? 0 : (Fp1 - F);                                      \
    const int s1 = (d1 > 4) ? (d1 - 4) : 0;                                  \
    F += s1;                                                                 \
    const int Fp2 = dpp_shl1_i(F);                                           \
    const int d2 = g63 ? 0 : (Fp2 - F);                                      \
    const int s2 = (d2 > 4) ? (d2 - 4) : 0;                                  \
    F += s2;                                                                 \
    const int sh = e + s1 + s2;                                              \
    b0 = ldexpf(b0, -sh); b1 = ldexpf(b1, -sh); b2 = ldexpf(b2, -sh);        \
    b3 = ldexpf(b3, -sh); b4 = ldexpf(b4, -sh); b5 = ldexpf(b5, -sh);        \
    b6 = ldexpf(b6, -sh); b7 = ldexpf(b7, -sh); bt = ldexpf(bt, -sh);        \
    u0 = ldexpf(u0, di_g - sh);                                              \
    v = ldexpf(v, di_g - sh);                                                \
    di_g = d2 - s2;                                                          \
  } while (0)

#define SLOTB(U, DI, RB) do {                                                \
    LEANB(q##U, RL(RB, (U) & 7), DI);                                        \
    q##U = gp[(size_t)(tt - 17 - U) * 64 + lane];                            \
  } while (0)

__global__ __launch_bounds__(128) void ctc_dp(const ushort4* __restrict__ packed,
                                              const float* __restrict__ blanks2,
                                              const int* __restrict__ labels,
                                              const int* __restrict__ widths,
                                              const int* __restrict__ lengths,
                                              float* __restrict__ out) {
  __shared__ float Alog[513];
  __shared__ float Blog[513];
  const int b = blockIdx.x;
  const int tid = threadIdx.x;
  const int wid = tid >> 6;
  const int lane = tid & 63;
  const int l8 = lane & 7;
  const int lpar = lane & 1;
  const bool g0 = (lane == 0);
  const bool g63 = (lane == 63);
  const int Tb = widths[b] >> 3;     // in [1536, 2048]
  const int s_end = 2 * lengths[b];
  const int tm = (Tb * 71) >> 7;     // meet row (fwd/bwd cost-balanced)
  const int* lab = labels + (b << 8);
  const int4 lb = *reinterpret_cast<const int4*>(lab + 4 * lane);
  const int pw = __shfl_up(lb.w, 1);
  const float m1 = (lane > 0 && lb.x != pw) ? 1.f : 0.f;
  const float m3 = (lb.y != lb.x) ? 1.f : 0.f;
  const float m5 = (lb.z != lb.y) ? 1.f : 0.f;
  const float m7 = (lb.w != lb.z) ? 1.f : 0.f;
  const float mdn = __shfl_down(m1, 1);
  const float mn = g63 ? 0.f : mdn;  // skip mask for s+2 = 8l+9

  const ushort4* gp = packed + (size_t)b * (T_ * 64);
  const float* gb = blanks2 + b * (2 * T_);

  if (wid == 0) {
    // ---------------- forward alpha: rows 0 .. tm-1 ----------------
    const ushort4 u0v = gp[lane];
    const float bl0 = gb[lpar];
    const ushort4 u1v = gp[64 + lane];
    const float bl1 = gb[2 + lpar];
    ushort4 q0 = gp[2 * 64 + lane],  q1 = gp[3 * 64 + lane];
    ushort4 q2 = gp[4 * 64 + lane],  q3 = gp[5 * 64 + lane];
    ushort4 q4 = gp[6 * 64 + lane],  q5 = gp[7 * 64 + lane];
    ushort4 q6 = gp[8 * 64 + lane],  q7 = gp[9 * 64 + lane];
    ushort4 q8 = gp[10 * 64 + lane], q9 = gp[11 * 64 + lane];
    ushort4 q10 = gp[12 * 64 + lane], q11 = gp[13 * 64 + lane];
    ushort4 q12 = gp[14 * 64 + lane], q13 = gp[15 * 64 + lane];
    ushort4 q14 = gp[16 * 64 + lane], q15 = gp[17 * 64 + lane];
    float rbA0 = gb[2 * (2 + l8)];
    float rbA1 = gb[2 * (10 + l8)];

    float a0 = 0.f, a1 = 0.f, a2 = 0.f, a3 = 0.f;
    float a4 = 0.f, a5 = 0.f, a6 = 0.f, a7 = 0.f, at = 0.f;
    int F = 0, di_g = 0;
    float b1_raw = 0.f;
    if (g0) { a0 = bl0; a1 = bfu(u0v.x); }
    float pb = bl1;
    float p1 = bfu(u1v.x), p3 = bfu(u1v.y), p5 = bfu(u1v.z), p7 = bfu(u1v.w);

    int tt = 1;
    for (; tt + 16 <= tm; tt += 16) {
      const float rbB0 = gb[2 * (tt + 17 + l8)];
      const float rbB1 = gb[2 * (tt + 25 + l8)];
      SLOTF(0, 0, rbA0);     SLOTF(1, di_g, rbA0);
      SLOTF(2, di_g, rbA0);  SLOTF(3, di_g, rbA0);
      SLOTF(4, di_g, rbA0);  SLOTF(5, di_g, rbA0);
      SLOTF(6, di_g, rbA0);  SLOTF(7, di_g, rbA0);
      SLOTF(8, di_g, rbA1);  SLOTF(9, di_g, rbA1);
      SLOTF(10, di_g, rbA1); SLOTF(11, di_g, rbA1);
      SLOTF(12, di_g, rbA1); SLOTF(13, di_g, rbA1);
      SLOTF(14, di_g, rbA1); SLOTF(15, di_g, rbA1);
      SYNCF;
      rbA0 = rbB0; rbA1 = rbB1;
    }
    if (tt + 0 < tm)  LEANF(q0,  RL(rbA0, 0), 0);
    if (tt + 1 < tm)  LEANF(q1,  RL(rbA0, 1), di_g);
    if (tt + 2 < tm)  LEANF(q2,  RL(rbA0, 2), di_g);
    if (tt + 3 < tm)  LEANF(q3,  RL(rbA0, 3), di_g);
    if (tt + 4 < tm)  LEANF(q4,  RL(rbA0, 4), di_g);
    if (tt + 5 < tm)  LEANF(q5,  RL(rbA0, 5), di_g);
    if (tt + 6 < tm)  LEANF(q6,  RL(rbA0, 6), di_g);
    if (tt + 7 < tm)  LEANF(q7,  RL(rbA0, 7), di_g);
    if (tt + 8 < tm)  LEANF(q8,  RL(rbA1, 0), di_g);
    if (tt + 9 < tm)  LEANF(q9,  RL(rbA1, 1), di_g);
    if (tt + 10 < tm) LEANF(q10, RL(rbA1, 2), di_g);
    if (tt + 11 < tm) LEANF(q11, RL(rbA1, 3), di_g);
    if (tt + 12 < tm) LEANF(q12, RL(rbA1, 4), di_g);
    if (tt + 13 < tm) LEANF(q13, RL(rbA1, 5), di_g);
    if (tt + 14 < tm) LEANF(q14, RL(rbA1, 6), di_g);

    const float Ff = (float)F;
    const int sb = 8 * lane;
    Alog[sb + 0] = (a0 > 0.f) ? lg2(a0) + Ff : -1.0e30f;
    Alog[sb + 1] = (a1 > 0.f) ? lg2(a1) + Ff : -1.0e30f;
    Alog[sb + 2] = (a2 > 0.f) ? lg2(a2) + Ff : -1.0e30f;
    Alog[sb + 3] = (a3 > 0.f) ? lg2(a3) + Ff : -1.0e30f;
    Alog[sb + 4] = (a4 > 0.f) ? lg2(a4) + Ff : -1.0e30f;
    Alog[sb + 5] = (a5 > 0.f) ? lg2(a5) + Ff : -1.0e30f;
    Alog[sb + 6] = (a6 > 0.f) ? lg2(a6) + Ff : -1.0e30f;
    Alog[sb + 7] = (a7 > 0.f) ? lg2(a7) + Ff : -1.0e30f;
    if (g63) Alog[512] = (at > 0.f) ? lg2(at) + Ff : -1.0e30f;
  } else {
    // ---------------- backward beta: rows Tb-1 .. tm ----------------
    const ushort4 uiv = gp[(size_t)(Tb - 1) * 64 + lane];
    const float bli = gb[2 * (Tb - 1) + lpar];
    ushort4 q0 = gp[(size_t)(Tb - 2) * 64 + lane],  q1 = gp[(size_t)(Tb - 3) * 64 + lane];
    ushort4 q2 = gp[(size_t)(Tb - 4) * 64 + lane],  q3 = gp[(size_t)(Tb - 5) * 64 + lane];
    ushort4 q4 = gp[(size_t)(Tb - 6) * 64 + lane],  q5 = gp[(size_t)(Tb - 7) * 64 + lane];
    ushort4 q6 = gp[(size_t)(Tb - 8) * 64 + lane],  q7 = gp[(size_t)(Tb - 9) * 64 + lane];
    ushort4 q8 = gp[(size_t)(Tb - 10) * 64 + lane], q9 = gp[(size_t)(Tb - 11) * 64 + lane];
    ushort4 q10 = gp[(size_t)(Tb - 12) * 64 + lane], q11 = gp[(size_t)(Tb - 13) * 64 + lane];
    ushort4 q12 = gp[(size_t)(Tb - 14) * 64 + lane], q13 = gp[(size_t)(Tb - 15) * 64 + lane];
    ushort4 q14 = gp[(size_t)(Tb - 16) * 64 + lane], q15 = gp[(size_t)(Tb - 17) * 64 + lane];
    float rbA0 = gb[2 * (Tb - 2 - l8)];
    float rbA1 = gb[2 * (Tb - 10 - l8)];

    const int sb = 8 * lane;
    float b0 = (sb + 0 == s_end || sb + 0 == s_end - 1) ? 1.f : 0.f;
    float b1 = (sb + 1 == s_end || sb + 1 == s_end - 1) ? 1.f : 0.f;
    float b2 = (sb + 2 == s_end || sb + 2 == s_end - 1) ? 1.f : 0.f;
    float b3 = (sb + 3 == s_end || sb + 3 == s_end - 1) ? 1.f : 0.f;
    float b4 = (sb + 4 == s_end || sb + 4 == s_end - 1) ? 1.f : 0.f;
    float b5 = (sb + 5 == s_end || sb + 5 == s_end - 1) ? 1.f : 0.f;
    float b6 = (sb + 6 == s_end || sb + 6 == s_end - 1) ? 1.f : 0.f;
    float b7 = (sb + 7 == s_end || sb + 7 == s_end - 1) ? 1.f : 0.f;
    float bt = (g63 && s_end == 512) ? 1.f : 0.f;
    int F = 0, di_g = 0;

    float pb = bli;  // probs of row Tb-1 (first consumed)
    float p1 = bfu(uiv.x), p3 = bfu(uiv.y), p5 = bfu(uiv.z), p7 = bfu(uiv.w);
    float u0 = dpp_shl1_f(b0);
    float v = dpp_shl1_f(b1 * p1);

    int tt = Tb - 1;
    for (; tt - 15 >= tm; tt -= 16) {
      const float rbB0 = gb[2 * (tt - 17 - l8)];
      const float rbB1 = gb[2 * (tt - 25 - l8)];
      SLOTB(0, 0, rbA0);     SLOTB(1, di_g, rbA0);
      SLOTB(2, di_g, rbA0);  SLOTB(3, di_g, rbA0);
      SLOTB(4, di_g, rbA0);  SLOTB(5, di_g, rbA0);
      SLOTB(6, di_g, rbA0);  SLOTB(7, di_g, rbA0);
      SLOTB(8, di_g, rbA1);  SLOTB(9, di_g, rbA1);
      SLOTB(10, di_g, rbA1); SLOTB(11, di_g, rbA1);
      SLOTB(12, di_g, rbA1); SLOTB(13, di_g, rbA1);
      SLOTB(14, di_g, rbA1); SLOTB(15, di_g, rbA1);
      SYNCB;
      rbA0 = rbB0; rbA1 = rbB1;
    }
    if (tt - 0 >= tm)  LEANB(q0,  RL(rbA0, 0), 0);
    if (tt - 1 >= tm)  LEANB(q1,  RL(rbA0, 1), di_g);
    if (tt - 2 >= tm)  LEANB(q2,  RL(rbA0, 2), di_g);
    if (tt - 3 >= tm)  LEANB(q3,  RL(rbA0, 3), di_g);
    if (tt - 4 >= tm)  LEANB(q4,  RL(rbA0, 4), di_g);
    if (tt - 5 >= tm)  LEANB(q5,  RL(rbA0, 5), di_g);
    if (tt - 6 >= tm)  LEANB(q6,  RL(rbA0, 6), di_g);
    if (tt - 7 >= tm)  LEANB(q7,  RL(rbA0, 7), di_g);
    if (tt - 8 >= tm)  LEANB(q8,  RL(rbA1, 0), di_g);
    if (tt - 9 >= tm)  LEANB(q9,  RL(rbA1, 1), di_g);
    if (tt - 10 >= tm) LEANB(q10, RL(rbA1, 2), di_g);
    if (tt - 11 >= tm) LEANB(q11, RL(rbA1, 3), di_g);
    if (tt - 12 >= tm) LEANB(q12, RL(rbA1, 4), di_g);
    if (tt - 13 >= tm) LEANB(q13, RL(rbA1, 5), di_g);
    if (tt - 14 >= tm) LEANB(q14, RL(rbA1, 6), di_g);

    const float Ff = (float)F;
    Blog[sb + 0] = (b0 > 0.f) ? lg2(b0) + Ff : -1.0e30f;
    Blog[sb + 1] = (b1 > 0.f) ? lg2(b1) + Ff : -1.0e30f;
    Blog[sb + 2] = (b2 > 0.f) ? lg2(b2) + Ff : -1.0e30f;
    Blog[sb + 3] = (b3 > 0.f) ? lg2(b3) + Ff : -1.0e30f;
    Blog[sb + 4] = (b4 > 0.f) ? lg2(b4) + Ff : -1.0e30f;
    Blog[sb + 5] = (b5 > 0.f) ? lg2(b5) + Ff : -1.0e30f;
    Blog[sb + 6] = (b6 > 0.f) ? lg2(b6) + Ff : -1.0e30f;
    Blog[sb + 7] = (b7 > 0.f) ? lg2(b7) + Ff : -1.0e30f;
    if (g63) Blog[512] = (bt > 0.f) ? lg2(bt) + Ff : -1.0e30f;
  }

  __syncthreads();

  if (wid == 0) {
    // log2 P = logsumexp2_s (Alog[s] + Blog[s])
    const int sb = 8 * lane;
    float t0 = Alog[sb + 0] + Blog[sb + 0];
    float t1 = Alog[sb + 1] + Blog[sb + 1];
    float t2 = Alog[sb + 2] + Blog[sb + 2];
    float t3 = Alog[sb + 3] + Blog[sb + 3];
    float t4 = Alog[sb + 4] + Blog[sb + 4];
    float t5 = Alog[sb + 5] + Blog[sb + 5];
    float t6 = Alog[sb + 6] + Blog[sb + 6];
    float t7 = Alog[sb + 7] + Blog[sb + 7];
    float t8 = g63 ? (Alog[512] + Blog[512]) : -1.0e30f;
    float M = fmaxf(fmaxf(fmaxf(t0, t1), fmaxf(t2, t3)),
                    fmaxf(fmaxf(t4, t5), fmaxf(fmaxf(t6, t7), t8)));
#pragma unroll
    for (int off = 32; off >= 1; off >>= 1) M = fmaxf(M, __shfl_xor(M, off));
    float sm = ex2(t0 - M) + ex2(t1 - M) + ex2(t2 - M) + ex2(t3 - M) +
               ex2(t4 - M) + ex2(t5 - M) + ex2(t6 - M) + ex2(t7 - M) +
               ex2(t8 - M);
#pragma unroll
    for (int off = 32; off >= 1; off >>= 1) sm += __shfl_xor(sm, off);
    if (lane == 0)
      out[b] = -0.6931471805599453f * (M + lg2(sm));
  }
}

extern "C" void kernel_launch(void* const* d_in, const int* in_sizes, int n_in,
                              void* d_out, int out_size, void* d_ws, size_t ws_size,
                              hipStream_t stream) {
  const int* labels = (const int*)d_in[0];
  const float* logits = (const float*)d_in[1];
  const int* widths = (const int*)d_in[2];
  const int* lengths = (const int*)d_in[3];
  float* out = (float*)d_out;

  // ws layout: [blanks2: B*T*2 fp32 = 512KB][packed: B*T*64 ushort4 = 32MB]
  float* blanks2 = (float*)d_ws;
  ushort4* packed = (ushort4*)((char*)d_ws + (size_t)B_ * T_ * 2 * sizeof(float));

  gather_pack<<<B_ * T_, 64, 0, stream>>>(logits, labels, blanks2, packed);
  ctc_dp<<<B_, 128, 0, stream>>>(packed, blanks2, labels, widths, lengths, out);
}